// Round 4
// baseline (695.441 us; speedup 1.0000x reference)
//
#include <hip/hip_runtime.h>
#include <hip/hip_bf16.h>
#include <math.h>

#define B_ 4
#define N_ 8192
#define MD_ 512
#define H_ 8
#define F_ 16
#define S_ 32
#define S3_ 32768
#define L_ 256
#define CO_ 152   // H*(F+3)
#define HF_ 128   // H*F
#define EPS_ 1e-5f

// ---------------- zero the 1024 bin counters --------------------------------
__global__ __launch_bounds__(1024) void zero_bins(int* __restrict__ counts) {
    counts[threadIdx.x] = 0;
}

// ---------------- style projections: h = style @ W.T + b --------------------
__global__ __launch_bounds__(256) void style_proj(
    const float* __restrict__ style,
    const float* __restrict__ kw_w, const float* __restrict__ kw_b,
    const float* __restrict__ vw_w, const float* __restrict__ vw_b,
    const float* __restrict__ aw_w, const float* __restrict__ aw_b,
    float* __restrict__ hk, float* __restrict__ hv, float* __restrict__ ha) {
    int b = blockIdx.x;
    const float* st = style + b * L_;
    for (int r = threadIdx.x; r < 48 + 256 + 256; r += 256) {
        const float* wrow; float bias; float* dst; int j;
        if (r < 48)       { j = r;       wrow = kw_w + j * L_; bias = kw_b[j]; dst = hk + b * 48; }
        else if (r < 304) { j = r - 48;  wrow = vw_w + j * L_; bias = vw_b[j]; dst = hv + b * 256; }
        else              { j = r - 304; wrow = aw_w + j * L_; bias = aw_b[j]; dst = ha + b * 256; }
        float acc = bias;
        for (int l = 0; l < L_; ++l) acc = fmaf(st[l], wrow[l], acc);
        dst[j] = acc;
    }
}

// ---------------- conv-weight transpose to [h][tap][ic][oc] -----------------
__global__ __launch_bounds__(256) void wtrans_vm(const float* __restrict__ cw, float* __restrict__ wt) {
    int i = blockIdx.x * 256 + threadIdx.x;   // 8*27*16*16 = 55296 total
    int oc  = i & 15;
    int ic  = (i >> 4) & 15;
    int tap = (i >> 8) % 27;
    int h   = (i >> 8) / 27;
    wt[i] = cw[(((h * 16 + oc) * 16 + ic) * 27) + tap];
}

// ---------------- kv = W_kv @ input  (per batch) ----------------------------
__global__ __launch_bounds__(256) void kv_gemm(
    const float* __restrict__ input, const float* __restrict__ Wkv, float* __restrict__ kv) {
    int b = blockIdx.z, rb = blockIdx.y;
    int n0 = blockIdx.x * 1024 + (threadIdx.x << 2);
    __shared__ float wlds[19 * MD_];
    for (int i = threadIdx.x; i < 19 * MD_ / 4; i += 256)
        ((float4*)wlds)[i] = ((const float4*)(Wkv + rb * 19 * MD_))[i];
    __syncthreads();
    float acc[19][4];
    #pragma unroll
    for (int i = 0; i < 19; ++i)
        for (int q = 0; q < 4; ++q) acc[i][q] = 0.f;
    const float* inb = input + (size_t)b * MD_ * N_ + n0;
    for (int c = 0; c < MD_; ++c) {
        float4 x = *(const float4*)(inb + (size_t)c * N_);
        #pragma unroll
        for (int i = 0; i < 19; ++i) {
            float w = wlds[i * MD_ + c];
            acc[i][0] = fmaf(w, x.x, acc[i][0]);
            acc[i][1] = fmaf(w, x.y, acc[i][1]);
            acc[i][2] = fmaf(w, x.z, acc[i][2]);
            acc[i][3] = fmaf(w, x.w, acc[i][3]);
        }
    }
    float* outb = kv + (size_t)b * CO_ * N_ + n0;
    #pragma unroll
    for (int i = 0; i < 19; ++i)
        *(float4*)(outb + (size_t)(rb * 19 + i) * N_) =
            make_float4(acc[i][0], acc[i][1], acc[i][2], acc[i][3]);
}

// ---------------- per-(b,channel) mean / rsig over N ------------------------
__global__ __launch_bounds__(256) void stats_kernel(
    const float* __restrict__ x, float* __restrict__ mean, float* __restrict__ rsig) {
    int bc = blockIdx.x;
    const float* p = x + (size_t)bc * N_;
    float s = 0.f, s2 = 0.f;
    for (int i = threadIdx.x; i < N_; i += 256) {
        float v = p[i]; s += v; s2 = fmaf(v, v, s2);
    }
    #pragma unroll
    for (int off = 32; off; off >>= 1) { s += __shfl_down(s, off); s2 += __shfl_down(s2, off); }
    __shared__ float ls[4], ls2[4];
    int wid = threadIdx.x >> 6;
    if ((threadIdx.x & 63) == 0) { ls[wid] = s; ls2[wid] = s2; }
    __syncthreads();
    if (threadIdx.x == 0) {
        float S = ls[0] + ls[1] + ls[2] + ls[3];
        float S2 = ls2[0] + ls2[1] + ls2[2] + ls2[3];
        float mu = S * (1.f / N_);
        float var = S2 * (1.f / N_) - mu * mu;
        mean[bc] = mu;
        rsig[bc] = rsqrtf(var + EPS_);
    }
}

// ---------------- point prep: AdaIN + transform + tanh + interp + count -----
__global__ __launch_bounds__(256) void point_prep(
    const float* __restrict__ kv, const float* __restrict__ mean_kv,
    const float* __restrict__ rsig_kv, const float* __restrict__ hk,
    const float* __restrict__ hv, const float* __restrict__ orig,
    const float* __restrict__ scale_p, const float* __restrict__ Tw,
    const float* __restrict__ Tb,
    float4* __restrict__ coordbuf, float* __restrict__ vbuf,
    int* __restrict__ counts) {
    int p = blockIdx.x * 256 + threadIdx.x;
    int n = p & (N_ - 1);
    int bh = p >> 13;
    int h = bh & 7, b = bh >> 3;
    float scl = scale_p[0];

    float pt[3];
    #pragma unroll
    for (int j = 0; j < 3; ++j) {
        int c = h * 3 + j;
        float x  = kv[((size_t)(b * CO_ + c)) * N_ + n];
        float xn = (x - mean_kv[b * CO_ + c]) * rsig_kv[b * CO_ + c];
        float kr = fmaf(1.f + hk[b * 48 + c], xn, hk[b * 48 + 24 + c]);
        pt[j] = fmaf(scl, kr, orig[((size_t)(b * 3 + j)) * N_ + n]);
    }
    int f0[3]; float tt[3];
    #pragma unroll
    for (int i = 0; i < 3; ++i) {
        float key = Tb[h * 3 + i];
        #pragma unroll
        for (int j = 0; j < 3; ++j) key = fmaf(Tw[(h * 3 + i) * 3 + j], pt[j], key);
        float lat = tanhf(key);
        float g = (lat + 1.f) * 0.5f * (float)(S_ - 1);
        float ff = floorf(g);
        ff = fminf(fmaxf(ff, 0.f), 30.f);
        f0[i] = (int)ff;
        tt[i] = fminf(fmaxf(g - ff, 0.f), 1.f);
    }
    coordbuf[p] = make_float4(tt[0], tt[1], tt[2],
                              __int_as_float(f0[0] | (f0[1] << 5) | (f0[2] << 10)));
    atomicAdd(&counts[(bh << 5) + f0[0]], 1);
    float vf[16];
    #pragma unroll
    for (int f = 0; f < F_; ++f) {
        int c = 24 + h * F_ + f;
        float x  = kv[((size_t)(b * CO_ + c)) * N_ + n];
        float xn = (x - mean_kv[b * CO_ + c]) * rsig_kv[b * CO_ + c];
        int cv = h * F_ + f;
        vf[f] = fmaf(1.f + hv[b * 256 + cv], xn, hv[b * 256 + 128 + cv]);
    }
    float4* vb = (float4*)(vbuf + (size_t)p * 16);
    #pragma unroll
    for (int q = 0; q < 4; ++q)
        vb[q] = make_float4(vf[q * 4], vf[q * 4 + 1], vf[q * 4 + 2], vf[q * 4 + 3]);
}

// ---------------- exclusive prefix over the 1024 bins (one wave) ------------
__global__ __launch_bounds__(64) void prefix_bins(
    const int* __restrict__ counts, int* __restrict__ base, int* __restrict__ cursor) {
    int lane = threadIdx.x;
    int local[16], sum = 0;
    #pragma unroll
    for (int i = 0; i < 16; ++i) { local[i] = sum; sum += counts[lane * 16 + i]; }
    int incl = sum;
    #pragma unroll
    for (int off = 1; off < 64; off <<= 1) {
        int v = __shfl_up(incl, off);
        if (lane >= off) incl += v;
    }
    int excl = incl - sum;
    #pragma unroll
    for (int i = 0; i < 16; ++i) {
        int bse = excl + local[i];
        base[lane * 16 + i] = bse;
        cursor[lane * 16 + i] = bse;
    }
    if (lane == 63) base[1024] = excl + sum;
}

// ---------------- scatter point indices into bins ---------------------------
__global__ __launch_bounds__(256) void scatter_pts(
    const float4* __restrict__ coordbuf, int* __restrict__ cursor,
    unsigned short* __restrict__ recs) {
    int p = blockIdx.x * 256 + threadIdx.x;
    int bh = p >> 13;
    int pk = __float_as_int(((const float*)coordbuf)[(size_t)p * 4 + 3]);
    int f0x = pk & 31;
    int slot = atomicAdd(&cursor[(bh << 5) + f0x], 1);
    recs[slot] = (unsigned short)(p & (N_ - 1));
}

// ---------------- splat, binned: all lanes active ---------------------------
// block -> one x-plane of one (b,h) lattice; reads bin[x0] (cx=0) + bin[x0-1] (cx=1)
__global__ __launch_bounds__(512) void splat2(
    const float4* __restrict__ coordbuf, const float* __restrict__ vbuf,
    const int* __restrict__ base, const unsigned short* __restrict__ recs,
    float* __restrict__ z) {
    __shared__ float tile[16384];             // 32*32 voxels * 16 f, swizzled
    int logical = (blockIdx.x & 7) * 128 + (blockIdx.x >> 3);  // XCD swizzle (1024 = 8*128)
    int bh = logical >> 5;
    int x0 = logical & 31;
    for (int i = threadIdx.x; i < 16384; i += 512) tile[i] = 0.f;
    __syncthreads();
    int bin0 = (bh << 5) + x0;
    int s0 = base[bin0], len0 = base[bin0 + 1] - s0;
    int s1 = 0, len1 = 0;
    if (x0 > 0) { s1 = base[bin0 - 1]; len1 = s0 - s1; }
    int total = len0 + len1;
    const float4* cb = coordbuf + (size_t)bh * N_;
    const float* vb = vbuf + ((size_t)bh * N_) * 16;
    for (int t = threadIdx.x; t < total; t += 512) {
        int cx, n;
        if (t < len0) { n = recs[s0 + t]; cx = 0; }
        else          { n = recs[s1 + (t - len0)]; cx = 1; }
        float4 c = cb[n];
        int pk = __float_as_int(c.w);
        float wx = cx ? c.x : 1.f - c.x;
        int f0y = (pk >> 5) & 31, f0z = (pk >> 10) & 31;
        const float4* vp = (const float4*)(vb + (size_t)n * 16);
        float4 v0 = vp[0], v1 = vp[1], v2 = vp[2], v3 = vp[3];
        float vf[16] = {v0.x, v0.y, v0.z, v0.w, v1.x, v1.y, v1.z, v1.w,
                        v2.x, v2.y, v2.z, v2.w, v3.x, v3.y, v3.z, v3.w};
        #pragma unroll
        for (int cy = 0; cy < 2; ++cy) {
            float wxy = wx * (cy ? c.y : 1.f - c.y);
            #pragma unroll
            for (int cz = 0; cz < 2; ++cz) {
                float w = wxy * (cz ? c.z : 1.f - c.z);
                int vox = ((f0y + cy) << 5) + f0z + cz;
                int bse = vox << 4, rot = vox & 15;
                #pragma unroll
                for (int f = 0; f < 16; ++f)
                    unsafeAtomicAdd(&tile[bse + ((f + rot) & 15)], vf[f] * w);
            }
        }
    }
    __syncthreads();
    float* zb = z + (((size_t)bh * S3_ + (x0 << 10)) << 4);
    for (int i = threadIdx.x; i < 16384; i += 512) {
        int vox = i >> 4, f = i & 15;
        zb[i] = tile[(vox << 4) + ((f + vox) & 15)];
    }
}

// ---------------- grouped 3x3x3 conv, voxel-major, no-spill -----------------
__global__ __launch_bounds__(512) void conv3d_vm(
    const float* __restrict__ z, const float* __restrict__ wt,
    const float* __restrict__ cbias, float* __restrict__ zc) {
    int logical = (blockIdx.x & 7) * 256 + (blockIdx.x >> 3);  // 2048 = 8*256
    int bh = logical >> 6;
    int part = logical & 63;
    int h = bh & 7;
    int vv = part * 512 + threadIdx.x;
    int xc = vv >> 10, yc = (vv >> 5) & 31, zd = vv & 31;
    const float* inb = z + ((size_t)bh << 19);   // 32768*16
    const float* wg = wt + h * 6912;
    float acc[16];
    #pragma unroll
    for (int o = 0; o < 16; ++o) acc[o] = 0.f;
    #pragma unroll 1
    for (int tap = 0; tap < 27; ++tap) {
        int dx = tap / 9, r9 = tap - dx * 9;
        int dy = r9 / 3, dz = r9 - dy * 3;
        int xx = xc + dx - 1, yy = yc + dy - 1, zz = zd + dz - 1;
        bool ok = (xx >= 0) & (xx <= 31) & (yy >= 0) & (yy <= 31) & (zz >= 0) & (zz <= 31);
        const float4* ip = (const float4*)(inb + ((size_t)((((xx << 5) + yy) << 5) + zz) << 4));
        float4 x0, x1, x2, x3;
        if (ok) { x0 = ip[0]; x1 = ip[1]; x2 = ip[2]; x3 = ip[3]; }
        else {
            x0 = make_float4(0.f, 0.f, 0.f, 0.f); x1 = x0; x2 = x0; x3 = x0;
        }
        float xin[16] = {x0.x, x0.y, x0.z, x0.w, x1.x, x1.y, x1.z, x1.w,
                         x2.x, x2.y, x2.z, x2.w, x3.x, x3.y, x3.z, x3.w};
        const float4* wp = (const float4*)(wg + tap * 256);
        #pragma unroll
        for (int ic = 0; ic < 16; ++ic) {
            float xv = xin[ic];
            float4 w0 = wp[ic * 4 + 0], w1 = wp[ic * 4 + 1];
            float4 w2 = wp[ic * 4 + 2], w3 = wp[ic * 4 + 3];
            acc[0]  = fmaf(xv, w0.x, acc[0]);  acc[1]  = fmaf(xv, w0.y, acc[1]);
            acc[2]  = fmaf(xv, w0.z, acc[2]);  acc[3]  = fmaf(xv, w0.w, acc[3]);
            acc[4]  = fmaf(xv, w1.x, acc[4]);  acc[5]  = fmaf(xv, w1.y, acc[5]);
            acc[6]  = fmaf(xv, w1.z, acc[6]);  acc[7]  = fmaf(xv, w1.w, acc[7]);
            acc[8]  = fmaf(xv, w2.x, acc[8]);  acc[9]  = fmaf(xv, w2.y, acc[9]);
            acc[10] = fmaf(xv, w2.z, acc[10]); acc[11] = fmaf(xv, w2.w, acc[11]);
            acc[12] = fmaf(xv, w3.x, acc[12]); acc[13] = fmaf(xv, w3.y, acc[13]);
            acc[14] = fmaf(xv, w3.z, acc[14]); acc[15] = fmaf(xv, w3.w, acc[15]);
        }
    }
    float* ob = zc + ((size_t)bh << 19) + ((size_t)vv << 4);
    const float* bp = cbias + h * 16;
    #pragma unroll
    for (int q = 0; q < 4; ++q)
        ((float4*)ob)[q] = make_float4(acc[q*4] + bp[q*4], acc[q*4+1] + bp[q*4+1],
                                       acc[q*4+2] + bp[q*4+2], acc[q*4+3] + bp[q*4+3]);
}

// ---------------- slice: weighted gather back to points ---------------------
__global__ __launch_bounds__(256) void slice_vm(
    const float* __restrict__ zc, const float4* __restrict__ coordbuf,
    float* __restrict__ out) {
    int p = blockIdx.x * 256 + threadIdx.x;
    int n = p & (N_ - 1);
    int bh = p >> 13;
    int h = bh & 7, b = bh >> 3;
    float4 c = coordbuf[p];
    int pk = __float_as_int(c.w);
    int f0x = pk & 31, f0y = (pk >> 5) & 31, f0z = (pk >> 10) & 31;
    const float* gb = zc + ((size_t)bh << 19);
    float acc[16];
    #pragma unroll
    for (int f = 0; f < 16; ++f) acc[f] = 0.f;
    #pragma unroll 1
    for (int k = 0; k < 8; ++k) {
        int cx = (k >> 2) & 1, cy = (k >> 1) & 1, cz = k & 1;
        float w = (cx ? c.x : 1.f - c.x) * (cy ? c.y : 1.f - c.y) * (cz ? c.z : 1.f - c.z);
        int vox = (((f0x + cx) << 5) + f0y + cy) * 32 + f0z + cz;
        const float4* ip = (const float4*)(gb + ((size_t)vox << 4));
        float4 a0 = ip[0], a1 = ip[1], a2 = ip[2], a3 = ip[3];
        acc[0]  = fmaf(w, a0.x, acc[0]);  acc[1]  = fmaf(w, a0.y, acc[1]);
        acc[2]  = fmaf(w, a0.z, acc[2]);  acc[3]  = fmaf(w, a0.w, acc[3]);
        acc[4]  = fmaf(w, a1.x, acc[4]);  acc[5]  = fmaf(w, a1.y, acc[5]);
        acc[6]  = fmaf(w, a1.z, acc[6]);  acc[7]  = fmaf(w, a1.w, acc[7]);
        acc[8]  = fmaf(w, a2.x, acc[8]);  acc[9]  = fmaf(w, a2.y, acc[9]);
        acc[10] = fmaf(w, a2.z, acc[10]); acc[11] = fmaf(w, a2.w, acc[11]);
        acc[12] = fmaf(w, a3.x, acc[12]); acc[13] = fmaf(w, a3.y, acc[13]);
        acc[14] = fmaf(w, a3.z, acc[14]); acc[15] = fmaf(w, a3.w, acc[15]);
    }
    #pragma unroll
    for (int f = 0; f < 16; ++f)
        out[(((size_t)(b * HF_ + h * F_ + f)) << 13) + n] = acc[f];
}

// ---------------- final AdaIN + ReLU (in place on d_out) --------------------
__global__ __launch_bounds__(256) void final_adain(
    float* __restrict__ out, const float* __restrict__ mean_o,
    const float* __restrict__ rsig_o, const float* __restrict__ ha) {
    size_t i = (size_t)blockIdx.x * 256 + threadIdx.x;
    int bc = (int)(i >> 13);
    int c = bc & 127, b = bc >> 7;
    float x = out[i];
    float xn = (x - mean_o[bc]) * rsig_o[bc];
    float y = fmaf(1.f + ha[b * 256 + c], xn, ha[b * 256 + 128 + c]);
    out[i] = fmaxf(y, 0.f);
}

extern "C" void kernel_launch(void* const* d_in, const int* in_sizes, int n_in,
                              void* d_out, int out_size, void* d_ws, size_t ws_size,
                              hipStream_t stream) {
    (void)in_sizes; (void)n_in; (void)out_size; (void)ws_size;
    const float* input   = (const float*)d_in[0];
    const float* style   = (const float*)d_in[1];
    const float* orig    = (const float*)d_in[2];
    const float* Wkv     = (const float*)d_in[3];
    const float* kw_w    = (const float*)d_in[4];
    const float* kw_b    = (const float*)d_in[5];
    const float* vw_w    = (const float*)d_in[6];
    const float* vw_b    = (const float*)d_in[7];
    const float* aw_w    = (const float*)d_in[8];
    const float* aw_b    = (const float*)d_in[9];
    const float* scale_p = (const float*)d_in[10];
    const float* Tw      = (const float*)d_in[11];
    const float* Tb      = (const float*)d_in[12];
    const float* conv_w  = (const float*)d_in[13];
    const float* conv_b  = (const float*)d_in[14];
    float* out = (float*)d_out;

    // -------- workspace layout (floats), ~139.2 MB total --------------------
    float* ws = (float*)d_ws;
    float* z        = ws;                        // 16,777,216  (64MB) splat lattice
    float* zc       = ws + 16777216;             // 16,777,216  (64MB) conv output
    float* coordbuf = ws + 2 * 16777216;         //  1,048,576  (float4 per point)
    float* wt       = coordbuf + 1048576;        //     55,296
    float* ha       = wt + 55296;                //      1,024
    float* mean_o   = ha + 1024;                 //        512
    float* rsig_o   = mean_o + 512;              //        512
    float* mean_kv  = rsig_o + 512;              //        608
    float* rsig_kv  = mean_kv + 608;             //        608
    float* hk       = rsig_kv + 608;             //        192
    float* hv       = hk + 192;                  //      1,024
    int*   counts   = (int*)(hv + 1024);         //      1,024 ints
    int*   base     = counts + 1024;             //      1,025 ints
    int*   cursor   = base + 1025;               //      1,024 ints
    unsigned short* recs = (unsigned short*)(cursor + 1024);  // 262,144 u16 (512KB)
    // aliased into zc (dead until conv3d runs):
    float* vbuf = zc;                            //  4,194,304 (16MB) AdaIN'd values
    float* kv   = zc + 4194304;                  //  4,980,736 (19MB)

    zero_bins<<<1, 1024, 0, stream>>>(counts);
    style_proj<<<B_, 256, 0, stream>>>(style, kw_w, kw_b, vw_w, vw_b, aw_w, aw_b, hk, hv, ha);
    wtrans_vm<<<216, 256, 0, stream>>>(conv_w, wt);
    kv_gemm<<<dim3(8, 8, B_), 256, 0, stream>>>(input, Wkv, kv);
    stats_kernel<<<B_ * CO_, 256, 0, stream>>>(kv, mean_kv, rsig_kv);
    point_prep<<<B_ * H_ * N_ / 256, 256, 0, stream>>>(
        kv, mean_kv, rsig_kv, hk, hv, orig, scale_p, Tw, Tb,
        (float4*)coordbuf, vbuf, counts);
    prefix_bins<<<1, 64, 0, stream>>>(counts, base, cursor);
    scatter_pts<<<B_ * H_ * N_ / 256, 256, 0, stream>>>((const float4*)coordbuf, cursor, recs);
    splat2<<<1024, 512, 0, stream>>>((const float4*)coordbuf, vbuf, base, recs, z);
    conv3d_vm<<<2048, 512, 0, stream>>>(z, wt, conv_b, zc);
    slice_vm<<<B_ * H_ * N_ / 256, 256, 0, stream>>>(zc, (const float4*)coordbuf, out);
    stats_kernel<<<B_ * HF_, 256, 0, stream>>>(out, mean_o, rsig_o);
    final_adain<<<B_ * HF_ * N_ / 256, 256, 0, stream>>>(out, mean_o, rsig_o, ha);
}

// Round 5
// 682.292 us; speedup vs baseline: 1.0193x; 1.0193x over previous
//
#include <hip/hip_runtime.h>
#include <hip/hip_bf16.h>
#include <math.h>

#define B_ 4
#define N_ 8192
#define MD_ 512
#define H_ 8
#define F_ 16
#define S_ 32
#define S3_ 32768
#define L_ 256
#define CO_ 152   // H*(F+3)
#define HF_ 128   // H*F
#define EPS_ 1e-5f

// ---------------- zero the 1024 bin counters --------------------------------
__global__ __launch_bounds__(1024) void zero_bins(int* __restrict__ counts) {
    counts[threadIdx.x] = 0;
}

// ---------------- style projections: h = style @ W.T + b --------------------
__global__ __launch_bounds__(256) void style_proj(
    const float* __restrict__ style,
    const float* __restrict__ kw_w, const float* __restrict__ kw_b,
    const float* __restrict__ vw_w, const float* __restrict__ vw_b,
    const float* __restrict__ aw_w, const float* __restrict__ aw_b,
    float* __restrict__ hk, float* __restrict__ hv, float* __restrict__ ha) {
    int b = blockIdx.x;
    const float* st = style + b * L_;
    for (int r = threadIdx.x; r < 48 + 256 + 256; r += 256) {
        const float* wrow; float bias; float* dst; int j;
        if (r < 48)       { j = r;       wrow = kw_w + j * L_; bias = kw_b[j]; dst = hk + b * 48; }
        else if (r < 304) { j = r - 48;  wrow = vw_w + j * L_; bias = vw_b[j]; dst = hv + b * 256; }
        else              { j = r - 304; wrow = aw_w + j * L_; bias = aw_b[j]; dst = ha + b * 256; }
        float acc = bias;
        for (int l = 0; l < L_; ++l) acc = fmaf(st[l], wrow[l], acc);
        dst[j] = acc;
    }
}

// ---------------- conv-weight transpose to [h][tap][ic][oc] -----------------
__global__ __launch_bounds__(256) void wtrans_vm(const float* __restrict__ cw, float* __restrict__ wt) {
    int i = blockIdx.x * 256 + threadIdx.x;   // 8*27*16*16 = 55296 total
    int oc  = i & 15;
    int ic  = (i >> 4) & 15;
    int tap = (i >> 8) % 27;
    int h   = (i >> 8) / 27;
    wt[i] = cw[(((h * 16 + oc) * 16 + ic) * 27) + tap];
}

// ---------------- kv = W_kv @ input  (per batch) ----------------------------
__global__ __launch_bounds__(256) void kv_gemm(
    const float* __restrict__ input, const float* __restrict__ Wkv, float* __restrict__ kv) {
    int b = blockIdx.z, rb = blockIdx.y;
    int n0 = blockIdx.x * 1024 + (threadIdx.x << 2);
    __shared__ float wlds[19 * MD_];
    for (int i = threadIdx.x; i < 19 * MD_ / 4; i += 256)
        ((float4*)wlds)[i] = ((const float4*)(Wkv + rb * 19 * MD_))[i];
    __syncthreads();
    float acc[19][4];
    #pragma unroll
    for (int i = 0; i < 19; ++i)
        for (int q = 0; q < 4; ++q) acc[i][q] = 0.f;
    const float* inb = input + (size_t)b * MD_ * N_ + n0;
    for (int c = 0; c < MD_; ++c) {
        float4 x = *(const float4*)(inb + (size_t)c * N_);
        #pragma unroll
        for (int i = 0; i < 19; ++i) {
            float w = wlds[i * MD_ + c];
            acc[i][0] = fmaf(w, x.x, acc[i][0]);
            acc[i][1] = fmaf(w, x.y, acc[i][1]);
            acc[i][2] = fmaf(w, x.z, acc[i][2]);
            acc[i][3] = fmaf(w, x.w, acc[i][3]);
        }
    }
    float* outb = kv + (size_t)b * CO_ * N_ + n0;
    #pragma unroll
    for (int i = 0; i < 19; ++i)
        *(float4*)(outb + (size_t)(rb * 19 + i) * N_) =
            make_float4(acc[i][0], acc[i][1], acc[i][2], acc[i][3]);
}

// ---------------- per-(b,channel) mean / rsig over N ------------------------
__global__ __launch_bounds__(256) void stats_kernel(
    const float* __restrict__ x, float* __restrict__ mean, float* __restrict__ rsig) {
    int bc = blockIdx.x;
    const float* p = x + (size_t)bc * N_;
    float s = 0.f, s2 = 0.f;
    for (int i = threadIdx.x; i < N_; i += 256) {
        float v = p[i]; s += v; s2 = fmaf(v, v, s2);
    }
    #pragma unroll
    for (int off = 32; off; off >>= 1) { s += __shfl_down(s, off); s2 += __shfl_down(s2, off); }
    __shared__ float ls[4], ls2[4];
    int wid = threadIdx.x >> 6;
    if ((threadIdx.x & 63) == 0) { ls[wid] = s; ls2[wid] = s2; }
    __syncthreads();
    if (threadIdx.x == 0) {
        float S = ls[0] + ls[1] + ls[2] + ls[3];
        float S2 = ls2[0] + ls2[1] + ls2[2] + ls2[3];
        float mu = S * (1.f / N_);
        float var = S2 * (1.f / N_) - mu * mu;
        mean[bc] = mu;
        rsig[bc] = rsqrtf(var + EPS_);
    }
}

// ---------------- point prep: AdaIN + transform + tanh + interp + count -----
__global__ __launch_bounds__(256) void point_prep(
    const float* __restrict__ kv, const float* __restrict__ mean_kv,
    const float* __restrict__ rsig_kv, const float* __restrict__ hk,
    const float* __restrict__ hv, const float* __restrict__ orig,
    const float* __restrict__ scale_p, const float* __restrict__ Tw,
    const float* __restrict__ Tb,
    float4* __restrict__ coordbuf, float* __restrict__ vbuf,
    int* __restrict__ counts) {
    int p = blockIdx.x * 256 + threadIdx.x;
    int n = p & (N_ - 1);
    int bh = p >> 13;
    int h = bh & 7, b = bh >> 3;
    float scl = scale_p[0];

    float pt[3];
    #pragma unroll
    for (int j = 0; j < 3; ++j) {
        int c = h * 3 + j;
        float x  = kv[((size_t)(b * CO_ + c)) * N_ + n];
        float xn = (x - mean_kv[b * CO_ + c]) * rsig_kv[b * CO_ + c];
        float kr = fmaf(1.f + hk[b * 48 + c], xn, hk[b * 48 + 24 + c]);
        pt[j] = fmaf(scl, kr, orig[((size_t)(b * 3 + j)) * N_ + n]);
    }
    int f0[3]; float tt[3];
    #pragma unroll
    for (int i = 0; i < 3; ++i) {
        float key = Tb[h * 3 + i];
        #pragma unroll
        for (int j = 0; j < 3; ++j) key = fmaf(Tw[(h * 3 + i) * 3 + j], pt[j], key);
        float lat = tanhf(key);
        float g = (lat + 1.f) * 0.5f * (float)(S_ - 1);
        float ff = floorf(g);
        ff = fminf(fmaxf(ff, 0.f), 30.f);
        f0[i] = (int)ff;
        tt[i] = fminf(fmaxf(g - ff, 0.f), 1.f);
    }
    coordbuf[p] = make_float4(tt[0], tt[1], tt[2],
                              __int_as_float(f0[0] | (f0[1] << 5) | (f0[2] << 10)));
    atomicAdd(&counts[(bh << 5) + f0[0]], 1);
    float vf[16];
    #pragma unroll
    for (int f = 0; f < F_; ++f) {
        int c = 24 + h * F_ + f;
        float x  = kv[((size_t)(b * CO_ + c)) * N_ + n];
        float xn = (x - mean_kv[b * CO_ + c]) * rsig_kv[b * CO_ + c];
        int cv = h * F_ + f;
        vf[f] = fmaf(1.f + hv[b * 256 + cv], xn, hv[b * 256 + 128 + cv]);
    }
    float4* vb = (float4*)(vbuf + (size_t)p * 16);
    #pragma unroll
    for (int q = 0; q < 4; ++q)
        vb[q] = make_float4(vf[q * 4], vf[q * 4 + 1], vf[q * 4 + 2], vf[q * 4 + 3]);
}

// ---------------- exclusive prefix over the 1024 bins (one wave) ------------
__global__ __launch_bounds__(64) void prefix_bins(
    const int* __restrict__ counts, int* __restrict__ base, int* __restrict__ cursor) {
    int lane = threadIdx.x;
    int local[16], sum = 0;
    #pragma unroll
    for (int i = 0; i < 16; ++i) { local[i] = sum; sum += counts[lane * 16 + i]; }
    int incl = sum;
    #pragma unroll
    for (int off = 1; off < 64; off <<= 1) {
        int v = __shfl_up(incl, off);
        if (lane >= off) incl += v;
    }
    int excl = incl - sum;
    #pragma unroll
    for (int i = 0; i < 16; ++i) {
        int bse = excl + local[i];
        base[lane * 16 + i] = bse;
        cursor[lane * 16 + i] = bse;
    }
    if (lane == 63) base[1024] = excl + sum;
}

// ---------------- scatter point indices into bins ---------------------------
__global__ __launch_bounds__(256) void scatter_pts(
    const float4* __restrict__ coordbuf, int* __restrict__ cursor,
    unsigned short* __restrict__ recs) {
    int p = blockIdx.x * 256 + threadIdx.x;
    int bh = p >> 13;
    int pk = __float_as_int(((const float*)coordbuf)[(size_t)p * 4 + 3]);
    int f0x = pk & 31;
    int slot = atomicAdd(&cursor[(bh << 5) + f0x], 1);
    recs[slot] = (unsigned short)(p & (N_ - 1));
}

// ---------------- splat, binned + lane-transposed (point x feature) ---------
// block -> one x-plane of one (b,h) lattice. 512 threads = 32 points x 16 f.
// Same-address LDS-atomic collisions capped at 4-way (4 points per wave);
// each point-group's 16 lanes hit 16 distinct banks (addr = vox*16+(f+vox)&15).
__global__ __launch_bounds__(512) void splat2(
    const float4* __restrict__ coordbuf, const float* __restrict__ vbuf,
    const int* __restrict__ base, const unsigned short* __restrict__ recs,
    float* __restrict__ z) {
    __shared__ float tile[16384];             // 32*32 voxels * 16 f, swizzled
    int logical = (blockIdx.x & 7) * 128 + (blockIdx.x >> 3);  // XCD swizzle (1024 = 8*128)
    int bh = logical >> 5;
    int x0 = logical & 31;
    for (int i = threadIdx.x; i < 16384; i += 512) tile[i] = 0.f;
    __syncthreads();
    int bin0 = (bh << 5) + x0;
    int s0 = base[bin0], len0 = base[bin0 + 1] - s0;
    int s1 = 0, len1 = 0;
    if (x0 > 0) { s1 = base[bin0 - 1]; len1 = s0 - s1; }
    int total = len0 + len1;
    const float4* cb = coordbuf + (size_t)bh * N_;
    const float* vb = vbuf + ((size_t)bh * N_) * 16;
    int psub = threadIdx.x >> 4;              // 0..31 point slot
    int f    = threadIdx.x & 15;              // feature
    for (int t0 = 0; t0 < total; t0 += 32) {
        int tp = t0 + psub;
        if (tp < total) {
            int cx, n;
            if (tp < len0) { n = recs[s0 + tp]; cx = 0; }
            else           { n = recs[s1 + (tp - len0)]; cx = 1; }
            float4 c = cb[n];                 // broadcast within 16-lane group
            int pk = __float_as_int(c.w);
            float wx = cx ? c.x : 1.f - c.x;
            int f0y = (pk >> 5) & 31, f0z = (pk >> 10) & 31;
            float vfv = vb[(size_t)n * 16 + f];   // coalesced 64B per group
            #pragma unroll
            for (int cy = 0; cy < 2; ++cy) {
                float wxy = wx * (cy ? c.y : 1.f - c.y);
                #pragma unroll
                for (int cz = 0; cz < 2; ++cz) {
                    float w = wxy * (cz ? c.z : 1.f - c.z);
                    int vox = ((f0y + cy) << 5) + f0z + cz;
                    unsafeAtomicAdd(&tile[(vox << 4) + ((f + vox) & 15)], vfv * w);
                }
            }
        }
    }
    __syncthreads();
    float* zb = z + (((size_t)bh * S3_ + (x0 << 10)) << 4);
    for (int i = threadIdx.x; i < 16384; i += 512) {
        int vox = i >> 4, ff = i & 15;
        zb[i] = tile[(vox << 4) + ((ff + vox) & 15)];
    }
}

// ---------------- grouped 3x3x3 conv, voxel-major, no-spill -----------------
__global__ __launch_bounds__(512) void conv3d_vm(
    const float* __restrict__ z, const float* __restrict__ wt,
    const float* __restrict__ cbias, float* __restrict__ zc) {
    int logical = (blockIdx.x & 7) * 256 + (blockIdx.x >> 3);  // 2048 = 8*256
    int bh = logical >> 6;
    int part = logical & 63;
    int h = bh & 7;
    int vv = part * 512 + threadIdx.x;
    int xc = vv >> 10, yc = (vv >> 5) & 31, zd = vv & 31;
    const float* inb = z + ((size_t)bh << 19);   // 32768*16
    const float* wg = wt + h * 6912;
    float acc[16];
    #pragma unroll
    for (int o = 0; o < 16; ++o) acc[o] = 0.f;
    #pragma unroll 1
    for (int tap = 0; tap < 27; ++tap) {
        int dx = tap / 9, r9 = tap - dx * 9;
        int dy = r9 / 3, dz = r9 - dy * 3;
        int xx = xc + dx - 1, yy = yc + dy - 1, zz = zd + dz - 1;
        bool ok = (xx >= 0) & (xx <= 31) & (yy >= 0) & (yy <= 31) & (zz >= 0) & (zz <= 31);
        const float4* ip = (const float4*)(inb + ((size_t)((((xx << 5) + yy) << 5) + zz) << 4));
        float4 x0, x1, x2, x3;
        if (ok) { x0 = ip[0]; x1 = ip[1]; x2 = ip[2]; x3 = ip[3]; }
        else {
            x0 = make_float4(0.f, 0.f, 0.f, 0.f); x1 = x0; x2 = x0; x3 = x0;
        }
        float xin[16] = {x0.x, x0.y, x0.z, x0.w, x1.x, x1.y, x1.z, x1.w,
                         x2.x, x2.y, x2.z, x2.w, x3.x, x3.y, x3.z, x3.w};
        const float4* wp = (const float4*)(wg + tap * 256);
        #pragma unroll
        for (int ic = 0; ic < 16; ++ic) {
            float xv = xin[ic];
            float4 w0 = wp[ic * 4 + 0], w1 = wp[ic * 4 + 1];
            float4 w2 = wp[ic * 4 + 2], w3 = wp[ic * 4 + 3];
            acc[0]  = fmaf(xv, w0.x, acc[0]);  acc[1]  = fmaf(xv, w0.y, acc[1]);
            acc[2]  = fmaf(xv, w0.z, acc[2]);  acc[3]  = fmaf(xv, w0.w, acc[3]);
            acc[4]  = fmaf(xv, w1.x, acc[4]);  acc[5]  = fmaf(xv, w1.y, acc[5]);
            acc[6]  = fmaf(xv, w1.z, acc[6]);  acc[7]  = fmaf(xv, w1.w, acc[7]);
            acc[8]  = fmaf(xv, w2.x, acc[8]);  acc[9]  = fmaf(xv, w2.y, acc[9]);
            acc[10] = fmaf(xv, w2.z, acc[10]); acc[11] = fmaf(xv, w2.w, acc[11]);
            acc[12] = fmaf(xv, w3.x, acc[12]); acc[13] = fmaf(xv, w3.y, acc[13]);
            acc[14] = fmaf(xv, w3.z, acc[14]); acc[15] = fmaf(xv, w3.w, acc[15]);
        }
    }
    float* ob = zc + ((size_t)bh << 19) + ((size_t)vv << 4);
    const float* bp = cbias + h * 16;
    #pragma unroll
    for (int q = 0; q < 4; ++q)
        ((float4*)ob)[q] = make_float4(acc[q*4] + bp[q*4], acc[q*4+1] + bp[q*4+1],
                                       acc[q*4+2] + bp[q*4+2], acc[q*4+3] + bp[q*4+3]);
}

// ---------------- slice: weighted gather back to points ---------------------
__global__ __launch_bounds__(256) void slice_vm(
    const float* __restrict__ zc, const float4* __restrict__ coordbuf,
    float* __restrict__ out) {
    int p = blockIdx.x * 256 + threadIdx.x;
    int n = p & (N_ - 1);
    int bh = p >> 13;
    int h = bh & 7, b = bh >> 3;
    float4 c = coordbuf[p];
    int pk = __float_as_int(c.w);
    int f0x = pk & 31, f0y = (pk >> 5) & 31, f0z = (pk >> 10) & 31;
    const float* gb = zc + ((size_t)bh << 19);
    float acc[16];
    #pragma unroll
    for (int f = 0; f < 16; ++f) acc[f] = 0.f;
    #pragma unroll 1
    for (int k = 0; k < 8; ++k) {
        int cx = (k >> 2) & 1, cy = (k >> 1) & 1, cz = k & 1;
        float w = (cx ? c.x : 1.f - c.x) * (cy ? c.y : 1.f - c.y) * (cz ? c.z : 1.f - c.z);
        int vox = (((f0x + cx) << 5) + f0y + cy) * 32 + f0z + cz;
        const float4* ip = (const float4*)(gb + ((size_t)vox << 4));
        float4 a0 = ip[0], a1 = ip[1], a2 = ip[2], a3 = ip[3];
        acc[0]  = fmaf(w, a0.x, acc[0]);  acc[1]  = fmaf(w, a0.y, acc[1]);
        acc[2]  = fmaf(w, a0.z, acc[2]);  acc[3]  = fmaf(w, a0.w, acc[3]);
        acc[4]  = fmaf(w, a1.x, acc[4]);  acc[5]  = fmaf(w, a1.y, acc[5]);
        acc[6]  = fmaf(w, a1.z, acc[6]);  acc[7]  = fmaf(w, a1.w, acc[7]);
        acc[8]  = fmaf(w, a2.x, acc[8]);  acc[9]  = fmaf(w, a2.y, acc[9]);
        acc[10] = fmaf(w, a2.z, acc[10]); acc[11] = fmaf(w, a2.w, acc[11]);
        acc[12] = fmaf(w, a3.x, acc[12]); acc[13] = fmaf(w, a3.y, acc[13]);
        acc[14] = fmaf(w, a3.z, acc[14]); acc[15] = fmaf(w, a3.w, acc[15]);
    }
    #pragma unroll
    for (int f = 0; f < 16; ++f)
        out[(((size_t)(b * HF_ + h * F_ + f)) << 13) + n] = acc[f];
}

// ---------------- final AdaIN + ReLU (in place on d_out) --------------------
__global__ __launch_bounds__(256) void final_adain(
    float* __restrict__ out, const float* __restrict__ mean_o,
    const float* __restrict__ rsig_o, const float* __restrict__ ha) {
    size_t i = (size_t)blockIdx.x * 256 + threadIdx.x;
    int bc = (int)(i >> 13);
    int c = bc & 127, b = bc >> 7;
    float x = out[i];
    float xn = (x - mean_o[bc]) * rsig_o[bc];
    float y = fmaf(1.f + ha[b * 256 + c], xn, ha[b * 256 + 128 + c]);
    out[i] = fmaxf(y, 0.f);
}

extern "C" void kernel_launch(void* const* d_in, const int* in_sizes, int n_in,
                              void* d_out, int out_size, void* d_ws, size_t ws_size,
                              hipStream_t stream) {
    (void)in_sizes; (void)n_in; (void)out_size; (void)ws_size;
    const float* input   = (const float*)d_in[0];
    const float* style   = (const float*)d_in[1];
    const float* orig    = (const float*)d_in[2];
    const float* Wkv     = (const float*)d_in[3];
    const float* kw_w    = (const float*)d_in[4];
    const float* kw_b    = (const float*)d_in[5];
    const float* vw_w    = (const float*)d_in[6];
    const float* vw_b    = (const float*)d_in[7];
    const float* aw_w    = (const float*)d_in[8];
    const float* aw_b    = (const float*)d_in[9];
    const float* scale_p = (const float*)d_in[10];
    const float* Tw      = (const float*)d_in[11];
    const float* Tb      = (const float*)d_in[12];
    const float* conv_w  = (const float*)d_in[13];
    const float* conv_b  = (const float*)d_in[14];
    float* out = (float*)d_out;

    // -------- workspace layout (floats), ~139.2 MB total --------------------
    float* ws = (float*)d_ws;
    float* z        = ws;                        // 16,777,216  (64MB) splat lattice
    float* zc       = ws + 16777216;             // 16,777,216  (64MB) conv output
    float* coordbuf = ws + 2 * 16777216;         //  1,048,576  (float4 per point)
    float* wt       = coordbuf + 1048576;        //     55,296
    float* ha       = wt + 55296;                //      1,024
    float* mean_o   = ha + 1024;                 //        512
    float* rsig_o   = mean_o + 512;              //        512
    float* mean_kv  = rsig_o + 512;              //        608
    float* rsig_kv  = mean_kv + 608;             //        608
    float* hk       = rsig_kv + 608;             //        192
    float* hv       = hk + 192;                  //      1,024
    int*   counts   = (int*)(hv + 1024);         //      1,024 ints
    int*   base     = counts + 1024;             //      1,025 ints
    int*   cursor   = base + 1025;               //      1,024 ints
    unsigned short* recs = (unsigned short*)(cursor + 1024);  // 262,144 u16 (512KB)
    // aliased into zc (dead until conv3d runs):
    float* vbuf = zc;                            //  4,194,304 (16MB) AdaIN'd values
    float* kv   = zc + 4194304;                  //  4,980,736 (19MB)

    zero_bins<<<1, 1024, 0, stream>>>(counts);
    style_proj<<<B_, 256, 0, stream>>>(style, kw_w, kw_b, vw_w, vw_b, aw_w, aw_b, hk, hv, ha);
    wtrans_vm<<<216, 256, 0, stream>>>(conv_w, wt);
    kv_gemm<<<dim3(8, 8, B_), 256, 0, stream>>>(input, Wkv, kv);
    stats_kernel<<<B_ * CO_, 256, 0, stream>>>(kv, mean_kv, rsig_kv);
    point_prep<<<B_ * H_ * N_ / 256, 256, 0, stream>>>(
        kv, mean_kv, rsig_kv, hk, hv, orig, scale_p, Tw, Tb,
        (float4*)coordbuf, vbuf, counts);
    prefix_bins<<<1, 64, 0, stream>>>(counts, base, cursor);
    scatter_pts<<<B_ * H_ * N_ / 256, 256, 0, stream>>>((const float4*)coordbuf, cursor, recs);
    splat2<<<1024, 512, 0, stream>>>((const float4*)coordbuf, vbuf, base, recs, z);
    conv3d_vm<<<2048, 512, 0, stream>>>(z, wt, conv_b, zc);
    slice_vm<<<B_ * H_ * N_ / 256, 256, 0, stream>>>(zc, (const float4*)coordbuf, out);
    stats_kernel<<<B_ * HF_, 256, 0, stream>>>(out, mean_o, rsig_o);
    final_adain<<<B_ * HF_ * N_ / 256, 256, 0, stream>>>(out, mean_o, rsig_o, ha);
}

// Round 6
// 521.890 us; speedup vs baseline: 1.3325x; 1.3073x over previous
//
#include <hip/hip_runtime.h>
#include <hip/hip_bf16.h>
#include <math.h>

#define B_ 4
#define N_ 8192
#define MD_ 512
#define H_ 8
#define F_ 16
#define S_ 32
#define S3_ 32768
#define L_ 256
#define CO_ 152   // H*(F+3)
#define HF_ 128   // H*F
#define EPS_ 1e-5f
#define CHUNK_ 2048

// ---------------- zero the 1024 bin counters --------------------------------
__global__ __launch_bounds__(1024) void zero_bins(int* __restrict__ counts) {
    counts[threadIdx.x] = 0;
}

// ---------------- style projections: h = style @ W.T + b --------------------
__global__ __launch_bounds__(256) void style_proj(
    const float* __restrict__ style,
    const float* __restrict__ kw_w, const float* __restrict__ kw_b,
    const float* __restrict__ vw_w, const float* __restrict__ vw_b,
    const float* __restrict__ aw_w, const float* __restrict__ aw_b,
    float* __restrict__ hk, float* __restrict__ hv, float* __restrict__ ha) {
    int b = blockIdx.x;
    const float* st = style + b * L_;
    for (int r = threadIdx.x; r < 48 + 256 + 256; r += 256) {
        const float* wrow; float bias; float* dst; int j;
        if (r < 48)       { j = r;       wrow = kw_w + j * L_; bias = kw_b[j]; dst = hk + b * 48; }
        else if (r < 304) { j = r - 48;  wrow = vw_w + j * L_; bias = vw_b[j]; dst = hv + b * 256; }
        else              { j = r - 304; wrow = aw_w + j * L_; bias = aw_b[j]; dst = ha + b * 256; }
        float acc = bias;
        for (int l = 0; l < L_; ++l) acc = fmaf(st[l], wrow[l], acc);
        dst[j] = acc;
    }
}

// ---------------- conv-weight transpose to [h][tap][ic][oc] -----------------
__global__ __launch_bounds__(256) void wtrans_vm(const float* __restrict__ cw, float* __restrict__ wt) {
    int i = blockIdx.x * 256 + threadIdx.x;   // 8*27*16*16 = 55296 total
    int oc  = i & 15;
    int ic  = (i >> 4) & 15;
    int tap = (i >> 8) % 27;
    int h   = (i >> 8) / 27;
    wt[i] = cw[(((h * 16 + oc) * 16 + ic) * 27) + tap];
}

// ---------------- kv = W_kv @ input  (per batch) ----------------------------
__global__ __launch_bounds__(256) void kv_gemm(
    const float* __restrict__ input, const float* __restrict__ Wkv, float* __restrict__ kv) {
    int b = blockIdx.z, rb = blockIdx.y;
    int n0 = blockIdx.x * 1024 + (threadIdx.x << 2);
    __shared__ float wlds[19 * MD_];
    for (int i = threadIdx.x; i < 19 * MD_ / 4; i += 256)
        ((float4*)wlds)[i] = ((const float4*)(Wkv + rb * 19 * MD_))[i];
    __syncthreads();
    float acc[19][4];
    #pragma unroll
    for (int i = 0; i < 19; ++i)
        for (int q = 0; q < 4; ++q) acc[i][q] = 0.f;
    const float* inb = input + (size_t)b * MD_ * N_ + n0;
    for (int c = 0; c < MD_; ++c) {
        float4 x = *(const float4*)(inb + (size_t)c * N_);
        #pragma unroll
        for (int i = 0; i < 19; ++i) {
            float w = wlds[i * MD_ + c];
            acc[i][0] = fmaf(w, x.x, acc[i][0]);
            acc[i][1] = fmaf(w, x.y, acc[i][1]);
            acc[i][2] = fmaf(w, x.z, acc[i][2]);
            acc[i][3] = fmaf(w, x.w, acc[i][3]);
        }
    }
    float* outb = kv + (size_t)b * CO_ * N_ + n0;
    #pragma unroll
    for (int i = 0; i < 19; ++i)
        *(float4*)(outb + (size_t)(rb * 19 + i) * N_) =
            make_float4(acc[i][0], acc[i][1], acc[i][2], acc[i][3]);
}

// ---------------- per-(b,channel) mean / rsig over N ------------------------
__global__ __launch_bounds__(256) void stats_kernel(
    const float* __restrict__ x, float* __restrict__ mean, float* __restrict__ rsig) {
    int bc = blockIdx.x;
    const float* p = x + (size_t)bc * N_;
    float s = 0.f, s2 = 0.f;
    for (int i = threadIdx.x; i < N_; i += 256) {
        float v = p[i]; s += v; s2 = fmaf(v, v, s2);
    }
    #pragma unroll
    for (int off = 32; off; off >>= 1) { s += __shfl_down(s, off); s2 += __shfl_down(s2, off); }
    __shared__ float ls[4], ls2[4];
    int wid = threadIdx.x >> 6;
    if ((threadIdx.x & 63) == 0) { ls[wid] = s; ls2[wid] = s2; }
    __syncthreads();
    if (threadIdx.x == 0) {
        float S = ls[0] + ls[1] + ls[2] + ls[3];
        float S2 = ls2[0] + ls2[1] + ls2[2] + ls2[3];
        float mu = S * (1.f / N_);
        float var = S2 * (1.f / N_) - mu * mu;
        mean[bc] = mu;
        rsig[bc] = rsqrtf(var + EPS_);
    }
}

// ---------------- point prep: AdaIN + transform + tanh + interp + count -----
__global__ __launch_bounds__(256) void point_prep(
    const float* __restrict__ kv, const float* __restrict__ mean_kv,
    const float* __restrict__ rsig_kv, const float* __restrict__ hk,
    const float* __restrict__ hv, const float* __restrict__ orig,
    const float* __restrict__ scale_p, const float* __restrict__ Tw,
    const float* __restrict__ Tb,
    float4* __restrict__ coordbuf, float* __restrict__ vbuf,
    int* __restrict__ counts) {
    int p = blockIdx.x * 256 + threadIdx.x;
    int n = p & (N_ - 1);
    int bh = p >> 13;
    int h = bh & 7, b = bh >> 3;
    float scl = scale_p[0];

    float pt[3];
    #pragma unroll
    for (int j = 0; j < 3; ++j) {
        int c = h * 3 + j;
        float x  = kv[((size_t)(b * CO_ + c)) * N_ + n];
        float xn = (x - mean_kv[b * CO_ + c]) * rsig_kv[b * CO_ + c];
        float kr = fmaf(1.f + hk[b * 48 + c], xn, hk[b * 48 + 24 + c]);
        pt[j] = fmaf(scl, kr, orig[((size_t)(b * 3 + j)) * N_ + n]);
    }
    int f0[3]; float tt[3];
    #pragma unroll
    for (int i = 0; i < 3; ++i) {
        float key = Tb[h * 3 + i];
        #pragma unroll
        for (int j = 0; j < 3; ++j) key = fmaf(Tw[(h * 3 + i) * 3 + j], pt[j], key);
        float lat = tanhf(key);
        float g = (lat + 1.f) * 0.5f * (float)(S_ - 1);
        float ff = floorf(g);
        ff = fminf(fmaxf(ff, 0.f), 30.f);
        f0[i] = (int)ff;
        tt[i] = fminf(fmaxf(g - ff, 0.f), 1.f);
    }
    coordbuf[p] = make_float4(tt[0], tt[1], tt[2],
                              __int_as_float(f0[0] | (f0[1] << 5) | (f0[2] << 10)));
    atomicAdd(&counts[(bh << 5) + f0[0]], 1);
    float vf[16];
    #pragma unroll
    for (int f = 0; f < F_; ++f) {
        int c = 24 + h * F_ + f;
        float x  = kv[((size_t)(b * CO_ + c)) * N_ + n];
        float xn = (x - mean_kv[b * CO_ + c]) * rsig_kv[b * CO_ + c];
        int cv = h * F_ + f;
        vf[f] = fmaf(1.f + hv[b * 256 + cv], xn, hv[b * 256 + 128 + cv]);
    }
    float4* vb = (float4*)(vbuf + (size_t)p * 16);
    #pragma unroll
    for (int q = 0; q < 4; ++q)
        vb[q] = make_float4(vf[q * 4], vf[q * 4 + 1], vf[q * 4 + 2], vf[q * 4 + 3]);
}

// ---------------- exclusive prefix over the 1024 bins (one wave) ------------
__global__ __launch_bounds__(64) void prefix_bins(
    const int* __restrict__ counts, int* __restrict__ base, int* __restrict__ cursor) {
    int lane = threadIdx.x;
    int local[16], sum = 0;
    #pragma unroll
    for (int i = 0; i < 16; ++i) { local[i] = sum; sum += counts[lane * 16 + i]; }
    int incl = sum;
    #pragma unroll
    for (int off = 1; off < 64; off <<= 1) {
        int v = __shfl_up(incl, off);
        if (lane >= off) incl += v;
    }
    int excl = incl - sum;
    #pragma unroll
    for (int i = 0; i < 16; ++i) {
        int bse = excl + local[i];
        base[lane * 16 + i] = bse;
        cursor[lane * 16 + i] = bse;
    }
    if (lane == 63) base[1024] = excl + sum;
}

// ---------------- scatter point indices into bins ---------------------------
__global__ __launch_bounds__(256) void scatter_pts(
    const float4* __restrict__ coordbuf, int* __restrict__ cursor,
    unsigned short* __restrict__ recs) {
    int p = blockIdx.x * 256 + threadIdx.x;
    int bh = p >> 13;
    int pk = __float_as_int(((const float*)coordbuf)[(size_t)p * 4 + 3]);
    int f0x = pk & 31;
    int slot = atomicAdd(&cursor[(bh << 5) + f0x], 1);
    recs[slot] = (unsigned short)(p & (N_ - 1));
}

// ---------------- splat3: in-block sub-sort by (y,z), then register gather --
// block -> one x-plane of one (b,h); 1024 threads, thread = voxel (y,z) owning
// its 16 features in registers. NO per-feature atomics: points are counting-
// sorted into 1024 (y,z) sub-bins in LDS, each thread gathers from its 4
// neighbor bins (f0y in {y-1,y} x f0z in {z-1,z}) with plain FMAs.
__global__ __launch_bounds__(1024) void splat3(
    const float4* __restrict__ coordbuf, const float* __restrict__ vbuf,
    const int* __restrict__ base, const unsigned short* __restrict__ recs,
    float* __restrict__ z) {
    __shared__ int s_cnt[1024];
    __shared__ int s_start[1024];
    __shared__ int s_cur[1024];
    __shared__ unsigned int s_pts[CHUNK_];
    __shared__ unsigned int s_sorted[CHUNK_];
    __shared__ int s_wavesum[16];
    int logical = (blockIdx.x & 7) * 128 + (blockIdx.x >> 3);  // XCD swizzle
    int bh = logical >> 5;
    int x0 = logical & 31;
    int tid = threadIdx.x;
    int y = tid >> 5, zc = tid & 31;
    int bin0 = (bh << 5) + x0;
    int s0 = base[bin0], len0 = base[bin0 + 1] - s0;
    int s1 = 0, len1 = 0;
    if (x0 > 0) { s1 = base[bin0 - 1]; len1 = s0 - s1; }
    int total = len0 + len1;
    const float4* cb = coordbuf + (size_t)bh * N_;
    const float* vb = vbuf + ((size_t)bh * N_) * 16;
    float acc[16];
    #pragma unroll
    for (int i = 0; i < 16; ++i) acc[i] = 0.f;

    for (int c0 = 0; c0 < total; c0 += CHUNK_) {
        int cl = min(CHUNK_, total - c0);
        s_cnt[tid] = 0;
        __syncthreads();
        // ---- stage + count
        for (int t = tid; t < cl; t += 1024) {
            int tp = c0 + t, n, cx;
            if (tp < len0) { n = recs[s0 + tp]; cx = 0; }
            else           { n = recs[s1 + (tp - len0)]; cx = 1; }
            int pk = __float_as_int(cb[n].w);
            int sb = (((pk >> 5) & 31) << 5) | ((pk >> 10) & 31);
            s_pts[t] = ((unsigned)sb << 16) | ((unsigned)cx << 14) | (unsigned)n;
            atomicAdd(&s_cnt[sb], 1);
        }
        __syncthreads();
        // ---- block-wide exclusive prefix over 1024 bins
        int v = s_cnt[tid];
        int incl = v;
        #pragma unroll
        for (int off = 1; off < 64; off <<= 1) {
            int u = __shfl_up(incl, off);
            if ((tid & 63) >= off) incl += u;
        }
        int wid = tid >> 6;
        if ((tid & 63) == 63) s_wavesum[wid] = incl;
        __syncthreads();
        if (tid < 16) {
            int wv = s_wavesum[tid];
            int wincl = wv;
            #pragma unroll
            for (int off = 1; off < 16; off <<= 1) {
                int u = __shfl_up(wincl, off);
                if (tid >= off) wincl += u;
            }
            s_wavesum[tid] = wincl - wv;   // exclusive wave offset
        }
        __syncthreads();
        int excl = incl - v + s_wavesum[wid];
        s_start[tid] = excl;
        s_cur[tid] = excl;
        __syncthreads();
        // ---- scatter into sorted order
        for (int t = tid; t < cl; t += 1024) {
            unsigned rec = s_pts[t];
            int slot = atomicAdd(&s_cur[rec >> 16], 1);
            s_sorted[slot] = rec;
        }
        __syncthreads();
        // ---- gather from 4 neighbor sub-bins into register accumulators
        #pragma unroll
        for (int sy = 0; sy < 2; ++sy) {
            int yy = y - sy;
            if (yy < 0) continue;
            #pragma unroll
            for (int sz = 0; sz < 2; ++sz) {
                int zz = zc - sz;
                if (zz < 0) continue;
                int sb = (yy << 5) | zz;
                int s = s_start[sb], e = s + s_cnt[sb];
                for (int i = s; i < e; ++i) {
                    unsigned rec = s_sorted[i];
                    int n = rec & 0x3FFF;
                    int cx = (rec >> 14) & 1;
                    float4 c = cb[n];
                    float wx = cx ? c.x : 1.f - c.x;
                    float wy = sy ? c.y : 1.f - c.y;
                    float wz = sz ? c.z : 1.f - c.z;
                    float w = wx * wy * wz;
                    const float4* vp = (const float4*)(vb + (size_t)n * 16);
                    float4 a0 = vp[0], a1 = vp[1], a2 = vp[2], a3 = vp[3];
                    acc[0]  = fmaf(w, a0.x, acc[0]);  acc[1]  = fmaf(w, a0.y, acc[1]);
                    acc[2]  = fmaf(w, a0.z, acc[2]);  acc[3]  = fmaf(w, a0.w, acc[3]);
                    acc[4]  = fmaf(w, a1.x, acc[4]);  acc[5]  = fmaf(w, a1.y, acc[5]);
                    acc[6]  = fmaf(w, a1.z, acc[6]);  acc[7]  = fmaf(w, a1.w, acc[7]);
                    acc[8]  = fmaf(w, a2.x, acc[8]);  acc[9]  = fmaf(w, a2.y, acc[9]);
                    acc[10] = fmaf(w, a2.z, acc[10]); acc[11] = fmaf(w, a2.w, acc[11]);
                    acc[12] = fmaf(w, a3.x, acc[12]); acc[13] = fmaf(w, a3.y, acc[13]);
                    acc[14] = fmaf(w, a3.z, acc[14]); acc[15] = fmaf(w, a3.w, acc[15]);
                }
            }
        }
        __syncthreads();   // protect s_* before next chunk
    }
    // ---- coalesced write: thread (y,z) -> z[bh][x0*1024 + tid][0..15]
    float* zb = z + (((size_t)bh * S3_ + (x0 << 10)) << 4) + ((size_t)tid << 4);
    #pragma unroll
    for (int q = 0; q < 4; ++q)
        ((float4*)zb)[q] = make_float4(acc[q * 4], acc[q * 4 + 1],
                                       acc[q * 4 + 2], acc[q * 4 + 3]);
}

// ---------------- grouped 3x3x3 conv, voxel-major, no-spill -----------------
__global__ __launch_bounds__(512) void conv3d_vm(
    const float* __restrict__ z, const float* __restrict__ wt,
    const float* __restrict__ cbias, float* __restrict__ zc) {
    int logical = (blockIdx.x & 7) * 256 + (blockIdx.x >> 3);  // 2048 = 8*256
    int bh = logical >> 6;
    int part = logical & 63;
    int h = bh & 7;
    int vv = part * 512 + threadIdx.x;
    int xc = vv >> 10, yc = (vv >> 5) & 31, zd = vv & 31;
    const float* inb = z + ((size_t)bh << 19);   // 32768*16
    const float* wg = wt + h * 6912;
    float acc[16];
    #pragma unroll
    for (int o = 0; o < 16; ++o) acc[o] = 0.f;
    #pragma unroll 1
    for (int tap = 0; tap < 27; ++tap) {
        int dx = tap / 9, r9 = tap - dx * 9;
        int dy = r9 / 3, dz = r9 - dy * 3;
        int xx = xc + dx - 1, yy = yc + dy - 1, zz = zd + dz - 1;
        bool ok = (xx >= 0) & (xx <= 31) & (yy >= 0) & (yy <= 31) & (zz >= 0) & (zz <= 31);
        const float4* ip = (const float4*)(inb + ((size_t)((((xx << 5) + yy) << 5) + zz) << 4));
        float4 x0, x1, x2, x3;
        if (ok) { x0 = ip[0]; x1 = ip[1]; x2 = ip[2]; x3 = ip[3]; }
        else {
            x0 = make_float4(0.f, 0.f, 0.f, 0.f); x1 = x0; x2 = x0; x3 = x0;
        }
        float xin[16] = {x0.x, x0.y, x0.z, x0.w, x1.x, x1.y, x1.z, x1.w,
                         x2.x, x2.y, x2.z, x2.w, x3.x, x3.y, x3.z, x3.w};
        const float4* wp = (const float4*)(wg + tap * 256);
        #pragma unroll
        for (int ic = 0; ic < 16; ++ic) {
            float xv = xin[ic];
            float4 w0 = wp[ic * 4 + 0], w1 = wp[ic * 4 + 1];
            float4 w2 = wp[ic * 4 + 2], w3 = wp[ic * 4 + 3];
            acc[0]  = fmaf(xv, w0.x, acc[0]);  acc[1]  = fmaf(xv, w0.y, acc[1]);
            acc[2]  = fmaf(xv, w0.z, acc[2]);  acc[3]  = fmaf(xv, w0.w, acc[3]);
            acc[4]  = fmaf(xv, w1.x, acc[4]);  acc[5]  = fmaf(xv, w1.y, acc[5]);
            acc[6]  = fmaf(xv, w1.z, acc[6]);  acc[7]  = fmaf(xv, w1.w, acc[7]);
            acc[8]  = fmaf(xv, w2.x, acc[8]);  acc[9]  = fmaf(xv, w2.y, acc[9]);
            acc[10] = fmaf(xv, w2.z, acc[10]); acc[11] = fmaf(xv, w2.w, acc[11]);
            acc[12] = fmaf(xv, w3.x, acc[12]); acc[13] = fmaf(xv, w3.y, acc[13]);
            acc[14] = fmaf(xv, w3.z, acc[14]); acc[15] = fmaf(xv, w3.w, acc[15]);
        }
    }
    float* ob = zc + ((size_t)bh << 19) + ((size_t)vv << 4);
    const float* bp = cbias + h * 16;
    #pragma unroll
    for (int q = 0; q < 4; ++q)
        ((float4*)ob)[q] = make_float4(acc[q*4] + bp[q*4], acc[q*4+1] + bp[q*4+1],
                                       acc[q*4+2] + bp[q*4+2], acc[q*4+3] + bp[q*4+3]);
}

// ---------------- slice: weighted gather back to points ---------------------
__global__ __launch_bounds__(256) void slice_vm(
    const float* __restrict__ zc, const float4* __restrict__ coordbuf,
    float* __restrict__ out) {
    int p = blockIdx.x * 256 + threadIdx.x;
    int n = p & (N_ - 1);
    int bh = p >> 13;
    int h = bh & 7, b = bh >> 3;
    float4 c = coordbuf[p];
    int pk = __float_as_int(c.w);
    int f0x = pk & 31, f0y = (pk >> 5) & 31, f0z = (pk >> 10) & 31;
    const float* gb = zc + ((size_t)bh << 19);
    float acc[16];
    #pragma unroll
    for (int f = 0; f < 16; ++f) acc[f] = 0.f;
    #pragma unroll 1
    for (int k = 0; k < 8; ++k) {
        int cx = (k >> 2) & 1, cy = (k >> 1) & 1, cz = k & 1;
        float w = (cx ? c.x : 1.f - c.x) * (cy ? c.y : 1.f - c.y) * (cz ? c.z : 1.f - c.z);
        int vox = (((f0x + cx) << 5) + f0y + cy) * 32 + f0z + cz;
        const float4* ip = (const float4*)(gb + ((size_t)vox << 4));
        float4 a0 = ip[0], a1 = ip[1], a2 = ip[2], a3 = ip[3];
        acc[0]  = fmaf(w, a0.x, acc[0]);  acc[1]  = fmaf(w, a0.y, acc[1]);
        acc[2]  = fmaf(w, a0.z, acc[2]);  acc[3]  = fmaf(w, a0.w, acc[3]);
        acc[4]  = fmaf(w, a1.x, acc[4]);  acc[5]  = fmaf(w, a1.y, acc[5]);
        acc[6]  = fmaf(w, a1.z, acc[6]);  acc[7]  = fmaf(w, a1.w, acc[7]);
        acc[8]  = fmaf(w, a2.x, acc[8]);  acc[9]  = fmaf(w, a2.y, acc[9]);
        acc[10] = fmaf(w, a2.z, acc[10]); acc[11] = fmaf(w, a2.w, acc[11]);
        acc[12] = fmaf(w, a3.x, acc[12]); acc[13] = fmaf(w, a3.y, acc[13]);
        acc[14] = fmaf(w, a3.z, acc[14]); acc[15] = fmaf(w, a3.w, acc[15]);
    }
    #pragma unroll
    for (int f = 0; f < 16; ++f)
        out[(((size_t)(b * HF_ + h * F_ + f)) << 13) + n] = acc[f];
}

// ---------------- final AdaIN + ReLU (in place on d_out) --------------------
__global__ __launch_bounds__(256) void final_adain(
    float* __restrict__ out, const float* __restrict__ mean_o,
    const float* __restrict__ rsig_o, const float* __restrict__ ha) {
    size_t i = (size_t)blockIdx.x * 256 + threadIdx.x;
    int bc = (int)(i >> 13);
    int c = bc & 127, b = bc >> 7;
    float x = out[i];
    float xn = (x - mean_o[bc]) * rsig_o[bc];
    float y = fmaf(1.f + ha[b * 256 + c], xn, ha[b * 256 + 128 + c]);
    out[i] = fmaxf(y, 0.f);
}

extern "C" void kernel_launch(void* const* d_in, const int* in_sizes, int n_in,
                              void* d_out, int out_size, void* d_ws, size_t ws_size,
                              hipStream_t stream) {
    (void)in_sizes; (void)n_in; (void)out_size; (void)ws_size;
    const float* input   = (const float*)d_in[0];
    const float* style   = (const float*)d_in[1];
    const float* orig    = (const float*)d_in[2];
    const float* Wkv     = (const float*)d_in[3];
    const float* kw_w    = (const float*)d_in[4];
    const float* kw_b    = (const float*)d_in[5];
    const float* vw_w    = (const float*)d_in[6];
    const float* vw_b    = (const float*)d_in[7];
    const float* aw_w    = (const float*)d_in[8];
    const float* aw_b    = (const float*)d_in[9];
    const float* scale_p = (const float*)d_in[10];
    const float* Tw      = (const float*)d_in[11];
    const float* Tb      = (const float*)d_in[12];
    const float* conv_w  = (const float*)d_in[13];
    const float* conv_b  = (const float*)d_in[14];
    float* out = (float*)d_out;

    // -------- workspace layout (floats), ~139.2 MB total --------------------
    float* ws = (float*)d_ws;
    float* z        = ws;                        // 16,777,216  (64MB) splat lattice
    float* zc       = ws + 16777216;             // 16,777,216  (64MB) conv output
    float* coordbuf = ws + 2 * 16777216;         //  1,048,576  (float4 per point)
    float* wt       = coordbuf + 1048576;        //     55,296
    float* ha       = wt + 55296;                //      1,024
    float* mean_o   = ha + 1024;                 //        512
    float* rsig_o   = mean_o + 512;              //        512
    float* mean_kv  = rsig_o + 512;              //        608
    float* rsig_kv  = mean_kv + 608;             //        608
    float* hk       = rsig_kv + 608;             //        192
    float* hv       = hk + 192;                  //      1,024
    int*   counts   = (int*)(hv + 1024);         //      1,024 ints
    int*   base     = counts + 1024;             //      1,025 ints
    int*   cursor   = base + 1025;               //      1,024 ints
    unsigned short* recs = (unsigned short*)(cursor + 1024);  // 262,144 u16 (512KB)
    // aliased into zc (dead until conv3d runs):
    float* vbuf = zc;                            //  4,194,304 (16MB) AdaIN'd values
    float* kv   = zc + 4194304;                  //  4,980,736 (19MB)

    zero_bins<<<1, 1024, 0, stream>>>(counts);
    style_proj<<<B_, 256, 0, stream>>>(style, kw_w, kw_b, vw_w, vw_b, aw_w, aw_b, hk, hv, ha);
    wtrans_vm<<<216, 256, 0, stream>>>(conv_w, wt);
    kv_gemm<<<dim3(8, 8, B_), 256, 0, stream>>>(input, Wkv, kv);
    stats_kernel<<<B_ * CO_, 256, 0, stream>>>(kv, mean_kv, rsig_kv);
    point_prep<<<B_ * H_ * N_ / 256, 256, 0, stream>>>(
        kv, mean_kv, rsig_kv, hk, hv, orig, scale_p, Tw, Tb,
        (float4*)coordbuf, vbuf, counts);
    prefix_bins<<<1, 64, 0, stream>>>(counts, base, cursor);
    scatter_pts<<<B_ * H_ * N_ / 256, 256, 0, stream>>>((const float4*)coordbuf, cursor, recs);
    splat3<<<1024, 1024, 0, stream>>>((const float4*)coordbuf, vbuf, base, recs, z);
    conv3d_vm<<<2048, 512, 0, stream>>>(z, wt, conv_b, zc);
    slice_vm<<<B_ * H_ * N_ / 256, 256, 0, stream>>>(zc, (const float4*)coordbuf, out);
    stats_kernel<<<B_ * HF_, 256, 0, stream>>>(out, mean_o, rsig_o);
    final_adain<<<B_ * HF_ * N_ / 256, 256, 0, stream>>>(out, mean_o, rsig_o, ha);
}

// Round 7
// 429.510 us; speedup vs baseline: 1.6191x; 1.2151x over previous
//
#include <hip/hip_runtime.h>
#include <hip/hip_bf16.h>
#include <math.h>

#define B_ 4
#define N_ 8192
#define MD_ 512
#define H_ 8
#define F_ 16
#define S_ 32
#define S3_ 32768
#define L_ 256
#define CO_ 152   // H*(F+3)
#define HF_ 128   // H*F
#define EPS_ 1e-5f
#define CHUNK_ 2048

typedef __attribute__((ext_vector_type(8))) short bf16x8;
typedef __attribute__((ext_vector_type(4))) float f32x4;

__device__ inline unsigned short f2bf(float f) {   // RNE fp32 -> bf16
    unsigned u = __float_as_uint(f);
    return (unsigned short)((u + 0x7FFFu + ((u >> 16) & 1u)) >> 16);
}

// ---------------- zero the 1024 bin counters --------------------------------
__global__ __launch_bounds__(1024) void zero_bins(int* __restrict__ counts) {
    counts[threadIdx.x] = 0;
}

// ---------------- style projections: h = style @ W.T + b --------------------
__global__ __launch_bounds__(256) void style_proj(
    const float* __restrict__ style,
    const float* __restrict__ kw_w, const float* __restrict__ kw_b,
    const float* __restrict__ vw_w, const float* __restrict__ vw_b,
    const float* __restrict__ aw_w, const float* __restrict__ aw_b,
    float* __restrict__ hk, float* __restrict__ hv, float* __restrict__ ha) {
    int b = blockIdx.x;
    const float* st = style + b * L_;
    for (int r = threadIdx.x; r < 48 + 256 + 256; r += 256) {
        const float* wrow; float bias; float* dst; int j;
        if (r < 48)       { j = r;       wrow = kw_w + j * L_; bias = kw_b[j]; dst = hk + b * 48; }
        else if (r < 304) { j = r - 48;  wrow = vw_w + j * L_; bias = vw_b[j]; dst = hv + b * 256; }
        else              { j = r - 304; wrow = aw_w + j * L_; bias = aw_b[j]; dst = ha + b * 256; }
        float acc = bias;
        for (int l = 0; l < L_; ++l) acc = fmaf(st[l], wrow[l], acc);
        dst[j] = acc;
    }
}

// ---------------- conv weights -> bf16 [h][28 taps][oc][ic] (tap 27 = 0) ----
__global__ __launch_bounds__(256) void wtrans_bf(const float* __restrict__ cw,
                                                 unsigned short* __restrict__ wb) {
    int i = blockIdx.x * 256 + threadIdx.x;   // 8*28*16*16 = 57344 total
    if (i >= 57344) return;
    int ic  = i & 15;
    int oc  = (i >> 4) & 15;
    int tap = (i >> 8) % 28;
    int h   = (i >> 8) / 28;
    float v = (tap < 27) ? cw[(((h * 16 + oc) * 16 + ic) * 27) + tap] : 0.f;
    wb[i] = f2bf(v);
}

// ---------------- kv = W_kv @ input  (per batch) ----------------------------
__global__ __launch_bounds__(256) void kv_gemm(
    const float* __restrict__ input, const float* __restrict__ Wkv, float* __restrict__ kv) {
    int b = blockIdx.z, rb = blockIdx.y;
    int n0 = blockIdx.x * 1024 + (threadIdx.x << 2);
    __shared__ float wlds[19 * MD_];
    for (int i = threadIdx.x; i < 19 * MD_ / 4; i += 256)
        ((float4*)wlds)[i] = ((const float4*)(Wkv + rb * 19 * MD_))[i];
    __syncthreads();
    float acc[19][4];
    #pragma unroll
    for (int i = 0; i < 19; ++i)
        for (int q = 0; q < 4; ++q) acc[i][q] = 0.f;
    const float* inb = input + (size_t)b * MD_ * N_ + n0;
    for (int c = 0; c < MD_; ++c) {
        float4 x = *(const float4*)(inb + (size_t)c * N_);
        #pragma unroll
        for (int i = 0; i < 19; ++i) {
            float w = wlds[i * MD_ + c];
            acc[i][0] = fmaf(w, x.x, acc[i][0]);
            acc[i][1] = fmaf(w, x.y, acc[i][1]);
            acc[i][2] = fmaf(w, x.z, acc[i][2]);
            acc[i][3] = fmaf(w, x.w, acc[i][3]);
        }
    }
    float* outb = kv + (size_t)b * CO_ * N_ + n0;
    #pragma unroll
    for (int i = 0; i < 19; ++i)
        *(float4*)(outb + (size_t)(rb * 19 + i) * N_) =
            make_float4(acc[i][0], acc[i][1], acc[i][2], acc[i][3]);
}

// ---------------- per-(b,channel) mean / rsig over N ------------------------
__global__ __launch_bounds__(256) void stats_kernel(
    const float* __restrict__ x, float* __restrict__ mean, float* __restrict__ rsig) {
    int bc = blockIdx.x;
    const float* p = x + (size_t)bc * N_;
    float s = 0.f, s2 = 0.f;
    for (int i = threadIdx.x; i < N_; i += 256) {
        float v = p[i]; s += v; s2 = fmaf(v, v, s2);
    }
    #pragma unroll
    for (int off = 32; off; off >>= 1) { s += __shfl_down(s, off); s2 += __shfl_down(s2, off); }
    __shared__ float ls[4], ls2[4];
    int wid = threadIdx.x >> 6;
    if ((threadIdx.x & 63) == 0) { ls[wid] = s; ls2[wid] = s2; }
    __syncthreads();
    if (threadIdx.x == 0) {
        float S = ls[0] + ls[1] + ls[2] + ls[3];
        float S2 = ls2[0] + ls2[1] + ls2[2] + ls2[3];
        float mu = S * (1.f / N_);
        float var = S2 * (1.f / N_) - mu * mu;
        mean[bc] = mu;
        rsig[bc] = rsqrtf(var + EPS_);
    }
}

// ---------------- point prep: AdaIN + transform + tanh + interp + count -----
__global__ __launch_bounds__(256) void point_prep(
    const float* __restrict__ kv, const float* __restrict__ mean_kv,
    const float* __restrict__ rsig_kv, const float* __restrict__ hk,
    const float* __restrict__ hv, const float* __restrict__ orig,
    const float* __restrict__ scale_p, const float* __restrict__ Tw,
    const float* __restrict__ Tb,
    float4* __restrict__ coordbuf, float* __restrict__ vbuf,
    int* __restrict__ counts) {
    int p = blockIdx.x * 256 + threadIdx.x;
    int n = p & (N_ - 1);
    int bh = p >> 13;
    int h = bh & 7, b = bh >> 3;
    float scl = scale_p[0];

    float pt[3];
    #pragma unroll
    for (int j = 0; j < 3; ++j) {
        int c = h * 3 + j;
        float x  = kv[((size_t)(b * CO_ + c)) * N_ + n];
        float xn = (x - mean_kv[b * CO_ + c]) * rsig_kv[b * CO_ + c];
        float kr = fmaf(1.f + hk[b * 48 + c], xn, hk[b * 48 + 24 + c]);
        pt[j] = fmaf(scl, kr, orig[((size_t)(b * 3 + j)) * N_ + n]);
    }
    int f0[3]; float tt[3];
    #pragma unroll
    for (int i = 0; i < 3; ++i) {
        float key = Tb[h * 3 + i];
        #pragma unroll
        for (int j = 0; j < 3; ++j) key = fmaf(Tw[(h * 3 + i) * 3 + j], pt[j], key);
        float lat = tanhf(key);
        float g = (lat + 1.f) * 0.5f * (float)(S_ - 1);
        float ff = floorf(g);
        ff = fminf(fmaxf(ff, 0.f), 30.f);
        f0[i] = (int)ff;
        tt[i] = fminf(fmaxf(g - ff, 0.f), 1.f);
    }
    coordbuf[p] = make_float4(tt[0], tt[1], tt[2],
                              __int_as_float(f0[0] | (f0[1] << 5) | (f0[2] << 10)));
    atomicAdd(&counts[(bh << 5) + f0[0]], 1);
    float vf[16];
    #pragma unroll
    for (int f = 0; f < F_; ++f) {
        int c = 24 + h * F_ + f;
        float x  = kv[((size_t)(b * CO_ + c)) * N_ + n];
        float xn = (x - mean_kv[b * CO_ + c]) * rsig_kv[b * CO_ + c];
        int cv = h * F_ + f;
        vf[f] = fmaf(1.f + hv[b * 256 + cv], xn, hv[b * 256 + 128 + cv]);
    }
    float4* vb = (float4*)(vbuf + (size_t)p * 16);
    #pragma unroll
    for (int q = 0; q < 4; ++q)
        vb[q] = make_float4(vf[q * 4], vf[q * 4 + 1], vf[q * 4 + 2], vf[q * 4 + 3]);
}

// ---------------- exclusive prefix over the 1024 bins (one wave) ------------
__global__ __launch_bounds__(64) void prefix_bins(
    const int* __restrict__ counts, int* __restrict__ base, int* __restrict__ cursor) {
    int lane = threadIdx.x;
    int local[16], sum = 0;
    #pragma unroll
    for (int i = 0; i < 16; ++i) { local[i] = sum; sum += counts[lane * 16 + i]; }
    int incl = sum;
    #pragma unroll
    for (int off = 1; off < 64; off <<= 1) {
        int v = __shfl_up(incl, off);
        if (lane >= off) incl += v;
    }
    int excl = incl - sum;
    #pragma unroll
    for (int i = 0; i < 16; ++i) {
        int bse = excl + local[i];
        base[lane * 16 + i] = bse;
        cursor[lane * 16 + i] = bse;
    }
    if (lane == 63) base[1024] = excl + sum;
}

// ---------------- scatter point indices into bins ---------------------------
__global__ __launch_bounds__(256) void scatter_pts(
    const float4* __restrict__ coordbuf, int* __restrict__ cursor,
    unsigned short* __restrict__ recs) {
    int p = blockIdx.x * 256 + threadIdx.x;
    int bh = p >> 13;
    int pk = __float_as_int(((const float*)coordbuf)[(size_t)p * 4 + 3]);
    int f0x = pk & 31;
    int slot = atomicAdd(&cursor[(bh << 5) + f0x], 1);
    recs[slot] = (unsigned short)(p & (N_ - 1));
}

// ---------------- splat3: in-block sub-sort by (y,z), register gather -------
// block -> one x-plane of one (b,h); 1024 threads, thread = voxel (y,z).
// Output lattice written in bf16 [bh][vox][16ch] for the MFMA conv.
__global__ __launch_bounds__(1024) void splat3(
    const float4* __restrict__ coordbuf, const float* __restrict__ vbuf,
    const int* __restrict__ base, const unsigned short* __restrict__ recs,
    unsigned short* __restrict__ zb16) {
    __shared__ int s_cnt[1024];
    __shared__ int s_start[1024];
    __shared__ int s_cur[1024];
    __shared__ unsigned int s_pts[CHUNK_];
    __shared__ unsigned int s_sorted[CHUNK_];
    __shared__ int s_wavesum[16];
    int logical = (blockIdx.x & 7) * 128 + (blockIdx.x >> 3);  // XCD swizzle
    int bh = logical >> 5;
    int x0 = logical & 31;
    int tid = threadIdx.x;
    int y = tid >> 5, zc = tid & 31;
    int bin0 = (bh << 5) + x0;
    int s0 = base[bin0], len0 = base[bin0 + 1] - s0;
    int s1 = 0, len1 = 0;
    if (x0 > 0) { s1 = base[bin0 - 1]; len1 = s0 - s1; }
    int total = len0 + len1;
    const float4* cb = coordbuf + (size_t)bh * N_;
    const float* vb = vbuf + ((size_t)bh * N_) * 16;
    float acc[16];
    #pragma unroll
    for (int i = 0; i < 16; ++i) acc[i] = 0.f;

    for (int c0 = 0; c0 < total; c0 += CHUNK_) {
        int cl = min(CHUNK_, total - c0);
        s_cnt[tid] = 0;
        __syncthreads();
        for (int t = tid; t < cl; t += 1024) {
            int tp = c0 + t, n, cx;
            if (tp < len0) { n = recs[s0 + tp]; cx = 0; }
            else           { n = recs[s1 + (tp - len0)]; cx = 1; }
            int pk = __float_as_int(cb[n].w);
            int sb = (((pk >> 5) & 31) << 5) | ((pk >> 10) & 31);
            s_pts[t] = ((unsigned)sb << 16) | ((unsigned)cx << 14) | (unsigned)n;
            atomicAdd(&s_cnt[sb], 1);
        }
        __syncthreads();
        int v = s_cnt[tid];
        int incl = v;
        #pragma unroll
        for (int off = 1; off < 64; off <<= 1) {
            int u = __shfl_up(incl, off);
            if ((tid & 63) >= off) incl += u;
        }
        int wid = tid >> 6;
        if ((tid & 63) == 63) s_wavesum[wid] = incl;
        __syncthreads();
        if (tid < 16) {
            int wv = s_wavesum[tid];
            int wincl = wv;
            #pragma unroll
            for (int off = 1; off < 16; off <<= 1) {
                int u = __shfl_up(wincl, off);
                if (tid >= off) wincl += u;
            }
            s_wavesum[tid] = wincl - wv;
        }
        __syncthreads();
        int excl = incl - v + s_wavesum[wid];
        s_start[tid] = excl;
        s_cur[tid] = excl;
        __syncthreads();
        for (int t = tid; t < cl; t += 1024) {
            unsigned rec = s_pts[t];
            int slot = atomicAdd(&s_cur[rec >> 16], 1);
            s_sorted[slot] = rec;
        }
        __syncthreads();
        #pragma unroll
        for (int sy = 0; sy < 2; ++sy) {
            int yy = y - sy;
            if (yy < 0) continue;
            #pragma unroll
            for (int sz = 0; sz < 2; ++sz) {
                int zz = zc - sz;
                if (zz < 0) continue;
                int sb = (yy << 5) | zz;
                int s = s_start[sb], e = s + s_cnt[sb];
                for (int i = s; i < e; ++i) {
                    unsigned rec = s_sorted[i];
                    int n = rec & 0x3FFF;
                    int cx = (rec >> 14) & 1;
                    float4 c = cb[n];
                    float wx = cx ? c.x : 1.f - c.x;
                    float wy = sy ? c.y : 1.f - c.y;
                    float wz = sz ? c.z : 1.f - c.z;
                    float w = wx * wy * wz;
                    const float4* vp = (const float4*)(vb + (size_t)n * 16);
                    float4 a0 = vp[0], a1 = vp[1], a2 = vp[2], a3 = vp[3];
                    acc[0]  = fmaf(w, a0.x, acc[0]);  acc[1]  = fmaf(w, a0.y, acc[1]);
                    acc[2]  = fmaf(w, a0.z, acc[2]);  acc[3]  = fmaf(w, a0.w, acc[3]);
                    acc[4]  = fmaf(w, a1.x, acc[4]);  acc[5]  = fmaf(w, a1.y, acc[5]);
                    acc[6]  = fmaf(w, a1.z, acc[6]);  acc[7]  = fmaf(w, a1.w, acc[7]);
                    acc[8]  = fmaf(w, a2.x, acc[8]);  acc[9]  = fmaf(w, a2.y, acc[9]);
                    acc[10] = fmaf(w, a2.z, acc[10]); acc[11] = fmaf(w, a2.w, acc[11]);
                    acc[12] = fmaf(w, a3.x, acc[12]); acc[13] = fmaf(w, a3.y, acc[13]);
                    acc[14] = fmaf(w, a3.z, acc[14]); acc[15] = fmaf(w, a3.w, acc[15]);
                }
            }
        }
        __syncthreads();
    }
    // bf16 pack + coalesced 32B write
    unsigned int pk[8];
    #pragma unroll
    for (int q = 0; q < 8; ++q)
        pk[q] = (unsigned)f2bf(acc[2 * q]) | ((unsigned)f2bf(acc[2 * q + 1]) << 16);
    unsigned short* zb = zb16 + (((size_t)bh * S3_ + (x0 << 10) + tid) << 4);
    ((uint4*)zb)[0] = make_uint4(pk[0], pk[1], pk[2], pk[3]);
    ((uint4*)zb)[1] = make_uint4(pk[4], pk[5], pk[6], pk[7]);
}

// ---------------- grouped 3x3x3 conv via bf16 MFMA --------------------------
// block = one x-plane of one (b,h): 4 waves x 16 tiles; tile = 16 z-voxels x 16 oc.
// K = 28 taps x 16 ic (tap 27 zero-padded) = 14 MFMA k-steps of 32.
__global__ __launch_bounds__(256) void conv3d_mfma(
    const unsigned short* __restrict__ zb16, const unsigned short* __restrict__ wb,
    const float* __restrict__ cbias, float* __restrict__ zc) {
    int logical = (blockIdx.x & 7) * 128 + (blockIdx.x >> 3);  // 1024 = 8*128
    int bh = logical >> 5;
    int x  = logical & 31;
    int h = bh & 7;
    int lane = threadIdx.x & 63;
    int wv = threadIdx.x >> 6;
    int rc = lane & 15;           // A-row (z in tile) / B-col (oc) / D-col (oc)
    int kb = lane >> 4;           // 0..3 k-group
    int ic0 = (kb & 1) << 3;
    int tsel = kb >> 1;           // which tap of the pair

    // B-frags: weights for this head, loaded once per wave
    bf16x8 bfr[14];
    const unsigned short* wh = wb + h * 28 * 256;   // [28][16 oc][16 ic]
    #pragma unroll
    for (int p = 0; p < 14; ++p) {
        int t = 2 * p + tsel;
        bfr[p] = *(const bf16x8*)(wh + (t * 16 + rc) * 16 + ic0);
    }
    float bias = cbias[h * 16 + rc];
    const unsigned short* zbh = zb16 + ((size_t)bh << 19);
    float* zcb = zc + ((size_t)bh << 19);
    const bf16x8 zerov = {0, 0, 0, 0, 0, 0, 0, 0};

    #pragma unroll 1
    for (int ti = 0; ti < 16; ++ti) {
        int tile = wv * 16 + ti;
        int y = tile >> 1;
        int z0 = (tile & 1) << 4;
        f32x4 acc = {0.f, 0.f, 0.f, 0.f};
        #pragma unroll
        for (int p = 0; p < 14; ++p) {
            int t = 2 * p + tsel;                 // 0..27
            int dx = t / 9, r9 = t - dx * 9;
            int dy = r9 / 3, dz = r9 - dy * 3;
            int xx = x + dx - 1, yy = y + dy - 1, zz = z0 + rc + dz - 1;
            bool ok = (t < 27) & (xx >= 0) & (xx < 32) & (yy >= 0) & (yy < 32)
                    & (zz >= 0) & (zz < 32);
            int vox = (((xx << 5) + yy) << 5) + zz;
            const unsigned short* ap = ok ? (zbh + ((size_t)vox << 4) + ic0) : zbh;
            bf16x8 a = *(const bf16x8*)ap;
            a = ok ? a : zerov;
            acc = __builtin_amdgcn_mfma_f32_16x16x32_bf16(a, bfr[p], acc, 0, 0, 0);
        }
        // D: col = rc (oc), row = kb*4 + r -> z = z0 + kb*4 + r
        int vbase = (((x << 5) + y) << 5) + z0 + (kb << 2);
        #pragma unroll
        for (int r = 0; r < 4; ++r)
            zcb[(size_t)(vbase + r) * 16 + rc] = acc[r] + bias;
    }
}

// ---------------- slice: weighted gather back to points ---------------------
__global__ __launch_bounds__(256) void slice_vm(
    const float* __restrict__ zc, const float4* __restrict__ coordbuf,
    float* __restrict__ out) {
    int p = blockIdx.x * 256 + threadIdx.x;
    int n = p & (N_ - 1);
    int bh = p >> 13;
    int h = bh & 7, b = bh >> 3;
    float4 c = coordbuf[p];
    int pk = __float_as_int(c.w);
    int f0x = pk & 31, f0y = (pk >> 5) & 31, f0z = (pk >> 10) & 31;
    const float* gb = zc + ((size_t)bh << 19);
    float acc[16];
    #pragma unroll
    for (int f = 0; f < 16; ++f) acc[f] = 0.f;
    #pragma unroll 1
    for (int k = 0; k < 8; ++k) {
        int cx = (k >> 2) & 1, cy = (k >> 1) & 1, cz = k & 1;
        float w = (cx ? c.x : 1.f - c.x) * (cy ? c.y : 1.f - c.y) * (cz ? c.z : 1.f - c.z);
        int vox = (((f0x + cx) << 5) + f0y + cy) * 32 + f0z + cz;
        const float4* ip = (const float4*)(gb + ((size_t)vox << 4));
        float4 a0 = ip[0], a1 = ip[1], a2 = ip[2], a3 = ip[3];
        acc[0]  = fmaf(w, a0.x, acc[0]);  acc[1]  = fmaf(w, a0.y, acc[1]);
        acc[2]  = fmaf(w, a0.z, acc[2]);  acc[3]  = fmaf(w, a0.w, acc[3]);
        acc[4]  = fmaf(w, a1.x, acc[4]);  acc[5]  = fmaf(w, a1.y, acc[5]);
        acc[6]  = fmaf(w, a1.z, acc[6]);  acc[7]  = fmaf(w, a1.w, acc[7]);
        acc[8]  = fmaf(w, a2.x, acc[8]);  acc[9]  = fmaf(w, a2.y, acc[9]);
        acc[10] = fmaf(w, a2.z, acc[10]); acc[11] = fmaf(w, a2.w, acc[11]);
        acc[12] = fmaf(w, a3.x, acc[12]); acc[13] = fmaf(w, a3.y, acc[13]);
        acc[14] = fmaf(w, a3.z, acc[14]); acc[15] = fmaf(w, a3.w, acc[15]);
    }
    #pragma unroll
    for (int f = 0; f < 16; ++f)
        out[(((size_t)(b * HF_ + h * F_ + f)) << 13) + n] = acc[f];
}

// ---------------- final AdaIN + ReLU (in place on d_out) --------------------
__global__ __launch_bounds__(256) void final_adain(
    float* __restrict__ out, const float* __restrict__ mean_o,
    const float* __restrict__ rsig_o, const float* __restrict__ ha) {
    size_t i = (size_t)blockIdx.x * 256 + threadIdx.x;
    int bc = (int)(i >> 13);
    int c = bc & 127, b = bc >> 7;
    float x = out[i];
    float xn = (x - mean_o[bc]) * rsig_o[bc];
    float y = fmaf(1.f + ha[b * 256 + c], xn, ha[b * 256 + 128 + c]);
    out[i] = fmaxf(y, 0.f);
}

extern "C" void kernel_launch(void* const* d_in, const int* in_sizes, int n_in,
                              void* d_out, int out_size, void* d_ws, size_t ws_size,
                              hipStream_t stream) {
    (void)in_sizes; (void)n_in; (void)out_size; (void)ws_size;
    const float* input   = (const float*)d_in[0];
    const float* style   = (const float*)d_in[1];
    const float* orig    = (const float*)d_in[2];
    const float* Wkv     = (const float*)d_in[3];
    const float* kw_w    = (const float*)d_in[4];
    const float* kw_b    = (const float*)d_in[5];
    const float* vw_w    = (const float*)d_in[6];
    const float* vw_b    = (const float*)d_in[7];
    const float* aw_w    = (const float*)d_in[8];
    const float* aw_b    = (const float*)d_in[9];
    const float* scale_p = (const float*)d_in[10];
    const float* Tw      = (const float*)d_in[11];
    const float* Tb      = (const float*)d_in[12];
    const float* conv_w  = (const float*)d_in[13];
    const float* conv_b  = (const float*)d_in[14];
    float* out = (float*)d_out;

    // -------- workspace layout (floats), ~139.2 MB total --------------------
    float* ws = (float*)d_ws;
    float* z        = ws;                        // lattice: bf16 [32][32768][16] (32MB used)
    float* zc       = ws + 16777216;             // 16,777,216  (64MB) conv output fp32
    float* coordbuf = ws + 2 * 16777216;         //  1,048,576  (float4 per point)
    float* wt       = coordbuf + 1048576;        //  55,296 floats (bf16 weights use 112KB)
    float* ha       = wt + 55296;                //      1,024
    float* mean_o   = ha + 1024;                 //        512
    float* rsig_o   = mean_o + 512;              //        512
    float* mean_kv  = rsig_o + 512;              //        608
    float* rsig_kv  = mean_kv + 608;             //        608
    float* hk       = rsig_kv + 608;             //        192
    float* hv       = hk + 192;                  //      1,024
    int*   counts   = (int*)(hv + 1024);         //      1,024 ints
    int*   base     = counts + 1024;             //      1,025 ints
    int*   cursor   = base + 1025;               //      1,024 ints
    unsigned short* recs = (unsigned short*)(cursor + 1024);  // 262,144 u16 (512KB)
    // aliased into zc (dead until conv3d runs):
    float* vbuf = zc;                            //  4,194,304 (16MB) AdaIN'd values
    float* kv   = zc + 4194304;                  //  4,980,736 (19MB)
    unsigned short* zb16 = (unsigned short*)z;
    unsigned short* wb16 = (unsigned short*)wt;

    zero_bins<<<1, 1024, 0, stream>>>(counts);
    style_proj<<<B_, 256, 0, stream>>>(style, kw_w, kw_b, vw_w, vw_b, aw_w, aw_b, hk, hv, ha);
    wtrans_bf<<<224, 256, 0, stream>>>(conv_w, wb16);
    kv_gemm<<<dim3(8, 8, B_), 256, 0, stream>>>(input, Wkv, kv);
    stats_kernel<<<B_ * CO_, 256, 0, stream>>>(kv, mean_kv, rsig_kv);
    point_prep<<<B_ * H_ * N_ / 256, 256, 0, stream>>>(
        kv, mean_kv, rsig_kv, hk, hv, orig, scale_p, Tw, Tb,
        (float4*)coordbuf, vbuf, counts);
    prefix_bins<<<1, 64, 0, stream>>>(counts, base, cursor);
    scatter_pts<<<B_ * H_ * N_ / 256, 256, 0, stream>>>((const float4*)coordbuf, cursor, recs);
    splat3<<<1024, 1024, 0, stream>>>((const float4*)coordbuf, vbuf, base, recs, zb16);
    conv3d_mfma<<<1024, 256, 0, stream>>>(zb16, wb16, conv_b, zc);
    slice_vm<<<B_ * H_ * N_ / 256, 256, 0, stream>>>(zc, (const float4*)coordbuf, out);
    stats_kernel<<<B_ * HF_, 256, 0, stream>>>(out, mean_o, rsig_o);
    final_adain<<<B_ * HF_ * N_ / 256, 256, 0, stream>>>(out, mean_o, rsig_o, ha);
}

// Round 8
// 356.335 us; speedup vs baseline: 1.9516x; 1.2054x over previous
//
#include <hip/hip_runtime.h>
#include <hip/hip_bf16.h>
#include <math.h>

#define B_ 4
#define N_ 8192
#define MD_ 512
#define H_ 8
#define F_ 16
#define S_ 32
#define S3_ 32768
#define L_ 256
#define CO_ 152   // H*(F+3)
#define HF_ 128   // H*F
#define EPS_ 1e-5f
#define CHUNK_ 2048

typedef __attribute__((ext_vector_type(8))) short bf16x8;
typedef __attribute__((ext_vector_type(4))) float f32x4;

__device__ inline unsigned short f2bf(float f) {   // RNE fp32 -> bf16
    unsigned u = __float_as_uint(f);
    return (unsigned short)((u + 0x7FFFu + ((u >> 16) & 1u)) >> 16);
}

// ---------------- zero the 1024 bin counters --------------------------------
__global__ __launch_bounds__(1024) void zero_bins(int* __restrict__ counts) {
    counts[threadIdx.x] = 0;
}

// ---------------- style projections: h = style @ W.T + b --------------------
__global__ __launch_bounds__(256) void style_proj(
    const float* __restrict__ style,
    const float* __restrict__ kw_w, const float* __restrict__ kw_b,
    const float* __restrict__ vw_w, const float* __restrict__ vw_b,
    const float* __restrict__ aw_w, const float* __restrict__ aw_b,
    float* __restrict__ hk, float* __restrict__ hv, float* __restrict__ ha) {
    int b = blockIdx.x;
    const float* st = style + b * L_;
    for (int r = threadIdx.x; r < 48 + 256 + 256; r += 256) {
        const float* wrow; float bias; float* dst; int j;
        if (r < 48)       { j = r;       wrow = kw_w + j * L_; bias = kw_b[j]; dst = hk + b * 48; }
        else if (r < 304) { j = r - 48;  wrow = vw_w + j * L_; bias = vw_b[j]; dst = hv + b * 256; }
        else              { j = r - 304; wrow = aw_w + j * L_; bias = aw_b[j]; dst = ha + b * 256; }
        float acc = bias;
        for (int l = 0; l < L_; ++l) acc = fmaf(st[l], wrow[l], acc);
        dst[j] = acc;
    }
}

// ---------------- conv weights -> bf16 [h][28 taps][oc][ic] (tap 27 = 0) ----
__global__ __launch_bounds__(256) void wtrans_bf(const float* __restrict__ cw,
                                                 unsigned short* __restrict__ wb) {
    int i = blockIdx.x * 256 + threadIdx.x;   // 8*28*16*16 = 57344 total
    if (i >= 57344) return;
    int ic  = i & 15;
    int oc  = (i >> 4) & 15;
    int tap = (i >> 8) % 28;
    int h   = (i >> 8) / 28;
    float v = (tap < 27) ? cw[(((h * 16 + oc) * 16 + ic) * 27) + tap] : 0.f;
    wb[i] = f2bf(v);
}

// ---------------- W_kv -> bf16 fragment layout [mt(10)][kc(64)][r16][k8] ----
__global__ __launch_bounds__(256) void wconvert(
    const float* __restrict__ Wkv, unsigned short* __restrict__ wkb) {
    int i = blockIdx.x * 256 + threadIdx.x;   // 10*64*16 = 10240
    if (i >= 10240) return;
    int r  = i & 15;
    int kc = (i >> 4) & 63;
    int mt = i >> 10;
    int row = mt * 16 + r;
    unsigned int pk[4];
    #pragma unroll
    for (int j = 0; j < 4; ++j) {
        float v0 = (row < CO_) ? Wkv[(size_t)row * MD_ + kc * 8 + 2 * j] : 0.f;
        float v1 = (row < CO_) ? Wkv[(size_t)row * MD_ + kc * 8 + 2 * j + 1] : 0.f;
        pk[j] = (unsigned)f2bf(v0) | ((unsigned)f2bf(v1) << 16);
    }
    *(uint4*)(wkb + (((size_t)(mt * 64 + kc)) * 16 + r) * 8) =
        make_uint4(pk[0], pk[1], pk[2], pk[3]);
}

// ---------------- input -> bf16 fragment layout [b][nt(512)][kc(64)][n16][k8]
__global__ __launch_bounds__(256) void xconvert(
    const float* __restrict__ X, unsigned short* __restrict__ xb) {
    int i = blockIdx.x * 256 + threadIdx.x;   // 4*64*8192 = 2,097,152
    int n  = i & (N_ - 1);
    int kc = (i >> 13) & 63;
    int b  = i >> 19;
    const float* xp = X + ((size_t)b * MD_ + kc * 8) * N_ + n;
    unsigned int pk[4];
    #pragma unroll
    for (int j = 0; j < 4; ++j) {
        float v0 = xp[(size_t)(2 * j) * N_];
        float v1 = xp[(size_t)(2 * j + 1) * N_];
        pk[j] = (unsigned)f2bf(v0) | ((unsigned)f2bf(v1) << 16);
    }
    int nt = n >> 4, n16 = n & 15;
    *(uint4*)(xb + ((((size_t)(b * 512 + nt)) * 64 + kc) * 16 + n16) * 8) =
        make_uint4(pk[0], pk[1], pk[2], pk[3]);
}

// ---------------- kv = W_kv @ input via bf16 MFMA (no LDS, no barriers) -----
// block = 4 waves; wave = 16 rows (M-tile) x 128 cols (8 N-tiles); K = 512.
__global__ __launch_bounds__(256) void kv_gemm_mfma(
    const unsigned short* __restrict__ xb, const unsigned short* __restrict__ wkb,
    float* __restrict__ kv) {
    int b  = blockIdx.z;
    int mt = blockIdx.y;
    int lane = threadIdx.x & 63, wv = threadIdx.x >> 6;
    int rc = lane & 15, kg = lane >> 4;
    int n0 = blockIdx.x * 512 + wv * 128;
    int nt0 = n0 >> 4;
    const unsigned short* ap = wkb + (((size_t)(mt * 64 + kg)) * 16 + rc) * 8;
    const unsigned short* bp = xb + ((((size_t)(b * 512 + nt0)) * 64 + kg) * 16 + rc) * 8;
    f32x4 acc[8];
    #pragma unroll
    for (int j = 0; j < 8; ++j) acc[j] = (f32x4){0.f, 0.f, 0.f, 0.f};
    #pragma unroll 1
    for (int ks = 0; ks < 16; ++ks) {
        bf16x8 a = *(const bf16x8*)(ap + ks * 512);
        #pragma unroll
        for (int j = 0; j < 8; ++j) {
            bf16x8 bfr = *(const bf16x8*)(bp + (size_t)j * 8192 + ks * 512);
            acc[j] = __builtin_amdgcn_mfma_f32_16x16x32_bf16(a, bfr, acc[j], 0, 0, 0);
        }
    }
    // D layout: col = lane&15, row = (lane>>4)*4 + reg
    #pragma unroll
    for (int j = 0; j < 8; ++j) {
        int col = n0 + j * 16 + rc;
        #pragma unroll
        for (int r = 0; r < 4; ++r) {
            int m = mt * 16 + kg * 4 + r;
            if (m < CO_) kv[((size_t)b * CO_ + m) * N_ + col] = acc[j][r];
        }
    }
}

// ---------------- per-(b,channel) mean / rsig over N ------------------------
__global__ __launch_bounds__(256) void stats_kernel(
    const float* __restrict__ x, float* __restrict__ mean, float* __restrict__ rsig) {
    int bc = blockIdx.x;
    const float* p = x + (size_t)bc * N_;
    float s = 0.f, s2 = 0.f;
    for (int i = threadIdx.x; i < N_; i += 256) {
        float v = p[i]; s += v; s2 = fmaf(v, v, s2);
    }
    #pragma unroll
    for (int off = 32; off; off >>= 1) { s += __shfl_down(s, off); s2 += __shfl_down(s2, off); }
    __shared__ float ls[4], ls2[4];
    int wid = threadIdx.x >> 6;
    if ((threadIdx.x & 63) == 0) { ls[wid] = s; ls2[wid] = s2; }
    __syncthreads();
    if (threadIdx.x == 0) {
        float S = ls[0] + ls[1] + ls[2] + ls[3];
        float S2 = ls2[0] + ls2[1] + ls2[2] + ls2[3];
        float mu = S * (1.f / N_);
        float var = S2 * (1.f / N_) - mu * mu;
        mean[bc] = mu;
        rsig[bc] = rsqrtf(var + EPS_);
    }
}

// ---------------- point prep: AdaIN + transform + tanh + interp + count -----
__global__ __launch_bounds__(256) void point_prep(
    const float* __restrict__ kv, const float* __restrict__ mean_kv,
    const float* __restrict__ rsig_kv, const float* __restrict__ hk,
    const float* __restrict__ hv, const float* __restrict__ orig,
    const float* __restrict__ scale_p, const float* __restrict__ Tw,
    const float* __restrict__ Tb,
    float4* __restrict__ coordbuf, float* __restrict__ vbuf,
    int* __restrict__ counts) {
    int p = blockIdx.x * 256 + threadIdx.x;
    int n = p & (N_ - 1);
    int bh = p >> 13;
    int h = bh & 7, b = bh >> 3;
    float scl = scale_p[0];

    float pt[3];
    #pragma unroll
    for (int j = 0; j < 3; ++j) {
        int c = h * 3 + j;
        float x  = kv[((size_t)(b * CO_ + c)) * N_ + n];
        float xn = (x - mean_kv[b * CO_ + c]) * rsig_kv[b * CO_ + c];
        float kr = fmaf(1.f + hk[b * 48 + c], xn, hk[b * 48 + 24 + c]);
        pt[j] = fmaf(scl, kr, orig[((size_t)(b * 3 + j)) * N_ + n]);
    }
    int f0[3]; float tt[3];
    #pragma unroll
    for (int i = 0; i < 3; ++i) {
        float key = Tb[h * 3 + i];
        #pragma unroll
        for (int j = 0; j < 3; ++j) key = fmaf(Tw[(h * 3 + i) * 3 + j], pt[j], key);
        float lat = tanhf(key);
        float g = (lat + 1.f) * 0.5f * (float)(S_ - 1);
        float ff = floorf(g);
        ff = fminf(fmaxf(ff, 0.f), 30.f);
        f0[i] = (int)ff;
        tt[i] = fminf(fmaxf(g - ff, 0.f), 1.f);
    }
    coordbuf[p] = make_float4(tt[0], tt[1], tt[2],
                              __int_as_float(f0[0] | (f0[1] << 5) | (f0[2] << 10)));
    atomicAdd(&counts[(bh << 5) + f0[0]], 1);
    float vf[16];
    #pragma unroll
    for (int f = 0; f < F_; ++f) {
        int c = 24 + h * F_ + f;
        float x  = kv[((size_t)(b * CO_ + c)) * N_ + n];
        float xn = (x - mean_kv[b * CO_ + c]) * rsig_kv[b * CO_ + c];
        int cv = h * F_ + f;
        vf[f] = fmaf(1.f + hv[b * 256 + cv], xn, hv[b * 256 + 128 + cv]);
    }
    float4* vb = (float4*)(vbuf + (size_t)p * 16);
    #pragma unroll
    for (int q = 0; q < 4; ++q)
        vb[q] = make_float4(vf[q * 4], vf[q * 4 + 1], vf[q * 4 + 2], vf[q * 4 + 3]);
}

// ---------------- exclusive prefix over the 1024 bins (one wave) ------------
__global__ __launch_bounds__(64) void prefix_bins(
    const int* __restrict__ counts, int* __restrict__ base, int* __restrict__ cursor) {
    int lane = threadIdx.x;
    int local[16], sum = 0;
    #pragma unroll
    for (int i = 0; i < 16; ++i) { local[i] = sum; sum += counts[lane * 16 + i]; }
    int incl = sum;
    #pragma unroll
    for (int off = 1; off < 64; off <<= 1) {
        int v = __shfl_up(incl, off);
        if (lane >= off) incl += v;
    }
    int excl = incl - sum;
    #pragma unroll
    for (int i = 0; i < 16; ++i) {
        int bse = excl + local[i];
        base[lane * 16 + i] = bse;
        cursor[lane * 16 + i] = bse;
    }
    if (lane == 63) base[1024] = excl + sum;
}

// ---------------- scatter point indices into bins ---------------------------
__global__ __launch_bounds__(256) void scatter_pts(
    const float4* __restrict__ coordbuf, int* __restrict__ cursor,
    unsigned short* __restrict__ recs) {
    int p = blockIdx.x * 256 + threadIdx.x;
    int bh = p >> 13;
    int pk = __float_as_int(((const float*)coordbuf)[(size_t)p * 4 + 3]);
    int f0x = pk & 31;
    int slot = atomicAdd(&cursor[(bh << 5) + f0x], 1);
    recs[slot] = (unsigned short)(p & (N_ - 1));
}

// ---------------- splat3: in-block sub-sort by (y,z), register gather -------
__global__ __launch_bounds__(1024) void splat3(
    const float4* __restrict__ coordbuf, const float* __restrict__ vbuf,
    const int* __restrict__ base, const unsigned short* __restrict__ recs,
    unsigned short* __restrict__ zb16) {
    __shared__ int s_cnt[1024];
    __shared__ int s_start[1024];
    __shared__ int s_cur[1024];
    __shared__ unsigned int s_pts[CHUNK_];
    __shared__ unsigned int s_sorted[CHUNK_];
    __shared__ int s_wavesum[16];
    int logical = (blockIdx.x & 7) * 128 + (blockIdx.x >> 3);  // XCD swizzle
    int bh = logical >> 5;
    int x0 = logical & 31;
    int tid = threadIdx.x;
    int y = tid >> 5, zc = tid & 31;
    int bin0 = (bh << 5) + x0;
    int s0 = base[bin0], len0 = base[bin0 + 1] - s0;
    int s1 = 0, len1 = 0;
    if (x0 > 0) { s1 = base[bin0 - 1]; len1 = s0 - s1; }
    int total = len0 + len1;
    const float4* cb = coordbuf + (size_t)bh * N_;
    const float* vb = vbuf + ((size_t)bh * N_) * 16;
    float acc[16];
    #pragma unroll
    for (int i = 0; i < 16; ++i) acc[i] = 0.f;

    for (int c0 = 0; c0 < total; c0 += CHUNK_) {
        int cl = min(CHUNK_, total - c0);
        s_cnt[tid] = 0;
        __syncthreads();
        for (int t = tid; t < cl; t += 1024) {
            int tp = c0 + t, n, cx;
            if (tp < len0) { n = recs[s0 + tp]; cx = 0; }
            else           { n = recs[s1 + (tp - len0)]; cx = 1; }
            int pk = __float_as_int(cb[n].w);
            int sb = (((pk >> 5) & 31) << 5) | ((pk >> 10) & 31);
            s_pts[t] = ((unsigned)sb << 16) | ((unsigned)cx << 14) | (unsigned)n;
            atomicAdd(&s_cnt[sb], 1);
        }
        __syncthreads();
        int v = s_cnt[tid];
        int incl = v;
        #pragma unroll
        for (int off = 1; off < 64; off <<= 1) {
            int u = __shfl_up(incl, off);
            if ((tid & 63) >= off) incl += u;
        }
        int wid = tid >> 6;
        if ((tid & 63) == 63) s_wavesum[wid] = incl;
        __syncthreads();
        if (tid < 16) {
            int wv = s_wavesum[tid];
            int wincl = wv;
            #pragma unroll
            for (int off = 1; off < 16; off <<= 1) {
                int u = __shfl_up(wincl, off);
                if (tid >= off) wincl += u;
            }
            s_wavesum[tid] = wincl - wv;
        }
        __syncthreads();
        int excl = incl - v + s_wavesum[wid];
        s_start[tid] = excl;
        s_cur[tid] = excl;
        __syncthreads();
        for (int t = tid; t < cl; t += 1024) {
            unsigned rec = s_pts[t];
            int slot = atomicAdd(&s_cur[rec >> 16], 1);
            s_sorted[slot] = rec;
        }
        __syncthreads();
        #pragma unroll
        for (int sy = 0; sy < 2; ++sy) {
            int yy = y - sy;
            if (yy < 0) continue;
            #pragma unroll
            for (int sz = 0; sz < 2; ++sz) {
                int zz = zc - sz;
                if (zz < 0) continue;
                int sb = (yy << 5) | zz;
                int s = s_start[sb], e = s + s_cnt[sb];
                for (int i = s; i < e; ++i) {
                    unsigned rec = s_sorted[i];
                    int n = rec & 0x3FFF;
                    int cx = (rec >> 14) & 1;
                    float4 c = cb[n];
                    float wx = cx ? c.x : 1.f - c.x;
                    float wy = sy ? c.y : 1.f - c.y;
                    float wz = sz ? c.z : 1.f - c.z;
                    float w = wx * wy * wz;
                    const float4* vp = (const float4*)(vb + (size_t)n * 16);
                    float4 a0 = vp[0], a1 = vp[1], a2 = vp[2], a3 = vp[3];
                    acc[0]  = fmaf(w, a0.x, acc[0]);  acc[1]  = fmaf(w, a0.y, acc[1]);
                    acc[2]  = fmaf(w, a0.z, acc[2]);  acc[3]  = fmaf(w, a0.w, acc[3]);
                    acc[4]  = fmaf(w, a1.x, acc[4]);  acc[5]  = fmaf(w, a1.y, acc[5]);
                    acc[6]  = fmaf(w, a1.z, acc[6]);  acc[7]  = fmaf(w, a1.w, acc[7]);
                    acc[8]  = fmaf(w, a2.x, acc[8]);  acc[9]  = fmaf(w, a2.y, acc[9]);
                    acc[10] = fmaf(w, a2.z, acc[10]); acc[11] = fmaf(w, a2.w, acc[11]);
                    acc[12] = fmaf(w, a3.x, acc[12]); acc[13] = fmaf(w, a3.y, acc[13]);
                    acc[14] = fmaf(w, a3.z, acc[14]); acc[15] = fmaf(w, a3.w, acc[15]);
                }
            }
        }
        __syncthreads();
    }
    unsigned int pk[8];
    #pragma unroll
    for (int q = 0; q < 8; ++q)
        pk[q] = (unsigned)f2bf(acc[2 * q]) | ((unsigned)f2bf(acc[2 * q + 1]) << 16);
    unsigned short* zb = zb16 + (((size_t)bh * S3_ + (x0 << 10) + tid) << 4);
    ((uint4*)zb)[0] = make_uint4(pk[0], pk[1], pk[2], pk[3]);
    ((uint4*)zb)[1] = make_uint4(pk[4], pk[5], pk[6], pk[7]);
}

// ---------------- grouped 3x3x3 conv via bf16 MFMA --------------------------
__global__ __launch_bounds__(256) void conv3d_mfma(
    const unsigned short* __restrict__ zb16, const unsigned short* __restrict__ wb,
    const float* __restrict__ cbias, float* __restrict__ zc) {
    int logical = (blockIdx.x & 7) * 128 + (blockIdx.x >> 3);  // 1024 = 8*128
    int bh = logical >> 5;
    int x  = logical & 31;
    int h = bh & 7;
    int lane = threadIdx.x & 63;
    int wv = threadIdx.x >> 6;
    int rc = lane & 15;
    int kb = lane >> 4;
    int ic0 = (kb & 1) << 3;
    int tsel = kb >> 1;

    bf16x8 bfr[14];
    const unsigned short* wh = wb + h * 28 * 256;
    #pragma unroll
    for (int p = 0; p < 14; ++p) {
        int t = 2 * p + tsel;
        bfr[p] = *(const bf16x8*)(wh + (t * 16 + rc) * 16 + ic0);
    }
    float bias = cbias[h * 16 + rc];
    const unsigned short* zbh = zb16 + ((size_t)bh << 19);
    float* zcb = zc + ((size_t)bh << 19);
    const bf16x8 zerov = {0, 0, 0, 0, 0, 0, 0, 0};

    #pragma unroll 1
    for (int ti = 0; ti < 16; ++ti) {
        int tile = wv * 16 + ti;
        int y = tile >> 1;
        int z0 = (tile & 1) << 4;
        f32x4 acc = {0.f, 0.f, 0.f, 0.f};
        #pragma unroll
        for (int p = 0; p < 14; ++p) {
            int t = 2 * p + tsel;
            int dx = t / 9, r9 = t - dx * 9;
            int dy = r9 / 3, dz = r9 - dy * 3;
            int xx = x + dx - 1, yy = y + dy - 1, zz = z0 + rc + dz - 1;
            bool ok = (t < 27) & (xx >= 0) & (xx < 32) & (yy >= 0) & (yy < 32)
                    & (zz >= 0) & (zz < 32);
            int vox = (((xx << 5) + yy) << 5) + zz;
            const unsigned short* ap = ok ? (zbh + ((size_t)vox << 4) + ic0) : zbh;
            bf16x8 a = *(const bf16x8*)ap;
            a = ok ? a : zerov;
            acc = __builtin_amdgcn_mfma_f32_16x16x32_bf16(a, bfr[p], acc, 0, 0, 0);
        }
        int vbase = (((x << 5) + y) << 5) + z0 + (kb << 2);
        #pragma unroll
        for (int r = 0; r < 4; ++r)
            zcb[(size_t)(vbase + r) * 16 + rc] = acc[r] + bias;
    }
}

// ---------------- slice: weighted gather back to points ---------------------
__global__ __launch_bounds__(256) void slice_vm(
    const float* __restrict__ zc, const float4* __restrict__ coordbuf,
    float* __restrict__ out) {
    int p = blockIdx.x * 256 + threadIdx.x;
    int n = p & (N_ - 1);
    int bh = p >> 13;
    int h = bh & 7, b = bh >> 3;
    float4 c = coordbuf[p];
    int pk = __float_as_int(c.w);
    int f0x = pk & 31, f0y = (pk >> 5) & 31, f0z = (pk >> 10) & 31;
    const float* gb = zc + ((size_t)bh << 19);
    float acc[16];
    #pragma unroll
    for (int f = 0; f < 16; ++f) acc[f] = 0.f;
    #pragma unroll 1
    for (int k = 0; k < 8; ++k) {
        int cx = (k >> 2) & 1, cy = (k >> 1) & 1, cz = k & 1;
        float w = (cx ? c.x : 1.f - c.x) * (cy ? c.y : 1.f - c.y) * (cz ? c.z : 1.f - c.z);
        int vox = (((f0x + cx) << 5) + f0y + cy) * 32 + f0z + cz;
        const float4* ip = (const float4*)(gb + ((size_t)vox << 4));
        float4 a0 = ip[0], a1 = ip[1], a2 = ip[2], a3 = ip[3];
        acc[0]  = fmaf(w, a0.x, acc[0]);  acc[1]  = fmaf(w, a0.y, acc[1]);
        acc[2]  = fmaf(w, a0.z, acc[2]);  acc[3]  = fmaf(w, a0.w, acc[3]);
        acc[4]  = fmaf(w, a1.x, acc[4]);  acc[5]  = fmaf(w, a1.y, acc[5]);
        acc[6]  = fmaf(w, a1.z, acc[6]);  acc[7]  = fmaf(w, a1.w, acc[7]);
        acc[8]  = fmaf(w, a2.x, acc[8]);  acc[9]  = fmaf(w, a2.y, acc[9]);
        acc[10] = fmaf(w, a2.z, acc[10]); acc[11] = fmaf(w, a2.w, acc[11]);
        acc[12] = fmaf(w, a3.x, acc[12]); acc[13] = fmaf(w, a3.y, acc[13]);
        acc[14] = fmaf(w, a3.z, acc[14]); acc[15] = fmaf(w, a3.w, acc[15]);
    }
    #pragma unroll
    for (int f = 0; f < 16; ++f)
        out[(((size_t)(b * HF_ + h * F_ + f)) << 13) + n] = acc[f];
}

// ---------------- final AdaIN + ReLU (in place on d_out) --------------------
__global__ __launch_bounds__(256) void final_adain(
    float* __restrict__ out, const float* __restrict__ mean_o,
    const float* __restrict__ rsig_o, const float* __restrict__ ha) {
    size_t i = (size_t)blockIdx.x * 256 + threadIdx.x;
    int bc = (int)(i >> 13);
    int c = bc & 127, b = bc >> 7;
    float x = out[i];
    float xn = (x - mean_o[bc]) * rsig_o[bc];
    float y = fmaf(1.f + ha[b * 256 + c], xn, ha[b * 256 + 128 + c]);
    out[i] = fmaxf(y, 0.f);
}

extern "C" void kernel_launch(void* const* d_in, const int* in_sizes, int n_in,
                              void* d_out, int out_size, void* d_ws, size_t ws_size,
                              hipStream_t stream) {
    (void)in_sizes; (void)n_in; (void)out_size; (void)ws_size;
    const float* input   = (const float*)d_in[0];
    const float* style   = (const float*)d_in[1];
    const float* orig    = (const float*)d_in[2];
    const float* Wkv     = (const float*)d_in[3];
    const float* kw_w    = (const float*)d_in[4];
    const float* kw_b    = (const float*)d_in[5];
    const float* vw_w    = (const float*)d_in[6];
    const float* vw_b    = (const float*)d_in[7];
    const float* aw_w    = (const float*)d_in[8];
    const float* aw_b    = (const float*)d_in[9];
    const float* scale_p = (const float*)d_in[10];
    const float* Tw      = (const float*)d_in[11];
    const float* Tb      = (const float*)d_in[12];
    const float* conv_w  = (const float*)d_in[13];
    const float* conv_b  = (const float*)d_in[14];
    float* out = (float*)d_out;

    // -------- workspace layout (floats), ~139.4 MB total --------------------
    float* ws = (float*)d_ws;
    float* z        = ws;                        // 64MB region: zb16 lattice [0,32MB) + Xbf [32,64MB)
    float* zc       = ws + 16777216;             // 16,777,216  (64MB) conv output fp32
    float* coordbuf = ws + 2 * 16777216;         //  1,048,576  (float4 per point)
    float* wt       = coordbuf + 1048576;        //  55,296 floats (conv bf16 weights use 112KB)
    float* ha       = wt + 55296;                //      1,024
    float* mean_o   = ha + 1024;                 //        512
    float* rsig_o   = mean_o + 512;              //        512
    float* mean_kv  = rsig_o + 512;              //        608
    float* rsig_kv  = mean_kv + 608;             //        608
    float* hk       = rsig_kv + 608;             //        192
    float* hv       = hk + 192;                  //      1,024
    int*   counts   = (int*)(hv + 1024);         //      1,024 ints
    int*   base     = counts + 1024;             //      1,025 ints
    int*   cursor   = base + 1025;               //      1,024 ints
    unsigned short* recs = (unsigned short*)(cursor + 1024);  // 262,144 u16 (512KB)
    unsigned short* wkb  = recs + 262144;        // 81,920 u16 (160KB) W_kv bf16 frags
    // aliased into zc (dead until conv3d runs):
    float* vbuf = zc;                            //  4,194,304 (16MB) AdaIN'd values
    float* kv   = zc + 4194304;                  //  4,980,736 (19MB)
    unsigned short* zb16 = (unsigned short*)z;             // bf16 lattice (32MB)
    unsigned short* xbf  = (unsigned short*)(z + 8388608); // bf16 input frags (32MB)
    unsigned short* wb16 = (unsigned short*)wt;

    zero_bins<<<1, 1024, 0, stream>>>(counts);
    style_proj<<<B_, 256, 0, stream>>>(style, kw_w, kw_b, vw_w, vw_b, aw_w, aw_b, hk, hv, ha);
    wtrans_bf<<<224, 256, 0, stream>>>(conv_w, wb16);
    wconvert<<<40, 256, 0, stream>>>(Wkv, wkb);
    xconvert<<<8192, 256, 0, stream>>>(input, xbf);
    kv_gemm_mfma<<<dim3(16, 10, B_), 256, 0, stream>>>(xbf, wkb, kv);
    stats_kernel<<<B_ * CO_, 256, 0, stream>>>(kv, mean_kv, rsig_kv);
    point_prep<<<B_ * H_ * N_ / 256, 256, 0, stream>>>(
        kv, mean_kv, rsig_kv, hk, hv, orig, scale_p, Tw, Tb,
        (float4*)coordbuf, vbuf, counts);
    prefix_bins<<<1, 64, 0, stream>>>(counts, base, cursor);
    scatter_pts<<<B_ * H_ * N_ / 256, 256, 0, stream>>>((const float4*)coordbuf, cursor, recs);
    splat3<<<1024, 1024, 0, stream>>>((const float4*)coordbuf, vbuf, base, recs, zb16);
    conv3d_mfma<<<1024, 256, 0, stream>>>(zb16, wb16, conv_b, zc);
    slice_vm<<<B_ * H_ * N_ / 256, 256, 0, stream>>>(zc, (const float4*)coordbuf, out);
    stats_kernel<<<B_ * HF_, 256, 0, stream>>>(out, mean_o, rsig_o);
    final_adain<<<B_ * HF_ * N_ / 256, 256, 0, stream>>>(out, mean_o, rsig_o, ha);
}

// Round 9
// 346.647 us; speedup vs baseline: 2.0062x; 1.0279x over previous
//
#include <hip/hip_runtime.h>
#include <hip/hip_bf16.h>
#include <math.h>

#define B_ 4
#define N_ 8192
#define MD_ 512
#define H_ 8
#define F_ 16
#define S_ 32
#define S3_ 32768
#define L_ 256
#define CO_ 152   // H*(F+3)
#define HF_ 128   // H*F
#define EPS_ 1e-5f
#define CHUNK_ 2048
#define PS_ 34            // padded lattice dim
#define PS2_ 1156         // 34*34
#define PV_ 39304         // 34^3 voxels per (b,h)

typedef __attribute__((ext_vector_type(8))) short bf16x8;
typedef __attribute__((ext_vector_type(4))) float f32x4;

__device__ inline unsigned short f2bf(float f) {   // RNE fp32 -> bf16
    unsigned u = __float_as_uint(f);
    return (unsigned short)((u + 0x7FFFu + ((u >> 16) & 1u)) >> 16);
}

// ---------------- zero kernels ----------------------------------------------
__global__ __launch_bounds__(1024) void zero_bins(int* __restrict__ counts) {
    counts[threadIdx.x] = 0;
}
__global__ __launch_bounds__(256) void zero_pad(float4* __restrict__ p, int n4) {
    int i = blockIdx.x * 256 + threadIdx.x;
    if (i < n4) p[i] = make_float4(0.f, 0.f, 0.f, 0.f);
}

// ---------------- style projections: h = style @ W.T + b --------------------
__global__ __launch_bounds__(256) void style_proj(
    const float* __restrict__ style,
    const float* __restrict__ kw_w, const float* __restrict__ kw_b,
    const float* __restrict__ vw_w, const float* __restrict__ vw_b,
    const float* __restrict__ aw_w, const float* __restrict__ aw_b,
    float* __restrict__ hk, float* __restrict__ hv, float* __restrict__ ha) {
    int b = blockIdx.x;
    const float* st = style + b * L_;
    for (int r = threadIdx.x; r < 48 + 256 + 256; r += 256) {
        const float* wrow; float bias; float* dst; int j;
        if (r < 48)       { j = r;       wrow = kw_w + j * L_; bias = kw_b[j]; dst = hk + b * 48; }
        else if (r < 304) { j = r - 48;  wrow = vw_w + j * L_; bias = vw_b[j]; dst = hv + b * 256; }
        else              { j = r - 304; wrow = aw_w + j * L_; bias = aw_b[j]; dst = ha + b * 256; }
        float acc = bias;
        for (int l = 0; l < L_; ++l) acc = fmaf(st[l], wrow[l], acc);
        dst[j] = acc;
    }
}

// ---------------- conv weights -> bf16 [h][28 taps][oc][ic] (tap 27 = 0) ----
__global__ __launch_bounds__(256) void wtrans_bf(const float* __restrict__ cw,
                                                 unsigned short* __restrict__ wb) {
    int i = blockIdx.x * 256 + threadIdx.x;   // 8*28*16*16 = 57344 total
    if (i >= 57344) return;
    int ic  = i & 15;
    int oc  = (i >> 4) & 15;
    int tap = (i >> 8) % 28;
    int h   = (i >> 8) / 28;
    float v = (tap < 27) ? cw[(((h * 16 + oc) * 16 + ic) * 27) + tap] : 0.f;
    wb[i] = f2bf(v);
}

// ---------------- W_kv -> bf16 fragment layout [mt(10)][kc(64)][r16][k8] ----
__global__ __launch_bounds__(256) void wconvert(
    const float* __restrict__ Wkv, unsigned short* __restrict__ wkb) {
    int i = blockIdx.x * 256 + threadIdx.x;   // 10*64*16 = 10240
    if (i >= 10240) return;
    int r  = i & 15;
    int kc = (i >> 4) & 63;
    int mt = i >> 10;
    int row = mt * 16 + r;
    unsigned int pk[4];
    #pragma unroll
    for (int j = 0; j < 4; ++j) {
        float v0 = (row < CO_) ? Wkv[(size_t)row * MD_ + kc * 8 + 2 * j] : 0.f;
        float v1 = (row < CO_) ? Wkv[(size_t)row * MD_ + kc * 8 + 2 * j + 1] : 0.f;
        pk[j] = (unsigned)f2bf(v0) | ((unsigned)f2bf(v1) << 16);
    }
    *(uint4*)(wkb + (((size_t)(mt * 64 + kc)) * 16 + r) * 8) =
        make_uint4(pk[0], pk[1], pk[2], pk[3]);
}

// ---------------- input -> bf16 fragment layout [b][nt(512)][kc(64)][n16][k8]
__global__ __launch_bounds__(256) void xconvert(
    const float* __restrict__ X, unsigned short* __restrict__ xb) {
    int i = blockIdx.x * 256 + threadIdx.x;   // 4*64*8192 = 2,097,152
    int n  = i & (N_ - 1);
    int kc = (i >> 13) & 63;
    int b  = i >> 19;
    const float* xp = X + ((size_t)b * MD_ + kc * 8) * N_ + n;
    unsigned int pk[4];
    #pragma unroll
    for (int j = 0; j < 4; ++j) {
        float v0 = xp[(size_t)(2 * j) * N_];
        float v1 = xp[(size_t)(2 * j + 1) * N_];
        pk[j] = (unsigned)f2bf(v0) | ((unsigned)f2bf(v1) << 16);
    }
    int nt = n >> 4, n16 = n & 15;
    *(uint4*)(xb + ((((size_t)(b * 512 + nt)) * 64 + kc) * 16 + n16) * 8) =
        make_uint4(pk[0], pk[1], pk[2], pk[3]);
}

// ---------------- kv = W_kv @ input via bf16 MFMA (no LDS, no barriers) -----
__global__ __launch_bounds__(256) void kv_gemm_mfma(
    const unsigned short* __restrict__ xb, const unsigned short* __restrict__ wkb,
    float* __restrict__ kv) {
    int b  = blockIdx.z;
    int mt = blockIdx.y;
    int lane = threadIdx.x & 63, wv = threadIdx.x >> 6;
    int rc = lane & 15, kg = lane >> 4;
    int n0 = blockIdx.x * 512 + wv * 128;
    int nt0 = n0 >> 4;
    const unsigned short* ap = wkb + (((size_t)(mt * 64 + kg)) * 16 + rc) * 8;
    const unsigned short* bp = xb + ((((size_t)(b * 512 + nt0)) * 64 + kg) * 16 + rc) * 8;
    f32x4 acc[8];
    #pragma unroll
    for (int j = 0; j < 8; ++j) acc[j] = (f32x4){0.f, 0.f, 0.f, 0.f};
    #pragma unroll 1
    for (int ks = 0; ks < 16; ++ks) {
        bf16x8 a = *(const bf16x8*)(ap + ks * 512);
        #pragma unroll
        for (int j = 0; j < 8; ++j) {
            bf16x8 bfr = *(const bf16x8*)(bp + (size_t)j * 8192 + ks * 512);
            acc[j] = __builtin_amdgcn_mfma_f32_16x16x32_bf16(a, bfr, acc[j], 0, 0, 0);
        }
    }
    #pragma unroll
    for (int j = 0; j < 8; ++j) {
        int col = n0 + j * 16 + rc;
        #pragma unroll
        for (int r = 0; r < 4; ++r) {
            int m = mt * 16 + kg * 4 + r;
            if (m < CO_) kv[((size_t)b * CO_ + m) * N_ + col] = acc[j][r];
        }
    }
}

// ---------------- per-(b,channel) mean / rsig over N ------------------------
__global__ __launch_bounds__(256) void stats_kernel(
    const float* __restrict__ x, float* __restrict__ mean, float* __restrict__ rsig) {
    int bc = blockIdx.x;
    const float* p = x + (size_t)bc * N_;
    float s = 0.f, s2 = 0.f;
    for (int i = threadIdx.x; i < N_; i += 256) {
        float v = p[i]; s += v; s2 = fmaf(v, v, s2);
    }
    #pragma unroll
    for (int off = 32; off; off >>= 1) { s += __shfl_down(s, off); s2 += __shfl_down(s2, off); }
    __shared__ float ls[4], ls2[4];
    int wid = threadIdx.x >> 6;
    if ((threadIdx.x & 63) == 0) { ls[wid] = s; ls2[wid] = s2; }
    __syncthreads();
    if (threadIdx.x == 0) {
        float S = ls[0] + ls[1] + ls[2] + ls[3];
        float S2 = ls2[0] + ls2[1] + ls2[2] + ls2[3];
        float mu = S * (1.f / N_);
        float var = S2 * (1.f / N_) - mu * mu;
        mean[bc] = mu;
        rsig[bc] = rsqrtf(var + EPS_);
    }
}

// ---------------- point prep: AdaIN + transform + tanh + interp + count -----
__global__ __launch_bounds__(256) void point_prep(
    const float* __restrict__ kv, const float* __restrict__ mean_kv,
    const float* __restrict__ rsig_kv, const float* __restrict__ hk,
    const float* __restrict__ hv, const float* __restrict__ orig,
    const float* __restrict__ scale_p, const float* __restrict__ Tw,
    const float* __restrict__ Tb,
    float4* __restrict__ coordbuf, float* __restrict__ vbuf,
    int* __restrict__ counts) {
    int p = blockIdx.x * 256 + threadIdx.x;
    int n = p & (N_ - 1);
    int bh = p >> 13;
    int h = bh & 7, b = bh >> 3;
    float scl = scale_p[0];

    float pt[3];
    #pragma unroll
    for (int j = 0; j < 3; ++j) {
        int c = h * 3 + j;
        float x  = kv[((size_t)(b * CO_ + c)) * N_ + n];
        float xn = (x - mean_kv[b * CO_ + c]) * rsig_kv[b * CO_ + c];
        float kr = fmaf(1.f + hk[b * 48 + c], xn, hk[b * 48 + 24 + c]);
        pt[j] = fmaf(scl, kr, orig[((size_t)(b * 3 + j)) * N_ + n]);
    }
    int f0[3]; float tt[3];
    #pragma unroll
    for (int i = 0; i < 3; ++i) {
        float key = Tb[h * 3 + i];
        #pragma unroll
        for (int j = 0; j < 3; ++j) key = fmaf(Tw[(h * 3 + i) * 3 + j], pt[j], key);
        float lat = tanhf(key);
        float g = (lat + 1.f) * 0.5f * (float)(S_ - 1);
        float ff = floorf(g);
        ff = fminf(fmaxf(ff, 0.f), 30.f);
        f0[i] = (int)ff;
        tt[i] = fminf(fmaxf(g - ff, 0.f), 1.f);
    }
    coordbuf[p] = make_float4(tt[0], tt[1], tt[2],
                              __int_as_float(f0[0] | (f0[1] << 5) | (f0[2] << 10)));
    atomicAdd(&counts[(bh << 5) + f0[0]], 1);
    float vf[16];
    #pragma unroll
    for (int f = 0; f < F_; ++f) {
        int c = 24 + h * F_ + f;
        float x  = kv[((size_t)(b * CO_ + c)) * N_ + n];
        float xn = (x - mean_kv[b * CO_ + c]) * rsig_kv[b * CO_ + c];
        int cv = h * F_ + f;
        vf[f] = fmaf(1.f + hv[b * 256 + cv], xn, hv[b * 256 + 128 + cv]);
    }
    float4* vb = (float4*)(vbuf + (size_t)p * 16);
    #pragma unroll
    for (int q = 0; q < 4; ++q)
        vb[q] = make_float4(vf[q * 4], vf[q * 4 + 1], vf[q * 4 + 2], vf[q * 4 + 3]);
}

// ---------------- exclusive prefix over the 1024 bins (one wave) ------------
__global__ __launch_bounds__(64) void prefix_bins(
    const int* __restrict__ counts, int* __restrict__ base, int* __restrict__ cursor) {
    int lane = threadIdx.x;
    int local[16], sum = 0;
    #pragma unroll
    for (int i = 0; i < 16; ++i) { local[i] = sum; sum += counts[lane * 16 + i]; }
    int incl = sum;
    #pragma unroll
    for (int off = 1; off < 64; off <<= 1) {
        int v = __shfl_up(incl, off);
        if (lane >= off) incl += v;
    }
    int excl = incl - sum;
    #pragma unroll
    for (int i = 0; i < 16; ++i) {
        int bse = excl + local[i];
        base[lane * 16 + i] = bse;
        cursor[lane * 16 + i] = bse;
    }
    if (lane == 63) base[1024] = excl + sum;
}

// ---------------- scatter point indices into bins ---------------------------
__global__ __launch_bounds__(256) void scatter_pts(
    const float4* __restrict__ coordbuf, int* __restrict__ cursor,
    unsigned short* __restrict__ recs) {
    int p = blockIdx.x * 256 + threadIdx.x;
    int bh = p >> 13;
    int pk = __float_as_int(((const float*)coordbuf)[(size_t)p * 4 + 3]);
    int f0x = pk & 31;
    int slot = atomicAdd(&cursor[(bh << 5) + f0x], 1);
    recs[slot] = (unsigned short)(p & (N_ - 1));
}

// ---------------- splat3: in-block sub-sort by (y,z), register gather -------
// Output lattice written bf16 into the PADDED [34][34][34] interior.
__global__ __launch_bounds__(1024) void splat3(
    const float4* __restrict__ coordbuf, const float* __restrict__ vbuf,
    const int* __restrict__ base, const unsigned short* __restrict__ recs,
    unsigned short* __restrict__ zb16p) {
    __shared__ int s_cnt[1024];
    __shared__ int s_start[1024];
    __shared__ int s_cur[1024];
    __shared__ unsigned int s_pts[CHUNK_];
    __shared__ unsigned int s_sorted[CHUNK_];
    __shared__ int s_wavesum[16];
    int logical = (blockIdx.x & 7) * 128 + (blockIdx.x >> 3);  // XCD swizzle
    int bh = logical >> 5;
    int x0 = logical & 31;
    int tid = threadIdx.x;
    int y = tid >> 5, zc = tid & 31;
    int bin0 = (bh << 5) + x0;
    int s0 = base[bin0], len0 = base[bin0 + 1] - s0;
    int s1 = 0, len1 = 0;
    if (x0 > 0) { s1 = base[bin0 - 1]; len1 = s0 - s1; }
    int total = len0 + len1;
    const float4* cb = coordbuf + (size_t)bh * N_;
    const float* vb = vbuf + ((size_t)bh * N_) * 16;
    float acc[16];
    #pragma unroll
    for (int i = 0; i < 16; ++i) acc[i] = 0.f;

    for (int c0 = 0; c0 < total; c0 += CHUNK_) {
        int cl = min(CHUNK_, total - c0);
        s_cnt[tid] = 0;
        __syncthreads();
        for (int t = tid; t < cl; t += 1024) {
            int tp = c0 + t, n, cx;
            if (tp < len0) { n = recs[s0 + tp]; cx = 0; }
            else           { n = recs[s1 + (tp - len0)]; cx = 1; }
            int pk = __float_as_int(cb[n].w);
            int sb = (((pk >> 5) & 31) << 5) | ((pk >> 10) & 31);
            s_pts[t] = ((unsigned)sb << 16) | ((unsigned)cx << 14) | (unsigned)n;
            atomicAdd(&s_cnt[sb], 1);
        }
        __syncthreads();
        int v = s_cnt[tid];
        int incl = v;
        #pragma unroll
        for (int off = 1; off < 64; off <<= 1) {
            int u = __shfl_up(incl, off);
            if ((tid & 63) >= off) incl += u;
        }
        int wid = tid >> 6;
        if ((tid & 63) == 63) s_wavesum[wid] = incl;
        __syncthreads();
        if (tid < 16) {
            int wv = s_wavesum[tid];
            int wincl = wv;
            #pragma unroll
            for (int off = 1; off < 16; off <<= 1) {
                int u = __shfl_up(wincl, off);
                if (tid >= off) wincl += u;
            }
            s_wavesum[tid] = wincl - wv;
        }
        __syncthreads();
        int excl = incl - v + s_wavesum[wid];
        s_start[tid] = excl;
        s_cur[tid] = excl;
        __syncthreads();
        for (int t = tid; t < cl; t += 1024) {
            unsigned rec = s_pts[t];
            int slot = atomicAdd(&s_cur[rec >> 16], 1);
            s_sorted[slot] = rec;
        }
        __syncthreads();
        #pragma unroll
        for (int sy = 0; sy < 2; ++sy) {
            int yy = y - sy;
            if (yy < 0) continue;
            #pragma unroll
            for (int sz = 0; sz < 2; ++sz) {
                int zz = zc - sz;
                if (zz < 0) continue;
                int sb = (yy << 5) | zz;
                int s = s_start[sb], e = s + s_cnt[sb];
                for (int i = s; i < e; ++i) {
                    unsigned rec = s_sorted[i];
                    int n = rec & 0x3FFF;
                    int cx = (rec >> 14) & 1;
                    float4 c = cb[n];
                    float wx = cx ? c.x : 1.f - c.x;
                    float wy = sy ? c.y : 1.f - c.y;
                    float wz = sz ? c.z : 1.f - c.z;
                    float w = wx * wy * wz;
                    const float4* vp = (const float4*)(vb + (size_t)n * 16);
                    float4 a0 = vp[0], a1 = vp[1], a2 = vp[2], a3 = vp[3];
                    acc[0]  = fmaf(w, a0.x, acc[0]);  acc[1]  = fmaf(w, a0.y, acc[1]);
                    acc[2]  = fmaf(w, a0.z, acc[2]);  acc[3]  = fmaf(w, a0.w, acc[3]);
                    acc[4]  = fmaf(w, a1.x, acc[4]);  acc[5]  = fmaf(w, a1.y, acc[5]);
                    acc[6]  = fmaf(w, a1.z, acc[6]);  acc[7]  = fmaf(w, a1.w, acc[7]);
                    acc[8]  = fmaf(w, a2.x, acc[8]);  acc[9]  = fmaf(w, a2.y, acc[9]);
                    acc[10] = fmaf(w, a2.z, acc[10]); acc[11] = fmaf(w, a2.w, acc[11]);
                    acc[12] = fmaf(w, a3.x, acc[12]); acc[13] = fmaf(w, a3.y, acc[13]);
                    acc[14] = fmaf(w, a3.z, acc[14]); acc[15] = fmaf(w, a3.w, acc[15]);
                }
            }
        }
        __syncthreads();
    }
    unsigned int pk[8];
    #pragma unroll
    for (int q = 0; q < 8; ++q)
        pk[q] = (unsigned)f2bf(acc[2 * q]) | ((unsigned)f2bf(acc[2 * q + 1]) << 16);
    int pv = ((x0 + 1) * PS_ + y + 1) * PS_ + zc + 1;
    unsigned short* zb = zb16p + ((size_t)bh * PV_ + pv) * 16;
    ((uint4*)zb)[0] = make_uint4(pk[0], pk[1], pk[2], pk[3]);
    ((uint4*)zb)[1] = make_uint4(pk[4], pk[5], pk[6], pk[7]);
}

// ---------------- grouped 3x3x3 conv via bf16 MFMA on PADDED lattice --------
// No bounds checks: halo zeros. Per-lane tap offsets precomputed once.
__global__ __launch_bounds__(256) void conv3d_mfma(
    const unsigned short* __restrict__ zp, const unsigned short* __restrict__ wb,
    const float* __restrict__ cbias, float* __restrict__ zc) {
    int logical = (blockIdx.x & 7) * 128 + (blockIdx.x >> 3);  // 1024 = 8*128
    int bh = logical >> 5;
    int x  = logical & 31;
    int h = bh & 7;
    int lane = threadIdx.x & 63;
    int wv = threadIdx.x >> 6;
    int rc = lane & 15;
    int kb = lane >> 4;
    int ic0 = (kb & 1) << 3;
    int tsel = kb >> 1;

    bf16x8 bfr[14];
    const unsigned short* wh = wb + h * 28 * 256;
    int doff[14];
    #pragma unroll
    for (int p = 0; p < 14; ++p) {
        int t = 2 * p + tsel;
        bfr[p] = *(const bf16x8*)(wh + (t * 16 + rc) * 16 + ic0);
        int dx = t / 9, r9 = t - dx * 9;
        int dy = r9 / 3, dz = r9 - dy * 3;
        doff[p] = (t < 27) ? ((dx - 1) * PS2_ + (dy - 1) * PS_ + (dz - 1)) * 32 : 0;
    }
    float bias = cbias[h * 16 + rc];
    const char* zb = (const char*)(zp + (size_t)bh * PV_ * 16);
    float* zcb = zc + ((size_t)bh << 19);
    int basex = (x + 1) * PS2_;

    #pragma unroll 1
    for (int ti = 0; ti < 16; ++ti) {
        int tile = wv * 16 + ti;
        int y = tile >> 1;
        int z0 = (tile & 1) << 4;
        int vbase = (basex + (y + 1) * PS_ + z0 + rc + 1) * 32 + ic0 * 2;
        f32x4 acc = {0.f, 0.f, 0.f, 0.f};
        #pragma unroll
        for (int p = 0; p < 14; ++p) {
            bf16x8 a = *(const bf16x8*)(zb + vbase + doff[p]);
            acc = __builtin_amdgcn_mfma_f32_16x16x32_bf16(a, bfr[p], acc, 0, 0, 0);
        }
        int vout = (((x << 5) + y) << 5) + z0 + (kb << 2);
        #pragma unroll
        for (int r = 0; r < 4; ++r)
            zcb[(size_t)(vout + r) * 16 + rc] = acc[r] + bias;
    }
}

// ---------------- slice: weighted gather back to points ---------------------
__global__ __launch_bounds__(256) void slice_vm(
    const float* __restrict__ zc, const float4* __restrict__ coordbuf,
    float* __restrict__ out) {
    int p = blockIdx.x * 256 + threadIdx.x;
    int n = p & (N_ - 1);
    int bh = p >> 13;
    int h = bh & 7, b = bh >> 3;
    float4 c = coordbuf[p];
    int pk = __float_as_int(c.w);
    int f0x = pk & 31, f0y = (pk >> 5) & 31, f0z = (pk >> 10) & 31;
    const float* gb = zc + ((size_t)bh << 19);
    float acc[16];
    #pragma unroll
    for (int f = 0; f < 16; ++f) acc[f] = 0.f;
    #pragma unroll 1
    for (int k = 0; k < 8; ++k) {
        int cx = (k >> 2) & 1, cy = (k >> 1) & 1, cz = k & 1;
        float w = (cx ? c.x : 1.f - c.x) * (cy ? c.y : 1.f - c.y) * (cz ? c.z : 1.f - c.z);
        int vox = (((f0x + cx) << 5) + f0y + cy) * 32 + f0z + cz;
        const float4* ip = (const float4*)(gb + ((size_t)vox << 4));
        float4 a0 = ip[0], a1 = ip[1], a2 = ip[2], a3 = ip[3];
        acc[0]  = fmaf(w, a0.x, acc[0]);  acc[1]  = fmaf(w, a0.y, acc[1]);
        acc[2]  = fmaf(w, a0.z, acc[2]);  acc[3]  = fmaf(w, a0.w, acc[3]);
        acc[4]  = fmaf(w, a1.x, acc[4]);  acc[5]  = fmaf(w, a1.y, acc[5]);
        acc[6]  = fmaf(w, a1.z, acc[6]);  acc[7]  = fmaf(w, a1.w, acc[7]);
        acc[8]  = fmaf(w, a2.x, acc[8]);  acc[9]  = fmaf(w, a2.y, acc[9]);
        acc[10] = fmaf(w, a2.z, acc[10]); acc[11] = fmaf(w, a2.w, acc[11]);
        acc[12] = fmaf(w, a3.x, acc[12]); acc[13] = fmaf(w, a3.y, acc[13]);
        acc[14] = fmaf(w, a3.z, acc[14]); acc[15] = fmaf(w, a3.w, acc[15]);
    }
    #pragma unroll
    for (int f = 0; f < 16; ++f)
        out[(((size_t)(b * HF_ + h * F_ + f)) << 13) + n] = acc[f];
}

// ---------------- final AdaIN + ReLU (in place on d_out) --------------------
__global__ __launch_bounds__(256) void final_adain(
    float* __restrict__ out, const float* __restrict__ mean_o,
    const float* __restrict__ rsig_o, const float* __restrict__ ha) {
    size_t i = (size_t)blockIdx.x * 256 + threadIdx.x;
    int bc = (int)(i >> 13);
    int c = bc & 127, b = bc >> 7;
    float x = out[i];
    float xn = (x - mean_o[bc]) * rsig_o[bc];
    float y = fmaf(1.f + ha[b * 256 + c], xn, ha[b * 256 + 128 + c]);
    out[i] = fmaxf(y, 0.f);
}

extern "C" void kernel_launch(void* const* d_in, const int* in_sizes, int n_in,
                              void* d_out, int out_size, void* d_ws, size_t ws_size,
                              hipStream_t stream) {
    (void)in_sizes; (void)n_in; (void)out_size; (void)ws_size;
    const float* input   = (const float*)d_in[0];
    const float* style   = (const float*)d_in[1];
    const float* orig    = (const float*)d_in[2];
    const float* Wkv     = (const float*)d_in[3];
    const float* kw_w    = (const float*)d_in[4];
    const float* kw_b    = (const float*)d_in[5];
    const float* vw_w    = (const float*)d_in[6];
    const float* vw_b    = (const float*)d_in[7];
    const float* aw_w    = (const float*)d_in[8];
    const float* aw_b    = (const float*)d_in[9];
    const float* scale_p = (const float*)d_in[10];
    const float* Tw      = (const float*)d_in[11];
    const float* Tb      = (const float*)d_in[12];
    const float* conv_w  = (const float*)d_in[13];
    const float* conv_b  = (const float*)d_in[14];
    float* out = (float*)d_out;

    // -------- workspace layout (floats), ~146.0 MB total --------------------
    float* ws = (float*)d_ws;
    unsigned short* zb16p = (unsigned short*)ws;     // padded lattice bf16, 10,061,824 floats (40.2MB)
    float* zc       = ws + 10061824;                 // 16,777,216 (64MB) conv output fp32
    float* xbf_f    = ws + 26839040;                 //  8,388,608 (32MB) bf16 input frags
    float* coordbuf = ws + 35227648;                 //  1,048,576
    float* wt       = ws + 36276224;                 //     55,296 (conv bf16 weights, 112KB used)
    float* wkb_f    = ws + 36331520;                 //     40,960 (W_kv bf16 frags, 160KB)
    float* recs_f   = ws + 36372480;                 //    131,072 (262,144 u16)
    float* ha       = ws + 36503552;                 //      1,024
    float* mean_o   = ha + 1024;                     //        512
    float* rsig_o   = mean_o + 512;                  //        512
    float* mean_kv  = rsig_o + 512;                  //        608
    float* rsig_kv  = mean_kv + 608;                 //        608
    float* hk       = rsig_kv + 608;                 //        192
    float* hv       = hk + 192;                      //      1,024
    int*   counts   = (int*)(hv + 1024);             //      1,024 ints
    int*   base     = counts + 1024;                 //      1,025 ints
    int*   cursor   = base + 1025;                   //      1,024 ints
    // aliased into zc (dead before conv3d writes zc):
    float* vbuf = zc;                                //  4,194,304 (16MB)
    float* kv   = zc + 4194304;                      //  4,980,736 (19MB)
    unsigned short* xbf  = (unsigned short*)xbf_f;
    unsigned short* wb16 = (unsigned short*)wt;
    unsigned short* wkb  = (unsigned short*)wkb_f;
    unsigned short* recs = (unsigned short*)recs_f;

    zero_bins<<<1, 1024, 0, stream>>>(counts);
    zero_pad<<<(2515456 + 255) / 256, 256, 0, stream>>>((float4*)zb16p, 2515456);
    style_proj<<<B_, 256, 0, stream>>>(style, kw_w, kw_b, vw_w, vw_b, aw_w, aw_b, hk, hv, ha);
    wtrans_bf<<<224, 256, 0, stream>>>(conv_w, wb16);
    wconvert<<<40, 256, 0, stream>>>(Wkv, wkb);
    xconvert<<<8192, 256, 0, stream>>>(input, xbf);
    kv_gemm_mfma<<<dim3(16, 10, B_), 256, 0, stream>>>(xbf, wkb, kv);
    stats_kernel<<<B_ * CO_, 256, 0, stream>>>(kv, mean_kv, rsig_kv);
    point_prep<<<B_ * H_ * N_ / 256, 256, 0, stream>>>(
        kv, mean_kv, rsig_kv, hk, hv, orig, scale_p, Tw, Tb,
        (float4*)coordbuf, vbuf, counts);
    prefix_bins<<<1, 64, 0, stream>>>(counts, base, cursor);
    scatter_pts<<<B_ * H_ * N_ / 256, 256, 0, stream>>>((const float4*)coordbuf, cursor, recs);
    splat3<<<1024, 1024, 0, stream>>>((const float4*)coordbuf, vbuf, base, recs, zb16p);
    conv3d_mfma<<<1024, 256, 0, stream>>>(zb16p, wb16, conv_b, zc);
    slice_vm<<<B_ * H_ * N_ / 256, 256, 0, stream>>>(zc, (const float4*)coordbuf, out);
    stats_kernel<<<B_ * HF_, 256, 0, stream>>>(out, mean_o, rsig_o);
    final_adain<<<B_ * HF_ * N_ / 256, 256, 0, stream>>>(out, mean_o, rsig_o, ha);
}

// Round 10
// 340.109 us; speedup vs baseline: 2.0448x; 1.0192x over previous
//
#include <hip/hip_runtime.h>
#include <hip/hip_bf16.h>
#include <math.h>

#define B_ 4
#define N_ 8192
#define MD_ 512
#define H_ 8
#define F_ 16
#define S_ 32
#define S3_ 32768
#define L_ 256
#define CO_ 152   // H*(F+3)
#define HF_ 128   // H*F
#define EPS_ 1e-5f
#define CHUNK_ 2048
#define PS_ 34            // padded lattice dim
#define PS2_ 1156         // 34*34
#define PV_ 39304         // 34^3 voxels per (b,h)
#define HALO_ 6536        // 34^3 - 32^3

typedef __attribute__((ext_vector_type(8))) short bf16x8;
typedef __attribute__((ext_vector_type(4))) float f32x4;

__device__ inline unsigned short f2bf(float f) {   // RNE fp32 -> bf16
    unsigned u = __float_as_uint(f);
    return (unsigned short)((u + 0x7FFFu + ((u >> 16) & 1u)) >> 16);
}

// ---------------- zero kernels ----------------------------------------------
__global__ __launch_bounds__(1024) void zero_bins(int* __restrict__ counts) {
    counts[threadIdx.x] = 0;
}
// zero only the halo shell of each padded lattice (interior fully written by splat3)
__global__ __launch_bounds__(256) void zero_halo(unsigned short* __restrict__ zb16p) {
    int i = blockIdx.x * 256 + threadIdx.x;     // 32 * 6536 total
    if (i >= 32 * HALO_) return;
    int bh = i / HALO_;
    int j  = i - bh * HALO_;
    int x, y, z;
    if (j < 2312) {                 // x = 0 or 33 full planes
        x = (j / 1156) * 33;
        int rem = j % 1156;
        y = rem / 34; z = rem % 34;
    } else {
        int k = j - 2312;
        x = 1 + k / 132;
        int m = k % 132;
        if (m < 34)       { y = 0;  z = m; }
        else if (m < 68)  { y = 33; z = m - 34; }
        else if (m < 100) { y = m - 68 + 1;  z = 0; }
        else              { y = m - 100 + 1; z = 33; }
    }
    int pv = (x * PS_ + y) * PS_ + z;
    unsigned short* p = zb16p + ((size_t)bh * PV_ + pv) * 16;
    ((uint4*)p)[0] = make_uint4(0, 0, 0, 0);
    ((uint4*)p)[1] = make_uint4(0, 0, 0, 0);
}

// ---------------- style projections: h = style @ W.T + b --------------------
__global__ __launch_bounds__(256) void style_proj(
    const float* __restrict__ style,
    const float* __restrict__ kw_w, const float* __restrict__ kw_b,
    const float* __restrict__ vw_w, const float* __restrict__ vw_b,
    const float* __restrict__ aw_w, const float* __restrict__ aw_b,
    float* __restrict__ hk, float* __restrict__ hv, float* __restrict__ ha) {
    int b = blockIdx.x;
    const float* st = style + b * L_;
    for (int r = threadIdx.x; r < 48 + 256 + 256; r += 256) {
        const float* wrow; float bias; float* dst; int j;
        if (r < 48)       { j = r;       wrow = kw_w + j * L_; bias = kw_b[j]; dst = hk + b * 48; }
        else if (r < 304) { j = r - 48;  wrow = vw_w + j * L_; bias = vw_b[j]; dst = hv + b * 256; }
        else              { j = r - 304; wrow = aw_w + j * L_; bias = aw_b[j]; dst = ha + b * 256; }
        float acc = bias;
        for (int l = 0; l < L_; ++l) acc = fmaf(st[l], wrow[l], acc);
        dst[j] = acc;
    }
}

// ---------------- conv weights -> bf16 [h][28 taps][oc][ic] (tap 27 = 0) ----
__global__ __launch_bounds__(256) void wtrans_bf(const float* __restrict__ cw,
                                                 unsigned short* __restrict__ wb) {
    int i = blockIdx.x * 256 + threadIdx.x;   // 8*28*16*16 = 57344 total
    if (i >= 57344) return;
    int ic  = i & 15;
    int oc  = (i >> 4) & 15;
    int tap = (i >> 8) % 28;
    int h   = (i >> 8) / 28;
    float v = (tap < 27) ? cw[(((h * 16 + oc) * 16 + ic) * 27) + tap] : 0.f;
    wb[i] = f2bf(v);
}

// ---------------- W_kv -> bf16 fragment layout [mt(10)][kc(64)][r16][k8] ----
__global__ __launch_bounds__(256) void wconvert(
    const float* __restrict__ Wkv, unsigned short* __restrict__ wkb) {
    int i = blockIdx.x * 256 + threadIdx.x;   // 10*64*16 = 10240
    if (i >= 10240) return;
    int r  = i & 15;
    int kc = (i >> 4) & 63;
    int mt = i >> 10;
    int row = mt * 16 + r;
    unsigned int pk[4];
    #pragma unroll
    for (int j = 0; j < 4; ++j) {
        float v0 = (row < CO_) ? Wkv[(size_t)row * MD_ + kc * 8 + 2 * j] : 0.f;
        float v1 = (row < CO_) ? Wkv[(size_t)row * MD_ + kc * 8 + 2 * j + 1] : 0.f;
        pk[j] = (unsigned)f2bf(v0) | ((unsigned)f2bf(v1) << 16);
    }
    *(uint4*)(wkb + (((size_t)(mt * 64 + kc)) * 16 + r) * 8) =
        make_uint4(pk[0], pk[1], pk[2], pk[3]);
}

// ---------------- input -> bf16 fragment layout [b][nt(512)][kc(64)][n16][k8]
__global__ __launch_bounds__(256) void xconvert(
    const float* __restrict__ X, unsigned short* __restrict__ xb) {
    int i = blockIdx.x * 256 + threadIdx.x;   // 4*64*8192 = 2,097,152
    int n  = i & (N_ - 1);
    int kc = (i >> 13) & 63;
    int b  = i >> 19;
    const float* xp = X + ((size_t)b * MD_ + kc * 8) * N_ + n;
    unsigned int pk[4];
    #pragma unroll
    for (int j = 0; j < 4; ++j) {
        float v0 = xp[(size_t)(2 * j) * N_];
        float v1 = xp[(size_t)(2 * j + 1) * N_];
        pk[j] = (unsigned)f2bf(v0) | ((unsigned)f2bf(v1) << 16);
    }
    int nt = n >> 4, n16 = n & 15;
    *(uint4*)(xb + ((((size_t)(b * 512 + nt)) * 64 + kc) * 16 + n16) * 8) =
        make_uint4(pk[0], pk[1], pk[2], pk[3]);
}

// ---------------- kv = W_kv @ input via bf16 MFMA (no LDS, no barriers) -----
__global__ __launch_bounds__(256) void kv_gemm_mfma(
    const unsigned short* __restrict__ xb, const unsigned short* __restrict__ wkb,
    float* __restrict__ kv) {
    int b  = blockIdx.z;
    int mt = blockIdx.y;
    int lane = threadIdx.x & 63, wv = threadIdx.x >> 6;
    int rc = lane & 15, kg = lane >> 4;
    int n0 = blockIdx.x * 512 + wv * 128;
    int nt0 = n0 >> 4;
    const unsigned short* ap = wkb + (((size_t)(mt * 64 + kg)) * 16 + rc) * 8;
    const unsigned short* bp = xb + ((((size_t)(b * 512 + nt0)) * 64 + kg) * 16 + rc) * 8;
    f32x4 acc[8];
    #pragma unroll
    for (int j = 0; j < 8; ++j) acc[j] = (f32x4){0.f, 0.f, 0.f, 0.f};
    #pragma unroll 1
    for (int ks = 0; ks < 16; ++ks) {
        bf16x8 a = *(const bf16x8*)(ap + ks * 512);
        #pragma unroll
        for (int j = 0; j < 8; ++j) {
            bf16x8 bfr = *(const bf16x8*)(bp + (size_t)j * 8192 + ks * 512);
            acc[j] = __builtin_amdgcn_mfma_f32_16x16x32_bf16(a, bfr, acc[j], 0, 0, 0);
        }
    }
    #pragma unroll
    for (int j = 0; j < 8; ++j) {
        int col = n0 + j * 16 + rc;
        #pragma unroll
        for (int r = 0; r < 4; ++r) {
            int m = mt * 16 + kg * 4 + r;
            if (m < CO_) kv[((size_t)b * CO_ + m) * N_ + col] = acc[j][r];
        }
    }
}

// ---------------- per-(b,channel) mean / rsig over N ------------------------
__global__ __launch_bounds__(256) void stats_kernel(
    const float* __restrict__ x, float* __restrict__ mean, float* __restrict__ rsig) {
    int bc = blockIdx.x;
    const float* p = x + (size_t)bc * N_;
    float s = 0.f, s2 = 0.f;
    for (int i = threadIdx.x; i < N_; i += 256) {
        float v = p[i]; s += v; s2 = fmaf(v, v, s2);
    }
    #pragma unroll
    for (int off = 32; off; off >>= 1) { s += __shfl_down(s, off); s2 += __shfl_down(s2, off); }
    __shared__ float ls[4], ls2[4];
    int wid = threadIdx.x >> 6;
    if ((threadIdx.x & 63) == 0) { ls[wid] = s; ls2[wid] = s2; }
    __syncthreads();
    if (threadIdx.x == 0) {
        float S = ls[0] + ls[1] + ls[2] + ls[3];
        float S2 = ls2[0] + ls2[1] + ls2[2] + ls2[3];
        float mu = S * (1.f / N_);
        float var = S2 * (1.f / N_) - mu * mu;
        mean[bc] = mu;
        rsig[bc] = rsqrtf(var + EPS_);
    }
}

// ---------------- point prep: AdaIN + transform + tanh + interp + count -----
__global__ __launch_bounds__(256) void point_prep(
    const float* __restrict__ kv, const float* __restrict__ mean_kv,
    const float* __restrict__ rsig_kv, const float* __restrict__ hk,
    const float* __restrict__ hv, const float* __restrict__ orig,
    const float* __restrict__ scale_p, const float* __restrict__ Tw,
    const float* __restrict__ Tb,
    float4* __restrict__ coordbuf, float* __restrict__ vbuf,
    int* __restrict__ counts) {
    int p = blockIdx.x * 256 + threadIdx.x;
    int n = p & (N_ - 1);
    int bh = p >> 13;
    int h = bh & 7, b = bh >> 3;
    float scl = scale_p[0];

    float pt[3];
    #pragma unroll
    for (int j = 0; j < 3; ++j) {
        int c = h * 3 + j;
        float x  = kv[((size_t)(b * CO_ + c)) * N_ + n];
        float xn = (x - mean_kv[b * CO_ + c]) * rsig_kv[b * CO_ + c];
        float kr = fmaf(1.f + hk[b * 48 + c], xn, hk[b * 48 + 24 + c]);
        pt[j] = fmaf(scl, kr, orig[((size_t)(b * 3 + j)) * N_ + n]);
    }
    int f0[3]; float tt[3];
    #pragma unroll
    for (int i = 0; i < 3; ++i) {
        float key = Tb[h * 3 + i];
        #pragma unroll
        for (int j = 0; j < 3; ++j) key = fmaf(Tw[(h * 3 + i) * 3 + j], pt[j], key);
        float lat = tanhf(key);
        float g = (lat + 1.f) * 0.5f * (float)(S_ - 1);
        float ff = floorf(g);
        ff = fminf(fmaxf(ff, 0.f), 30.f);
        f0[i] = (int)ff;
        tt[i] = fminf(fmaxf(g - ff, 0.f), 1.f);
    }
    coordbuf[p] = make_float4(tt[0], tt[1], tt[2],
                              __int_as_float(f0[0] | (f0[1] << 5) | (f0[2] << 10)));
    atomicAdd(&counts[(bh << 5) + f0[0]], 1);
    float vf[16];
    #pragma unroll
    for (int f = 0; f < F_; ++f) {
        int c = 24 + h * F_ + f;
        float x  = kv[((size_t)(b * CO_ + c)) * N_ + n];
        float xn = (x - mean_kv[b * CO_ + c]) * rsig_kv[b * CO_ + c];
        int cv = h * F_ + f;
        vf[f] = fmaf(1.f + hv[b * 256 + cv], xn, hv[b * 256 + 128 + cv]);
    }
    float4* vb = (float4*)(vbuf + (size_t)p * 16);
    #pragma unroll
    for (int q = 0; q < 4; ++q)
        vb[q] = make_float4(vf[q * 4], vf[q * 4 + 1], vf[q * 4 + 2], vf[q * 4 + 3]);
}

// ---------------- exclusive prefix over the 1024 bins (one wave) ------------
__global__ __launch_bounds__(64) void prefix_bins(
    const int* __restrict__ counts, int* __restrict__ base, int* __restrict__ cursor) {
    int lane = threadIdx.x;
    int local[16], sum = 0;
    #pragma unroll
    for (int i = 0; i < 16; ++i) { local[i] = sum; sum += counts[lane * 16 + i]; }
    int incl = sum;
    #pragma unroll
    for (int off = 1; off < 64; off <<= 1) {
        int v = __shfl_up(incl, off);
        if (lane >= off) incl += v;
    }
    int excl = incl - sum;
    #pragma unroll
    for (int i = 0; i < 16; ++i) {
        int bse = excl + local[i];
        base[lane * 16 + i] = bse;
        cursor[lane * 16 + i] = bse;
    }
    if (lane == 63) base[1024] = excl + sum;
}

// ---------------- scatter point indices into bins ---------------------------
__global__ __launch_bounds__(256) void scatter_pts(
    const float4* __restrict__ coordbuf, int* __restrict__ cursor,
    unsigned short* __restrict__ recs) {
    int p = blockIdx.x * 256 + threadIdx.x;
    int bh = p >> 13;
    int pk = __float_as_int(((const float*)coordbuf)[(size_t)p * 4 + 3]);
    int f0x = pk & 31;
    int slot = atomicAdd(&cursor[(bh << 5) + f0x], 1);
    recs[slot] = (unsigned short)(p & (N_ - 1));
}

// ---------------- splat3: in-block sub-sort by (y,z), register gather -------
// Output lattice written bf16 into the PADDED [34][34][34] interior.
__global__ __launch_bounds__(1024) void splat3(
    const float4* __restrict__ coordbuf, const float* __restrict__ vbuf,
    const int* __restrict__ base, const unsigned short* __restrict__ recs,
    unsigned short* __restrict__ zb16p) {
    __shared__ int s_cnt[1024];
    __shared__ int s_start[1024];
    __shared__ int s_cur[1024];
    __shared__ unsigned int s_pts[CHUNK_];
    __shared__ unsigned int s_sorted[CHUNK_];
    __shared__ int s_wavesum[16];
    int logical = (blockIdx.x & 7) * 128 + (blockIdx.x >> 3);  // XCD swizzle
    int bh = logical >> 5;
    int x0 = logical & 31;
    int tid = threadIdx.x;
    int y = tid >> 5, zc = tid & 31;
    int bin0 = (bh << 5) + x0;
    int s0 = base[bin0], len0 = base[bin0 + 1] - s0;
    int s1 = 0, len1 = 0;
    if (x0 > 0) { s1 = base[bin0 - 1]; len1 = s0 - s1; }
    int total = len0 + len1;
    const float4* cb = coordbuf + (size_t)bh * N_;
    const float* vb = vbuf + ((size_t)bh * N_) * 16;
    float acc[16];
    #pragma unroll
    for (int i = 0; i < 16; ++i) acc[i] = 0.f;

    for (int c0 = 0; c0 < total; c0 += CHUNK_) {
        int cl = min(CHUNK_, total - c0);
        s_cnt[tid] = 0;
        __syncthreads();
        for (int t = tid; t < cl; t += 1024) {
            int tp = c0 + t, n, cx;
            if (tp < len0) { n = recs[s0 + tp]; cx = 0; }
            else           { n = recs[s1 + (tp - len0)]; cx = 1; }
            int pk = __float_as_int(cb[n].w);
            int sb = (((pk >> 5) & 31) << 5) | ((pk >> 10) & 31);
            s_pts[t] = ((unsigned)sb << 16) | ((unsigned)cx << 14) | (unsigned)n;
            atomicAdd(&s_cnt[sb], 1);
        }
        __syncthreads();
        int v = s_cnt[tid];
        int incl = v;
        #pragma unroll
        for (int off = 1; off < 64; off <<= 1) {
            int u = __shfl_up(incl, off);
            if ((tid & 63) >= off) incl += u;
        }
        int wid = tid >> 6;
        if ((tid & 63) == 63) s_wavesum[wid] = incl;
        __syncthreads();
        if (tid < 16) {
            int wv = s_wavesum[tid];
            int wincl = wv;
            #pragma unroll
            for (int off = 1; off < 16; off <<= 1) {
                int u = __shfl_up(wincl, off);
                if (tid >= off) wincl += u;
            }
            s_wavesum[tid] = wincl - wv;
        }
        __syncthreads();
        int excl = incl - v + s_wavesum[wid];
        s_start[tid] = excl;
        s_cur[tid] = excl;
        __syncthreads();
        for (int t = tid; t < cl; t += 1024) {
            unsigned rec = s_pts[t];
            int slot = atomicAdd(&s_cur[rec >> 16], 1);
            s_sorted[slot] = rec;
        }
        __syncthreads();
        #pragma unroll
        for (int sy = 0; sy < 2; ++sy) {
            int yy = y - sy;
            if (yy < 0) continue;
            #pragma unroll
            for (int sz = 0; sz < 2; ++sz) {
                int zz = zc - sz;
                if (zz < 0) continue;
                int sb = (yy << 5) | zz;
                int s = s_start[sb], e = s + s_cnt[sb];
                for (int i = s; i < e; ++i) {
                    unsigned rec = s_sorted[i];
                    int n = rec & 0x3FFF;
                    int cx = (rec >> 14) & 1;
                    float4 c = cb[n];
                    float wx = cx ? c.x : 1.f - c.x;
                    float wy = sy ? c.y : 1.f - c.y;
                    float wz = sz ? c.z : 1.f - c.z;
                    float w = wx * wy * wz;
                    const float4* vp = (const float4*)(vb + (size_t)n * 16);
                    float4 a0 = vp[0], a1 = vp[1], a2 = vp[2], a3 = vp[3];
                    acc[0]  = fmaf(w, a0.x, acc[0]);  acc[1]  = fmaf(w, a0.y, acc[1]);
                    acc[2]  = fmaf(w, a0.z, acc[2]);  acc[3]  = fmaf(w, a0.w, acc[3]);
                    acc[4]  = fmaf(w, a1.x, acc[4]);  acc[5]  = fmaf(w, a1.y, acc[5]);
                    acc[6]  = fmaf(w, a1.z, acc[6]);  acc[7]  = fmaf(w, a1.w, acc[7]);
                    acc[8]  = fmaf(w, a2.x, acc[8]);  acc[9]  = fmaf(w, a2.y, acc[9]);
                    acc[10] = fmaf(w, a2.z, acc[10]); acc[11] = fmaf(w, a2.w, acc[11]);
                    acc[12] = fmaf(w, a3.x, acc[12]); acc[13] = fmaf(w, a3.y, acc[13]);
                    acc[14] = fmaf(w, a3.z, acc[14]); acc[15] = fmaf(w, a3.w, acc[15]);
                }
            }
        }
        __syncthreads();
    }
    unsigned int pk[8];
    #pragma unroll
    for (int q = 0; q < 8; ++q)
        pk[q] = (unsigned)f2bf(acc[2 * q]) | ((unsigned)f2bf(acc[2 * q + 1]) << 16);
    int pv = ((x0 + 1) * PS_ + y + 1) * PS_ + zc + 1;
    unsigned short* zb = zb16p + ((size_t)bh * PV_ + pv) * 16;
    ((uint4*)zb)[0] = make_uint4(pk[0], pk[1], pk[2], pk[3]);
    ((uint4*)zb)[1] = make_uint4(pk[4], pk[5], pk[6], pk[7]);
}

// ---------------- grouped 3x3x3 conv via bf16 MFMA on PADDED lattice --------
// 2048 blocks (half x-plane each) for 8 blocks/CU; dual accumulator chains.
__global__ __launch_bounds__(256) void conv3d_mfma(
    const unsigned short* __restrict__ zp, const unsigned short* __restrict__ wb,
    const float* __restrict__ cbias, float* __restrict__ zc) {
    int logical = (blockIdx.x & 7) * 256 + (blockIdx.x >> 3);  // 2048 = 8*256
    int bh = logical >> 6;
    int rest = logical & 63;
    int x = rest >> 1;
    int half = rest & 1;
    int h = bh & 7;
    int lane = threadIdx.x & 63;
    int wv = threadIdx.x >> 6;
    int rc = lane & 15;
    int kb = lane >> 4;
    int ic0 = (kb & 1) << 3;
    int tsel = kb >> 1;

    bf16x8 bfr[14];
    const unsigned short* wh = wb + h * 28 * 256;
    int doff[14];
    #pragma unroll
    for (int p = 0; p < 14; ++p) {
        int t = 2 * p + tsel;
        bfr[p] = *(const bf16x8*)(wh + (t * 16 + rc) * 16 + ic0);
        int dx = t / 9, r9 = t - dx * 9;
        int dy = r9 / 3, dz = r9 - dy * 3;
        doff[p] = (t < 27) ? ((dx - 1) * PS2_ + (dy - 1) * PS_ + (dz - 1)) * 32 : 0;
    }
    float bias = cbias[h * 16 + rc];
    const char* zb = (const char*)(zp + (size_t)bh * PV_ * 16);
    float* zcb = zc + ((size_t)bh << 19);
    int basex = (x + 1) * PS2_;

    #pragma unroll 1
    for (int ti = 0; ti < 8; ++ti) {
        int tile = wv * 8 + ti;                   // 0..31
        int y = half * 16 + (tile >> 1);
        int z0 = (tile & 1) << 4;
        int vbase = (basex + (y + 1) * PS_ + z0 + rc + 1) * 32 + ic0 * 2;
        f32x4 acc0 = {0.f, 0.f, 0.f, 0.f};
        f32x4 acc1 = {0.f, 0.f, 0.f, 0.f};
        #pragma unroll
        for (int p = 0; p < 14; p += 2) {
            bf16x8 a0 = *(const bf16x8*)(zb + vbase + doff[p]);
            bf16x8 a1 = *(const bf16x8*)(zb + vbase + doff[p + 1]);
            acc0 = __builtin_amdgcn_mfma_f32_16x16x32_bf16(a0, bfr[p], acc0, 0, 0, 0);
            acc1 = __builtin_amdgcn_mfma_f32_16x16x32_bf16(a1, bfr[p + 1], acc1, 0, 0, 0);
        }
        int vout = (((x << 5) + y) << 5) + z0 + (kb << 2);
        #pragma unroll
        for (int r = 0; r < 4; ++r)
            zcb[(size_t)(vout + r) * 16 + rc] = acc0[r] + acc1[r] + bias;
    }
}

// ---------------- slice: weighted gather back to points ---------------------
__global__ __launch_bounds__(256) void slice_vm(
    const float* __restrict__ zc, const float4* __restrict__ coordbuf,
    float* __restrict__ out) {
    int p = blockIdx.x * 256 + threadIdx.x;
    int n = p & (N_ - 1);
    int bh = p >> 13;
    int h = bh & 7, b = bh >> 3;
    float4 c = coordbuf[p];
    int pk = __float_as_int(c.w);
    int f0x = pk & 31, f0y = (pk >> 5) & 31, f0z = (pk >> 10) & 31;
    const float* gb = zc + ((size_t)bh << 19);
    float acc[16];
    #pragma unroll
    for (int f = 0; f < 16; ++f) acc[f] = 0.f;
    #pragma unroll 1
    for (int k = 0; k < 8; ++k) {
        int cx = (k >> 2) & 1, cy = (k >> 1) & 1, cz = k & 1;
        float w = (cx ? c.x : 1.f - c.x) * (cy ? c.y : 1.f - c.y) * (cz ? c.z : 1.f - c.z);
        int vox = (((f0x + cx) << 5) + f0y + cy) * 32 + f0z + cz;
        const float4* ip = (const float4*)(gb + ((size_t)vox << 4));
        float4 a0 = ip[0], a1 = ip[1], a2 = ip[2], a3 = ip[3];
        acc[0]  = fmaf(w, a0.x, acc[0]);  acc[1]  = fmaf(w, a0.y, acc[1]);
        acc[2]  = fmaf(w, a0.z, acc[2]);  acc[3]  = fmaf(w, a0.w, acc[3]);
        acc[4]  = fmaf(w, a1.x, acc[4]);  acc[5]  = fmaf(w, a1.y, acc[5]);
        acc[6]  = fmaf(w, a1.z, acc[6]);  acc[7]  = fmaf(w, a1.w, acc[7]);
        acc[8]  = fmaf(w, a2.x, acc[8]);  acc[9]  = fmaf(w, a2.y, acc[9]);
        acc[10] = fmaf(w, a2.z, acc[10]); acc[11] = fmaf(w, a2.w, acc[11]);
        acc[12] = fmaf(w, a3.x, acc[12]); acc[13] = fmaf(w, a3.y, acc[13]);
        acc[14] = fmaf(w, a3.z, acc[14]); acc[15] = fmaf(w, a3.w, acc[15]);
    }
    #pragma unroll
    for (int f = 0; f < 16; ++f)
        out[(((size_t)(b * HF_ + h * F_ + f)) << 13) + n] = acc[f];
}

// ---------------- final AdaIN + ReLU (in place on d_out) --------------------
__global__ __launch_bounds__(256) void final_adain(
    float* __restrict__ out, const float* __restrict__ mean_o,
    const float* __restrict__ rsig_o, const float* __restrict__ ha) {
    size_t i = (size_t)blockIdx.x * 256 + threadIdx.x;
    int bc = (int)(i >> 13);
    int c = bc & 127, b = bc >> 7;
    float x = out[i];
    float xn = (x - mean_o[bc]) * rsig_o[bc];
    float y = fmaf(1.f + ha[b * 256 + c], xn, ha[b * 256 + 128 + c]);
    out[i] = fmaxf(y, 0.f);
}

extern "C" void kernel_launch(void* const* d_in, const int* in_sizes, int n_in,
                              void* d_out, int out_size, void* d_ws, size_t ws_size,
                              hipStream_t stream) {
    (void)in_sizes; (void)n_in; (void)out_size; (void)ws_size;
    const float* input   = (const float*)d_in[0];
    const float* style   = (const float*)d_in[1];
    const float* orig    = (const float*)d_in[2];
    const float* Wkv     = (const float*)d_in[3];
    const float* kw_w    = (const float*)d_in[4];
    const float* kw_b    = (const float*)d_in[5];
    const float* vw_w    = (const float*)d_in[6];
    const float* vw_b    = (const float*)d_in[7];
    const float* aw_w    = (const float*)d_in[8];
    const float* aw_b    = (const float*)d_in[9];
    const float* scale_p = (const float*)d_in[10];
    const float* Tw      = (const float*)d_in[11];
    const float* Tb      = (const float*)d_in[12];
    const float* conv_w  = (const float*)d_in[13];
    const float* conv_b  = (const float*)d_in[14];
    float* out = (float*)d_out;

    // -------- workspace layout (floats), ~146.0 MB total --------------------
    float* ws = (float*)d_ws;
    unsigned short* zb16p = (unsigned short*)ws;     // padded lattice bf16, 10,061,824 floats (40.2MB)
    float* zc       = ws + 10061824;                 // 16,777,216 (64MB) conv output fp32
    float* xbf_f    = ws + 26839040;                 //  8,388,608 (32MB) bf16 input frags
    float* coordbuf = ws + 35227648;                 //  1,048,576
    float* wt       = ws + 36276224;                 //     55,296 (conv bf16 weights, 112KB used)
    float* wkb_f    = ws + 36331520;                 //     40,960 (W_kv bf16 frags, 160KB)
    float* recs_f   = ws + 36372480;                 //    131,072 (262,144 u16)
    float* ha       = ws + 36503552;                 //      1,024
    float* mean_o   = ha + 1024;                     //        512
    float* rsig_o   = mean_o + 512;                  //        512
    float* mean_kv  = rsig_o + 512;                  //        608
    float* rsig_kv  = mean_kv + 608;                 //        608
    float* hk       = rsig_kv + 608;                 //        192
    float* hv       = hk + 192;                      //      1,024
    int*   counts   = (int*)(hv + 1024);             //      1,024 ints
    int*   base     = counts + 1024;                 //      1,025 ints
    int*   cursor   = base + 1025;                   //      1,024 ints
    // aliased into zc (dead before conv3d writes zc):
    float* vbuf = zc;                                //  4,194,304 (16MB)
    float* kv   = zc + 4194304;                      //  4,980,736 (19MB)
    unsigned short* xbf  = (unsigned short*)xbf_f;
    unsigned short* wb16 = (unsigned short*)wt;
    unsigned short* wkb  = (unsigned short*)wkb_f;
    unsigned short* recs = (unsigned short*)recs_f;

    zero_bins<<<1, 1024, 0, stream>>>(counts);
    zero_halo<<<(32 * HALO_ + 255) / 256, 256, 0, stream>>>(zb16p);
    style_proj<<<B_, 256, 0, stream>>>(style, kw_w, kw_b, vw_w, vw_b, aw_w, aw_b, hk, hv, ha);
    wtrans_bf<<<224, 256, 0, stream>>>(conv_w, wb16);
    wconvert<<<40, 256, 0, stream>>>(Wkv, wkb);
    xconvert<<<8192, 256, 0, stream>>>(input, xbf);
    kv_gemm_mfma<<<dim3(16, 10, B_), 256, 0, stream>>>(xbf, wkb, kv);
    stats_kernel<<<B_ * CO_, 256, 0, stream>>>(kv, mean_kv, rsig_kv);
    point_prep<<<B_ * H_ * N_ / 256, 256, 0, stream>>>(
        kv, mean_kv, rsig_kv, hk, hv, orig, scale_p, Tw, Tb,
        (float4*)coordbuf, vbuf, counts);
    prefix_bins<<<1, 64, 0, stream>>>(counts, base, cursor);
    scatter_pts<<<B_ * H_ * N_ / 256, 256, 0, stream>>>((const float4*)coordbuf, cursor, recs);
    splat3<<<1024, 1024, 0, stream>>>((const float4*)coordbuf, vbuf, base, recs, zb16p);
    conv3d_mfma<<<2048, 256, 0, stream>>>(zb16p, wb16, conv_b, zc);
    slice_vm<<<B_ * H_ * N_ / 256, 256, 0, stream>>>(zc, (const float4*)coordbuf, out);
    stats_kernel<<<B_ * HF_, 256, 0, stream>>>(out, mean_o, rsig_o);
    final_adain<<<B_ * HF_ * N_ / 256, 256, 0, stream>>>(out, mean_o, rsig_o, ha);
}

// Round 11
// 251.350 us; speedup vs baseline: 2.7668x; 1.3531x over previous
//
#include <hip/hip_runtime.h>
#include <hip/hip_bf16.h>
#include <math.h>

#define B_ 4
#define N_ 8192
#define MD_ 512
#define H_ 8
#define F_ 16
#define S_ 32
#define S3_ 32768
#define L_ 256
#define CO_ 152   // H*(F+3)
#define HF_ 128   // H*F
#define EPS_ 1e-5f
#define CHUNK_ 2048
#define PS_ 34            // padded lattice dim
#define PS2_ 1156         // 34*34
#define PV_ 39304         // 34^3 voxels per (b,h)
#define HALO_ 6536        // 34^3 - 32^3

typedef __attribute__((ext_vector_type(8))) short bf16x8;
typedef __attribute__((ext_vector_type(4))) float f32x4;

__device__ inline unsigned short f2bf(float f) {   // RNE fp32 -> bf16
    unsigned u = __float_as_uint(f);
    return (unsigned short)((u + 0x7FFFu + ((u >> 16) & 1u)) >> 16);
}

// ---------------- zero kernels ----------------------------------------------
__global__ __launch_bounds__(1024) void zero_bins(int* __restrict__ counts) {
    counts[threadIdx.x] = 0;
}
// zero only the halo shell of each padded lattice (interior fully written by splat3)
__global__ __launch_bounds__(256) void zero_halo(unsigned short* __restrict__ zb16p) {
    int i = blockIdx.x * 256 + threadIdx.x;     // 32 * 6536 total
    if (i >= 32 * HALO_) return;
    int bh = i / HALO_;
    int j  = i - bh * HALO_;
    int x, y, z;
    if (j < 2312) {                 // x = 0 or 33 full planes
        x = (j / 1156) * 33;
        int rem = j % 1156;
        y = rem / 34; z = rem % 34;
    } else {
        int k = j - 2312;
        x = 1 + k / 132;
        int m = k % 132;
        if (m < 34)       { y = 0;  z = m; }
        else if (m < 68)  { y = 33; z = m - 34; }
        else if (m < 100) { y = m - 68 + 1;  z = 0; }
        else              { y = m - 100 + 1; z = 33; }
    }
    int pv = (x * PS_ + y) * PS_ + z;
    unsigned short* p = zb16p + ((size_t)bh * PV_ + pv) * 16;
    ((uint4*)p)[0] = make_uint4(0, 0, 0, 0);
    ((uint4*)p)[1] = make_uint4(0, 0, 0, 0);
}

// ---------------- style projections: h = style @ W.T + b --------------------
__global__ __launch_bounds__(256) void style_proj(
    const float* __restrict__ style,
    const float* __restrict__ kw_w, const float* __restrict__ kw_b,
    const float* __restrict__ vw_w, const float* __restrict__ vw_b,
    const float* __restrict__ aw_w, const float* __restrict__ aw_b,
    float* __restrict__ hk, float* __restrict__ hv, float* __restrict__ ha) {
    int b = blockIdx.x;
    const float* st = style + b * L_;
    for (int r = threadIdx.x; r < 48 + 256 + 256; r += 256) {
        const float* wrow; float bias; float* dst; int j;
        if (r < 48)       { j = r;       wrow = kw_w + j * L_; bias = kw_b[j]; dst = hk + b * 48; }
        else if (r < 304) { j = r - 48;  wrow = vw_w + j * L_; bias = vw_b[j]; dst = hv + b * 256; }
        else              { j = r - 304; wrow = aw_w + j * L_; bias = aw_b[j]; dst = ha + b * 256; }
        float acc = bias;
        for (int l = 0; l < L_; ++l) acc = fmaf(st[l], wrow[l], acc);
        dst[j] = acc;
    }
}

// ---------------- conv weights -> bf16 [h][28 taps][oc][ic] (tap 27 = 0) ----
__global__ __launch_bounds__(256) void wtrans_bf(const float* __restrict__ cw,
                                                 unsigned short* __restrict__ wb) {
    int i = blockIdx.x * 256 + threadIdx.x;   // 8*28*16*16 = 57344 total
    if (i >= 57344) return;
    int ic  = i & 15;
    int oc  = (i >> 4) & 15;
    int tap = (i >> 8) % 28;
    int h   = (i >> 8) / 28;
    float v = (tap < 27) ? cw[(((h * 16 + oc) * 16 + ic) * 27) + tap] : 0.f;
    wb[i] = f2bf(v);
}

// ---------------- W_kv -> bf16 fragment layout [mt(10)][kc(64)][r16][k8] ----
__global__ __launch_bounds__(256) void wconvert(
    const float* __restrict__ Wkv, unsigned short* __restrict__ wkb) {
    int i = blockIdx.x * 256 + threadIdx.x;   // 10*64*16 = 10240
    if (i >= 10240) return;
    int r  = i & 15;
    int kc = (i >> 4) & 63;
    int mt = i >> 10;
    int row = mt * 16 + r;
    unsigned int pk[4];
    #pragma unroll
    for (int j = 0; j < 4; ++j) {
        float v0 = (row < CO_) ? Wkv[(size_t)row * MD_ + kc * 8 + 2 * j] : 0.f;
        float v1 = (row < CO_) ? Wkv[(size_t)row * MD_ + kc * 8 + 2 * j + 1] : 0.f;
        pk[j] = (unsigned)f2bf(v0) | ((unsigned)f2bf(v1) << 16);
    }
    *(uint4*)(wkb + (((size_t)(mt * 64 + kc)) * 16 + r) * 8) =
        make_uint4(pk[0], pk[1], pk[2], pk[3]);
}

// ---------------- input -> bf16 fragment layout [b][nt(512)][kc(64)][n16][k8]
__global__ __launch_bounds__(256) void xconvert(
    const float* __restrict__ X, unsigned short* __restrict__ xb) {
    int i = blockIdx.x * 256 + threadIdx.x;   // 4*64*8192 = 2,097,152
    int n  = i & (N_ - 1);
    int kc = (i >> 13) & 63;
    int b  = i >> 19;
    const float* xp = X + ((size_t)b * MD_ + kc * 8) * N_ + n;
    unsigned int pk[4];
    #pragma unroll
    for (int j = 0; j < 4; ++j) {
        float v0 = xp[(size_t)(2 * j) * N_];
        float v1 = xp[(size_t)(2 * j + 1) * N_];
        pk[j] = (unsigned)f2bf(v0) | ((unsigned)f2bf(v1) << 16);
    }
    int nt = n >> 4, n16 = n & 15;
    *(uint4*)(xb + ((((size_t)(b * 512 + nt)) * 64 + kc) * 16 + n16) * 8) =
        make_uint4(pk[0], pk[1], pk[2], pk[3]);
}

// ---------------- kv = W_kv @ input via bf16 MFMA (no LDS, no barriers) -----
__global__ __launch_bounds__(256) void kv_gemm_mfma(
    const unsigned short* __restrict__ xb, const unsigned short* __restrict__ wkb,
    float* __restrict__ kv) {
    int b  = blockIdx.z;
    int mt = blockIdx.y;
    int lane = threadIdx.x & 63, wv = threadIdx.x >> 6;
    int rc = lane & 15, kg = lane >> 4;
    int n0 = blockIdx.x * 512 + wv * 128;
    int nt0 = n0 >> 4;
    const unsigned short* ap = wkb + (((size_t)(mt * 64 + kg)) * 16 + rc) * 8;
    const unsigned short* bp = xb + ((((size_t)(b * 512 + nt0)) * 64 + kg) * 16 + rc) * 8;
    f32x4 acc[8];
    #pragma unroll
    for (int j = 0; j < 8; ++j) acc[j] = (f32x4){0.f, 0.f, 0.f, 0.f};
    #pragma unroll 1
    for (int ks = 0; ks < 16; ++ks) {
        bf16x8 a = *(const bf16x8*)(ap + ks * 512);
        #pragma unroll
        for (int j = 0; j < 8; ++j) {
            bf16x8 bfr = *(const bf16x8*)(bp + (size_t)j * 8192 + ks * 512);
            acc[j] = __builtin_amdgcn_mfma_f32_16x16x32_bf16(a, bfr, acc[j], 0, 0, 0);
        }
    }
    #pragma unroll
    for (int j = 0; j < 8; ++j) {
        int col = n0 + j * 16 + rc;
        #pragma unroll
        for (int r = 0; r < 4; ++r) {
            int m = mt * 16 + kg * 4 + r;
            if (m < CO_) kv[((size_t)b * CO_ + m) * N_ + col] = acc[j][r];
        }
    }
}

// ---------------- per-(b,channel) mean / rsig over N ------------------------
__global__ __launch_bounds__(256) void stats_kernel(
    const float* __restrict__ x, float* __restrict__ mean, float* __restrict__ rsig) {
    int bc = blockIdx.x;
    const float* p = x + (size_t)bc * N_;
    float s = 0.f, s2 = 0.f;
    for (int i = threadIdx.x; i < N_; i += 256) {
        float v = p[i]; s += v; s2 = fmaf(v, v, s2);
    }
    #pragma unroll
    for (int off = 32; off; off >>= 1) { s += __shfl_down(s, off); s2 += __shfl_down(s2, off); }
    __shared__ float ls[4], ls2[4];
    int wid = threadIdx.x >> 6;
    if ((threadIdx.x & 63) == 0) { ls[wid] = s; ls2[wid] = s2; }
    __syncthreads();
    if (threadIdx.x == 0) {
        float S = ls[0] + ls[1] + ls[2] + ls[3];
        float S2 = ls2[0] + ls2[1] + ls2[2] + ls2[3];
        float mu = S * (1.f / N_);
        float var = S2 * (1.f / N_) - mu * mu;
        mean[bc] = mu;
        rsig[bc] = rsqrtf(var + EPS_);
    }
}

// ---------------- point prep: AdaIN + transform + tanh + interp + count -----
// counts via block-local LDS histogram: <=32 global atomics per block
__global__ __launch_bounds__(256) void point_prep(
    const float* __restrict__ kv, const float* __restrict__ mean_kv,
    const float* __restrict__ rsig_kv, const float* __restrict__ hk,
    const float* __restrict__ hv, const float* __restrict__ orig,
    const float* __restrict__ scale_p, const float* __restrict__ Tw,
    const float* __restrict__ Tb,
    float4* __restrict__ coordbuf, float* __restrict__ vbuf,
    int* __restrict__ counts) {
    __shared__ int s_hist[32];
    int tid = threadIdx.x;
    if (tid < 32) s_hist[tid] = 0;
    __syncthreads();
    int p = blockIdx.x * 256 + tid;
    int n = p & (N_ - 1);
    int bh = p >> 13;               // uniform per block (256 | 8192)
    int h = bh & 7, b = bh >> 3;
    float scl = scale_p[0];

    float pt[3];
    #pragma unroll
    for (int j = 0; j < 3; ++j) {
        int c = h * 3 + j;
        float x  = kv[((size_t)(b * CO_ + c)) * N_ + n];
        float xn = (x - mean_kv[b * CO_ + c]) * rsig_kv[b * CO_ + c];
        float kr = fmaf(1.f + hk[b * 48 + c], xn, hk[b * 48 + 24 + c]);
        pt[j] = fmaf(scl, kr, orig[((size_t)(b * 3 + j)) * N_ + n]);
    }
    int f0[3]; float tt[3];
    #pragma unroll
    for (int i = 0; i < 3; ++i) {
        float key = Tb[h * 3 + i];
        #pragma unroll
        for (int j = 0; j < 3; ++j) key = fmaf(Tw[(h * 3 + i) * 3 + j], pt[j], key);
        float lat = tanhf(key);
        float g = (lat + 1.f) * 0.5f * (float)(S_ - 1);
        float ff = floorf(g);
        ff = fminf(fmaxf(ff, 0.f), 30.f);
        f0[i] = (int)ff;
        tt[i] = fminf(fmaxf(g - ff, 0.f), 1.f);
    }
    coordbuf[p] = make_float4(tt[0], tt[1], tt[2],
                              __int_as_float(f0[0] | (f0[1] << 5) | (f0[2] << 10)));
    atomicAdd(&s_hist[f0[0]], 1);   // LDS
    float vf[16];
    #pragma unroll
    for (int f = 0; f < F_; ++f) {
        int c = 24 + h * F_ + f;
        float x  = kv[((size_t)(b * CO_ + c)) * N_ + n];
        float xn = (x - mean_kv[b * CO_ + c]) * rsig_kv[b * CO_ + c];
        int cv = h * F_ + f;
        vf[f] = fmaf(1.f + hv[b * 256 + cv], xn, hv[b * 256 + 128 + cv]);
    }
    float4* vb = (float4*)(vbuf + (size_t)p * 16);
    #pragma unroll
    for (int q = 0; q < 4; ++q)
        vb[q] = make_float4(vf[q * 4], vf[q * 4 + 1], vf[q * 4 + 2], vf[q * 4 + 3]);
    __syncthreads();
    if (tid < 32 && s_hist[tid] > 0)
        atomicAdd(&counts[(bh << 5) + tid], s_hist[tid]);
}

// ---------------- exclusive prefix over the 1024 bins (one wave) ------------
__global__ __launch_bounds__(64) void prefix_bins(
    const int* __restrict__ counts, int* __restrict__ base, int* __restrict__ cursor) {
    int lane = threadIdx.x;
    int local[16], sum = 0;
    #pragma unroll
    for (int i = 0; i < 16; ++i) { local[i] = sum; sum += counts[lane * 16 + i]; }
    int incl = sum;
    #pragma unroll
    for (int off = 1; off < 64; off <<= 1) {
        int v = __shfl_up(incl, off);
        if (lane >= off) incl += v;
    }
    int excl = incl - sum;
    #pragma unroll
    for (int i = 0; i < 16; ++i) {
        int bse = excl + local[i];
        base[lane * 16 + i] = bse;
        cursor[lane * 16 + i] = bse;
    }
    if (lane == 63) base[1024] = excl + sum;
}

// ---------------- scatter point indices into bins (LDS-aggregated) ----------
__global__ __launch_bounds__(256) void scatter_pts(
    const float4* __restrict__ coordbuf, int* __restrict__ cursor,
    unsigned short* __restrict__ recs) {
    __shared__ int s_hist[32];
    __shared__ int s_base[32];
    int tid = threadIdx.x;
    if (tid < 32) s_hist[tid] = 0;
    __syncthreads();
    int p = blockIdx.x * 256 + tid;
    int bh = p >> 13;               // uniform per block
    int pk = __float_as_int(((const float*)coordbuf)[(size_t)p * 4 + 3]);
    int f0x = pk & 31;
    int rank = atomicAdd(&s_hist[f0x], 1);   // LDS
    __syncthreads();
    if (tid < 32 && s_hist[tid] > 0)
        s_base[tid] = atomicAdd(&cursor[(bh << 5) + tid], s_hist[tid]);
    __syncthreads();
    recs[s_base[f0x] + rank] = (unsigned short)(p & (N_ - 1));
}

// ---------------- splat3: in-block sub-sort by (y,z), register gather -------
// Output lattice written bf16 into the PADDED [34][34][34] interior.
__global__ __launch_bounds__(1024) void splat3(
    const float4* __restrict__ coordbuf, const float* __restrict__ vbuf,
    const int* __restrict__ base, const unsigned short* __restrict__ recs,
    unsigned short* __restrict__ zb16p) {
    __shared__ int s_cnt[1024];
    __shared__ int s_start[1024];
    __shared__ int s_cur[1024];
    __shared__ unsigned int s_pts[CHUNK_];
    __shared__ unsigned int s_sorted[CHUNK_];
    __shared__ int s_wavesum[16];
    int logical = (blockIdx.x & 7) * 128 + (blockIdx.x >> 3);  // XCD swizzle
    int bh = logical >> 5;
    int x0 = logical & 31;
    int tid = threadIdx.x;
    int y = tid >> 5, zc = tid & 31;
    int bin0 = (bh << 5) + x0;
    int s0 = base[bin0], len0 = base[bin0 + 1] - s0;
    int s1 = 0, len1 = 0;
    if (x0 > 0) { s1 = base[bin0 - 1]; len1 = s0 - s1; }
    int total = len0 + len1;
    const float4* cb = coordbuf + (size_t)bh * N_;
    const float* vb = vbuf + ((size_t)bh * N_) * 16;
    float acc[16];
    #pragma unroll
    for (int i = 0; i < 16; ++i) acc[i] = 0.f;

    for (int c0 = 0; c0 < total; c0 += CHUNK_) {
        int cl = min(CHUNK_, total - c0);
        s_cnt[tid] = 0;
        __syncthreads();
        for (int t = tid; t < cl; t += 1024) {
            int tp = c0 + t, n, cx;
            if (tp < len0) { n = recs[s0 + tp]; cx = 0; }
            else           { n = recs[s1 + (tp - len0)]; cx = 1; }
            int pk = __float_as_int(cb[n].w);
            int sb = (((pk >> 5) & 31) << 5) | ((pk >> 10) & 31);
            s_pts[t] = ((unsigned)sb << 16) | ((unsigned)cx << 14) | (unsigned)n;
            atomicAdd(&s_cnt[sb], 1);
        }
        __syncthreads();
        int v = s_cnt[tid];
        int incl = v;
        #pragma unroll
        for (int off = 1; off < 64; off <<= 1) {
            int u = __shfl_up(incl, off);
            if ((tid & 63) >= off) incl += u;
        }
        int wid = tid >> 6;
        if ((tid & 63) == 63) s_wavesum[wid] = incl;
        __syncthreads();
        if (tid < 16) {
            int wv = s_wavesum[tid];
            int wincl = wv;
            #pragma unroll
            for (int off = 1; off < 16; off <<= 1) {
                int u = __shfl_up(wincl, off);
                if (tid >= off) wincl += u;
            }
            s_wavesum[tid] = wincl - wv;
        }
        __syncthreads();
        int excl = incl - v + s_wavesum[wid];
        s_start[tid] = excl;
        s_cur[tid] = excl;
        __syncthreads();
        for (int t = tid; t < cl; t += 1024) {
            unsigned rec = s_pts[t];
            int slot = atomicAdd(&s_cur[rec >> 16], 1);
            s_sorted[slot] = rec;
        }
        __syncthreads();
        #pragma unroll
        for (int sy = 0; sy < 2; ++sy) {
            int yy = y - sy;
            if (yy < 0) continue;
            #pragma unroll
            for (int sz = 0; sz < 2; ++sz) {
                int zz = zc - sz;
                if (zz < 0) continue;
                int sb = (yy << 5) | zz;
                int s = s_start[sb], e = s + s_cnt[sb];
                for (int i = s; i < e; ++i) {
                    unsigned rec = s_sorted[i];
                    int n = rec & 0x3FFF;
                    int cx = (rec >> 14) & 1;
                    float4 c = cb[n];
                    float wx = cx ? c.x : 1.f - c.x;
                    float wy = sy ? c.y : 1.f - c.y;
                    float wz = sz ? c.z : 1.f - c.z;
                    float w = wx * wy * wz;
                    const float4* vp = (const float4*)(vb + (size_t)n * 16);
                    float4 a0 = vp[0], a1 = vp[1], a2 = vp[2], a3 = vp[3];
                    acc[0]  = fmaf(w, a0.x, acc[0]);  acc[1]  = fmaf(w, a0.y, acc[1]);
                    acc[2]  = fmaf(w, a0.z, acc[2]);  acc[3]  = fmaf(w, a0.w, acc[3]);
                    acc[4]  = fmaf(w, a1.x, acc[4]);  acc[5]  = fmaf(w, a1.y, acc[5]);
                    acc[6]  = fmaf(w, a1.z, acc[6]);  acc[7]  = fmaf(w, a1.w, acc[7]);
                    acc[8]  = fmaf(w, a2.x, acc[8]);  acc[9]  = fmaf(w, a2.y, acc[9]);
                    acc[10] = fmaf(w, a2.z, acc[10]); acc[11] = fmaf(w, a2.w, acc[11]);
                    acc[12] = fmaf(w, a3.x, acc[12]); acc[13] = fmaf(w, a3.y, acc[13]);
                    acc[14] = fmaf(w, a3.z, acc[14]); acc[15] = fmaf(w, a3.w, acc[15]);
                }
            }
        }
        __syncthreads();
    }
    unsigned int pk[8];
    #pragma unroll
    for (int q = 0; q < 8; ++q)
        pk[q] = (unsigned)f2bf(acc[2 * q]) | ((unsigned)f2bf(acc[2 * q + 1]) << 16);
    int pv = ((x0 + 1) * PS_ + y + 1) * PS_ + zc + 1;
    unsigned short* zb = zb16p + ((size_t)bh * PV_ + pv) * 16;
    ((uint4*)zb)[0] = make_uint4(pk[0], pk[1], pk[2], pk[3]);
    ((uint4*)zb)[1] = make_uint4(pk[4], pk[5], pk[6], pk[7]);
}

// ---------------- grouped 3x3x3 conv via bf16 MFMA on PADDED lattice --------
// 2048 blocks (half x-plane each) for 8 blocks/CU; dual accumulator chains.
__global__ __launch_bounds__(256) void conv3d_mfma(
    const unsigned short* __restrict__ zp, const unsigned short* __restrict__ wb,
    const float* __restrict__ cbias, float* __restrict__ zc) {
    int logical = (blockIdx.x & 7) * 256 + (blockIdx.x >> 3);  // 2048 = 8*256
    int bh = logical >> 6;
    int rest = logical & 63;
    int x = rest >> 1;
    int half = rest & 1;
    int h = bh & 7;
    int lane = threadIdx.x & 63;
    int wv = threadIdx.x >> 6;
    int rc = lane & 15;
    int kb = lane >> 4;
    int ic0 = (kb & 1) << 3;
    int tsel = kb >> 1;

    bf16x8 bfr[14];
    const unsigned short* wh = wb + h * 28 * 256;
    int doff[14];
    #pragma unroll
    for (int p = 0; p < 14; ++p) {
        int t = 2 * p + tsel;
        bfr[p] = *(const bf16x8*)(wh + (t * 16 + rc) * 16 + ic0);
        int dx = t / 9, r9 = t - dx * 9;
        int dy = r9 / 3, dz = r9 - dy * 3;
        doff[p] = (t < 27) ? ((dx - 1) * PS2_ + (dy - 1) * PS_ + (dz - 1)) * 32 : 0;
    }
    float bias = cbias[h * 16 + rc];
    const char* zb = (const char*)(zp + (size_t)bh * PV_ * 16);
    float* zcb = zc + ((size_t)bh << 19);
    int basex = (x + 1) * PS2_;

    #pragma unroll 1
    for (int ti = 0; ti < 8; ++ti) {
        int tile = wv * 8 + ti;                   // 0..31
        int y = half * 16 + (tile >> 1);
        int z0 = (tile & 1) << 4;
        int vbase = (basex + (y + 1) * PS_ + z0 + rc + 1) * 32 + ic0 * 2;
        f32x4 acc0 = {0.f, 0.f, 0.f, 0.f};
        f32x4 acc1 = {0.f, 0.f, 0.f, 0.f};
        #pragma unroll
        for (int p = 0; p < 14; p += 2) {
            bf16x8 a0 = *(const bf16x8*)(zb + vbase + doff[p]);
            bf16x8 a1 = *(const bf16x8*)(zb + vbase + doff[p + 1]);
            acc0 = __builtin_amdgcn_mfma_f32_16x16x32_bf16(a0, bfr[p], acc0, 0, 0, 0);
            acc1 = __builtin_amdgcn_mfma_f32_16x16x32_bf16(a1, bfr[p + 1], acc1, 0, 0, 0);
        }
        int vout = (((x << 5) + y) << 5) + z0 + (kb << 2);
        #pragma unroll
        for (int r = 0; r < 4; ++r)
            zcb[(size_t)(vout + r) * 16 + rc] = acc0[r] + acc1[r] + bias;
    }
}

// ---------------- slice: weighted gather back to points ---------------------
__global__ __launch_bounds__(256) void slice_vm(
    const float* __restrict__ zc, const float4* __restrict__ coordbuf,
    float* __restrict__ out) {
    int p = blockIdx.x * 256 + threadIdx.x;
    int n = p & (N_ - 1);
    int bh = p >> 13;
    int h = bh & 7, b = bh >> 3;
    float4 c = coordbuf[p];
    int pk = __float_as_int(c.w);
    int f0x = pk & 31, f0y = (pk >> 5) & 31, f0z = (pk >> 10) & 31;
    const float* gb = zc + ((size_t)bh << 19);
    float acc[16];
    #pragma unroll
    for (int f = 0; f < 16; ++f) acc[f] = 0.f;
    #pragma unroll 1
    for (int k = 0; k < 8; ++k) {
        int cx = (k >> 2) & 1, cy = (k >> 1) & 1, cz = k & 1;
        float w = (cx ? c.x : 1.f - c.x) * (cy ? c.y : 1.f - c.y) * (cz ? c.z : 1.f - c.z);
        int vox = (((f0x + cx) << 5) + f0y + cy) * 32 + f0z + cz;
        const float4* ip = (const float4*)(gb + ((size_t)vox << 4));
        float4 a0 = ip[0], a1 = ip[1], a2 = ip[2], a3 = ip[3];
        acc[0]  = fmaf(w, a0.x, acc[0]);  acc[1]  = fmaf(w, a0.y, acc[1]);
        acc[2]  = fmaf(w, a0.z, acc[2]);  acc[3]  = fmaf(w, a0.w, acc[3]);
        acc[4]  = fmaf(w, a1.x, acc[4]);  acc[5]  = fmaf(w, a1.y, acc[5]);
        acc[6]  = fmaf(w, a1.z, acc[6]);  acc[7]  = fmaf(w, a1.w, acc[7]);
        acc[8]  = fmaf(w, a2.x, acc[8]);  acc[9]  = fmaf(w, a2.y, acc[9]);
        acc[10] = fmaf(w, a2.z, acc[10]); acc[11] = fmaf(w, a2.w, acc[11]);
        acc[12] = fmaf(w, a3.x, acc[12]); acc[13] = fmaf(w, a3.y, acc[13]);
        acc[14] = fmaf(w, a3.z, acc[14]); acc[15] = fmaf(w, a3.w, acc[15]);
    }
    #pragma unroll
    for (int f = 0; f < 16; ++f)
        out[(((size_t)(b * HF_ + h * F_ + f)) << 13) + n] = acc[f];
}

// ---------------- final AdaIN + ReLU (in place on d_out) --------------------
__global__ __launch_bounds__(256) void final_adain(
    float* __restrict__ out, const float* __restrict__ mean_o,
    const float* __restrict__ rsig_o, const float* __restrict__ ha) {
    size_t i = (size_t)blockIdx.x * 256 + threadIdx.x;
    int bc = (int)(i >> 13);
    int c = bc & 127, b = bc >> 7;
    float x = out[i];
    float xn = (x - mean_o[bc]) * rsig_o[bc];
    float y = fmaf(1.f + ha[b * 256 + c], xn, ha[b * 256 + 128 + c]);
    out[i] = fmaxf(y, 0.f);
}

extern "C" void kernel_launch(void* const* d_in, const int* in_sizes, int n_in,
                              void* d_out, int out_size, void* d_ws, size_t ws_size,
                              hipStream_t stream) {
    (void)in_sizes; (void)n_in; (void)out_size; (void)ws_size;
    const float* input   = (const float*)d_in[0];
    const float* style   = (const float*)d_in[1];
    const float* orig    = (const float*)d_in[2];
    const float* Wkv     = (const float*)d_in[3];
    const float* kw_w    = (const float*)d_in[4];
    const float* kw_b    = (const float*)d_in[5];
    const float* vw_w    = (const float*)d_in[6];
    const float* vw_b    = (const float*)d_in[7];
    const float* aw_w    = (const float*)d_in[8];
    const float* aw_b    = (const float*)d_in[9];
    const float* scale_p = (const float*)d_in[10];
    const float* Tw      = (const float*)d_in[11];
    const float* Tb      = (const float*)d_in[12];
    const float* conv_w  = (const float*)d_in[13];
    const float* conv_b  = (const float*)d_in[14];
    float* out = (float*)d_out;

    // -------- workspace layout (floats), ~146.0 MB total --------------------
    float* ws = (float*)d_ws;
    unsigned short* zb16p = (unsigned short*)ws;     // padded lattice bf16, 10,061,824 floats (40.2MB)
    float* zc       = ws + 10061824;                 // 16,777,216 (64MB) conv output fp32
    float* xbf_f    = ws + 26839040;                 //  8,388,608 (32MB) bf16 input frags
    float* coordbuf = ws + 35227648;                 //  1,048,576
    float* wt       = ws + 36276224;                 //     55,296 (conv bf16 weights, 112KB used)
    float* wkb_f    = ws + 36331520;                 //     40,960 (W_kv bf16 frags, 160KB)
    float* recs_f   = ws + 36372480;                 //    131,072 (262,144 u16)
    float* ha       = ws + 36503552;                 //      1,024
    float* mean_o   = ha + 1024;                     //        512
    float* rsig_o   = mean_o + 512;                  //        512
    float* mean_kv  = rsig_o + 512;                  //        608
    float* rsig_kv  = mean_kv + 608;                 //        608
    float* hk       = rsig_kv + 608;                 //        192
    float* hv       = hk + 192;                      //      1,024
    int*   counts   = (int*)(hv + 1024);             //      1,024 ints
    int*   base     = counts + 1024;                 //      1,025 ints
    int*   cursor   = base + 1025;                   //      1,024 ints
    // aliased into zc (dead before conv3d writes zc):
    float* vbuf = zc;                                //  4,194,304 (16MB)
    float* kv   = zc + 4194304;                      //  4,980,736 (19MB)
    unsigned short* xbf  = (unsigned short*)xbf_f;
    unsigned short* wb16 = (unsigned short*)wt;
    unsigned short* wkb  = (unsigned short*)wkb_f;
    unsigned short* recs = (unsigned short*)recs_f;

    zero_bins<<<1, 1024, 0, stream>>>(counts);
    zero_halo<<<(32 * HALO_ + 255) / 256, 256, 0, stream>>>(zb16p);
    style_proj<<<B_, 256, 0, stream>>>(style, kw_w, kw_b, vw_w, vw_b, aw_w, aw_b, hk, hv, ha);
    wtrans_bf<<<224, 256, 0, stream>>>(conv_w, wb16);
    wconvert<<<40, 256, 0, stream>>>(Wkv, wkb);
    xconvert<<<8192, 256, 0, stream>>>(input, xbf);
    kv_gemm_mfma<<<dim3(16, 10, B_), 256, 0, stream>>>(xbf, wkb, kv);
    stats_kernel<<<B_ * CO_, 256, 0, stream>>>(kv, mean_kv, rsig_kv);
    point_prep<<<B_ * H_ * N_ / 256, 256, 0, stream>>>(
        kv, mean_kv, rsig_kv, hk, hv, orig, scale_p, Tw, Tb,
        (float4*)coordbuf, vbuf, counts);
    prefix_bins<<<1, 64, 0, stream>>>(counts, base, cursor);
    scatter_pts<<<B_ * H_ * N_ / 256, 256, 0, stream>>>((const float4*)coordbuf, cursor, recs);
    splat3<<<1024, 1024, 0, stream>>>((const float4*)coordbuf, vbuf, base, recs, zb16p);
    conv3d_mfma<<<2048, 256, 0, stream>>>(zb16p, wb16, conv_b, zc);
    slice_vm<<<B_ * H_ * N_ / 256, 256, 0, stream>>>(zc, (const float4*)coordbuf, out);
    stats_kernel<<<B_ * HF_, 256, 0, stream>>>(out, mean_o, rsig_o);
    final_adain<<<B_ * HF_ * N_ / 256, 256, 0, stream>>>(out, mean_o, rsig_o, ha);
}

// Round 12
// 230.383 us; speedup vs baseline: 3.0186x; 1.0910x over previous
//
#include <hip/hip_runtime.h>
#include <hip/hip_bf16.h>
#include <math.h>

#define B_ 4
#define N_ 8192
#define MD_ 512
#define H_ 8
#define F_ 16
#define S_ 32
#define S3_ 32768
#define L_ 256
#define CO_ 152   // H*(F+3)
#define HF_ 128   // H*F
#define EPS_ 1e-5f
#define CHUNK_ 2048
#define PS_ 34            // padded lattice dim
#define PS2_ 1156         // 34*34
#define PV_ 39304         // 34^3 voxels per (b,h)
#define HALO_ 6536        // 34^3 - 32^3

typedef __attribute__((ext_vector_type(8))) short bf16x8;
typedef __attribute__((ext_vector_type(4))) float f32x4;

__device__ inline unsigned short f2bf(float f) {   // RNE fp32 -> bf16
    unsigned u = __float_as_uint(f);
    return (unsigned short)((u + 0x7FFFu + ((u >> 16) & 1u)) >> 16);
}

// ---------------- fused setup: zero_bins + style_proj + wtrans_bf + wconvert
__global__ __launch_bounds__(256) void setup_misc(
    const float* __restrict__ style,
    const float* __restrict__ kw_w, const float* __restrict__ kw_b,
    const float* __restrict__ vw_w, const float* __restrict__ vw_b,
    const float* __restrict__ aw_w, const float* __restrict__ aw_b,
    const float* __restrict__ cw, const float* __restrict__ Wkv,
    float* __restrict__ hk, float* __restrict__ hv, float* __restrict__ ha,
    unsigned short* __restrict__ wb, unsigned short* __restrict__ wkb,
    int* __restrict__ counts) {
    int blk = blockIdx.x;
    int tid = threadIdx.x;
    if (blk == 0) {                       // zero the 1024 bin counters
        #pragma unroll
        for (int q = 0; q < 4; ++q) counts[q * 256 + tid] = 0;
    } else if (blk < 5) {                 // style projections (4 blocks)
        int b = blk - 1;
        const float* st = style + b * L_;
        for (int r = tid; r < 48 + 256 + 256; r += 256) {
            const float* wrow; float bias; float* dst; int j;
            if (r < 48)       { j = r;       wrow = kw_w + j * L_; bias = kw_b[j]; dst = hk + b * 48; }
            else if (r < 304) { j = r - 48;  wrow = vw_w + j * L_; bias = vw_b[j]; dst = hv + b * 256; }
            else              { j = r - 304; wrow = aw_w + j * L_; bias = aw_b[j]; dst = ha + b * 256; }
            float acc = bias;
            for (int l = 0; l < L_; ++l) acc = fmaf(st[l], wrow[l], acc);
            dst[j] = acc;
        }
    } else if (blk < 229) {               // conv weights -> bf16 [h][28][oc][ic]
        int i = (blk - 5) * 256 + tid;    // 57344 total
        if (i < 57344) {
            int ic  = i & 15;
            int oc  = (i >> 4) & 15;
            int tap = (i >> 8) % 28;
            int h   = (i >> 8) / 28;
            float v = (tap < 27) ? cw[(((h * 16 + oc) * 16 + ic) * 27) + tap] : 0.f;
            wb[i] = f2bf(v);
        }
    } else {                              // W_kv -> bf16 frags [mt][kc][r16][k8]
        int i = (blk - 229) * 256 + tid;  // 10240 total
        if (i < 10240) {
            int r  = i & 15;
            int kc = (i >> 4) & 63;
            int mt = i >> 10;
            int row = mt * 16 + r;
            unsigned int pk[4];
            #pragma unroll
            for (int j = 0; j < 4; ++j) {
                float v0 = (row < CO_) ? Wkv[(size_t)row * MD_ + kc * 8 + 2 * j] : 0.f;
                float v1 = (row < CO_) ? Wkv[(size_t)row * MD_ + kc * 8 + 2 * j + 1] : 0.f;
                pk[j] = (unsigned)f2bf(v0) | ((unsigned)f2bf(v1) << 16);
            }
            *(uint4*)(wkb + (((size_t)(mt * 64 + kc)) * 16 + r) * 8) =
                make_uint4(pk[0], pk[1], pk[2], pk[3]);
        }
    }
}

// zero only the halo shell of each padded lattice (interior fully written by splat3)
__global__ __launch_bounds__(256) void zero_halo(unsigned short* __restrict__ zb16p) {
    int i = blockIdx.x * 256 + threadIdx.x;     // 32 * 6536 total
    if (i >= 32 * HALO_) return;
    int bh = i / HALO_;
    int j  = i - bh * HALO_;
    int x, y, z;
    if (j < 2312) {                 // x = 0 or 33 full planes
        x = (j / 1156) * 33;
        int rem = j % 1156;
        y = rem / 34; z = rem % 34;
    } else {
        int k = j - 2312;
        x = 1 + k / 132;
        int m = k % 132;
        if (m < 34)       { y = 0;  z = m; }
        else if (m < 68)  { y = 33; z = m - 34; }
        else if (m < 100) { y = m - 68 + 1;  z = 0; }
        else              { y = m - 100 + 1; z = 33; }
    }
    int pv = (x * PS_ + y) * PS_ + z;
    unsigned short* p = zb16p + ((size_t)bh * PV_ + pv) * 16;
    ((uint4*)p)[0] = make_uint4(0, 0, 0, 0);
    ((uint4*)p)[1] = make_uint4(0, 0, 0, 0);
}

// ---------------- input -> bf16 fragment layout [b][nt(512)][kc(64)][n16][k8]
__global__ __launch_bounds__(256) void xconvert(
    const float* __restrict__ X, unsigned short* __restrict__ xb) {
    int i = blockIdx.x * 256 + threadIdx.x;   // 4*64*8192 = 2,097,152
    int n  = i & (N_ - 1);
    int kc = (i >> 13) & 63;
    int b  = i >> 19;
    const float* xp = X + ((size_t)b * MD_ + kc * 8) * N_ + n;
    unsigned int pk[4];
    #pragma unroll
    for (int j = 0; j < 4; ++j) {
        float v0 = xp[(size_t)(2 * j) * N_];
        float v1 = xp[(size_t)(2 * j + 1) * N_];
        pk[j] = (unsigned)f2bf(v0) | ((unsigned)f2bf(v1) << 16);
    }
    int nt = n >> 4, n16 = n & 15;
    *(uint4*)(xb + ((((size_t)(b * 512 + nt)) * 64 + kc) * 16 + n16) * 8) =
        make_uint4(pk[0], pk[1], pk[2], pk[3]);
}

// ---------------- kv = W_kv @ input via bf16 MFMA (no LDS, no barriers) -----
__global__ __launch_bounds__(256) void kv_gemm_mfma(
    const unsigned short* __restrict__ xb, const unsigned short* __restrict__ wkb,
    float* __restrict__ kv) {
    int b  = blockIdx.z;
    int mt = blockIdx.y;
    int lane = threadIdx.x & 63, wv = threadIdx.x >> 6;
    int rc = lane & 15, kg = lane >> 4;
    int n0 = blockIdx.x * 512 + wv * 128;
    int nt0 = n0 >> 4;
    const unsigned short* ap = wkb + (((size_t)(mt * 64 + kg)) * 16 + rc) * 8;
    const unsigned short* bp = xb + ((((size_t)(b * 512 + nt0)) * 64 + kg) * 16 + rc) * 8;
    f32x4 acc[8];
    #pragma unroll
    for (int j = 0; j < 8; ++j) acc[j] = (f32x4){0.f, 0.f, 0.f, 0.f};
    #pragma unroll 1
    for (int ks = 0; ks < 16; ++ks) {
        bf16x8 a = *(const bf16x8*)(ap + ks * 512);
        #pragma unroll
        for (int j = 0; j < 8; ++j) {
            bf16x8 bfr = *(const bf16x8*)(bp + (size_t)j * 8192 + ks * 512);
            acc[j] = __builtin_amdgcn_mfma_f32_16x16x32_bf16(a, bfr, acc[j], 0, 0, 0);
        }
    }
    #pragma unroll
    for (int j = 0; j < 8; ++j) {
        int col = n0 + j * 16 + rc;
        #pragma unroll
        for (int r = 0; r < 4; ++r) {
            int m = mt * 16 + kg * 4 + r;
            if (m < CO_) kv[((size_t)b * CO_ + m) * N_ + col] = acc[j][r];
        }
    }
}

// ---------------- per-(b,channel) mean / rsig over N ------------------------
__global__ __launch_bounds__(256) void stats_kernel(
    const float* __restrict__ x, float* __restrict__ mean, float* __restrict__ rsig) {
    int bc = blockIdx.x;
    const float* p = x + (size_t)bc * N_;
    float s = 0.f, s2 = 0.f;
    for (int i = threadIdx.x; i < N_; i += 256) {
        float v = p[i]; s += v; s2 = fmaf(v, v, s2);
    }
    #pragma unroll
    for (int off = 32; off; off >>= 1) { s += __shfl_down(s, off); s2 += __shfl_down(s2, off); }
    __shared__ float ls[4], ls2[4];
    int wid = threadIdx.x >> 6;
    if ((threadIdx.x & 63) == 0) { ls[wid] = s; ls2[wid] = s2; }
    __syncthreads();
    if (threadIdx.x == 0) {
        float S = ls[0] + ls[1] + ls[2] + ls[3];
        float S2 = ls2[0] + ls2[1] + ls2[2] + ls2[3];
        float mu = S * (1.f / N_);
        float var = S2 * (1.f / N_) - mu * mu;
        mean[bc] = mu;
        rsig[bc] = rsqrtf(var + EPS_);
    }
}

// ---------------- point prep: AdaIN + transform + tanh + interp + count -----
__global__ __launch_bounds__(256) void point_prep(
    const float* __restrict__ kv, const float* __restrict__ mean_kv,
    const float* __restrict__ rsig_kv, const float* __restrict__ hk,
    const float* __restrict__ hv, const float* __restrict__ orig,
    const float* __restrict__ scale_p, const float* __restrict__ Tw,
    const float* __restrict__ Tb,
    float4* __restrict__ coordbuf, float* __restrict__ vbuf,
    int* __restrict__ counts) {
    __shared__ int s_hist[32];
    int tid = threadIdx.x;
    if (tid < 32) s_hist[tid] = 0;
    __syncthreads();
    int p = blockIdx.x * 256 + tid;
    int n = p & (N_ - 1);
    int bh = p >> 13;               // uniform per block
    int h = bh & 7, b = bh >> 3;
    float scl = scale_p[0];

    float pt[3];
    #pragma unroll
    for (int j = 0; j < 3; ++j) {
        int c = h * 3 + j;
        float x  = kv[((size_t)(b * CO_ + c)) * N_ + n];
        float xn = (x - mean_kv[b * CO_ + c]) * rsig_kv[b * CO_ + c];
        float kr = fmaf(1.f + hk[b * 48 + c], xn, hk[b * 48 + 24 + c]);
        pt[j] = fmaf(scl, kr, orig[((size_t)(b * 3 + j)) * N_ + n]);
    }
    int f0[3]; float tt[3];
    #pragma unroll
    for (int i = 0; i < 3; ++i) {
        float key = Tb[h * 3 + i];
        #pragma unroll
        for (int j = 0; j < 3; ++j) key = fmaf(Tw[(h * 3 + i) * 3 + j], pt[j], key);
        float lat = tanhf(key);
        float g = (lat + 1.f) * 0.5f * (float)(S_ - 1);
        float ff = floorf(g);
        ff = fminf(fmaxf(ff, 0.f), 30.f);
        f0[i] = (int)ff;
        tt[i] = fminf(fmaxf(g - ff, 0.f), 1.f);
    }
    coordbuf[p] = make_float4(tt[0], tt[1], tt[2],
                              __int_as_float(f0[0] | (f0[1] << 5) | (f0[2] << 10)));
    atomicAdd(&s_hist[f0[0]], 1);   // LDS
    float vf[16];
    #pragma unroll
    for (int f = 0; f < F_; ++f) {
        int c = 24 + h * F_ + f;
        float x  = kv[((size_t)(b * CO_ + c)) * N_ + n];
        float xn = (x - mean_kv[b * CO_ + c]) * rsig_kv[b * CO_ + c];
        int cv = h * F_ + f;
        vf[f] = fmaf(1.f + hv[b * 256 + cv], xn, hv[b * 256 + 128 + cv]);
    }
    float4* vb = (float4*)(vbuf + (size_t)p * 16);
    #pragma unroll
    for (int q = 0; q < 4; ++q)
        vb[q] = make_float4(vf[q * 4], vf[q * 4 + 1], vf[q * 4 + 2], vf[q * 4 + 3]);
    __syncthreads();
    if (tid < 32 && s_hist[tid] > 0)
        atomicAdd(&counts[(bh << 5) + tid], s_hist[tid]);
}

// ---------------- exclusive prefix over the 1024 bins (one wave) ------------
__global__ __launch_bounds__(64) void prefix_bins(
    const int* __restrict__ counts, int* __restrict__ base, int* __restrict__ cursor) {
    int lane = threadIdx.x;
    int local[16], sum = 0;
    #pragma unroll
    for (int i = 0; i < 16; ++i) { local[i] = sum; sum += counts[lane * 16 + i]; }
    int incl = sum;
    #pragma unroll
    for (int off = 1; off < 64; off <<= 1) {
        int v = __shfl_up(incl, off);
        if (lane >= off) incl += v;
    }
    int excl = incl - sum;
    #pragma unroll
    for (int i = 0; i < 16; ++i) {
        int bse = excl + local[i];
        base[lane * 16 + i] = bse;
        cursor[lane * 16 + i] = bse;
    }
    if (lane == 63) base[1024] = excl + sum;
}

// ---------------- scatter point indices into bins (LDS-aggregated) ----------
__global__ __launch_bounds__(256) void scatter_pts(
    const float4* __restrict__ coordbuf, int* __restrict__ cursor,
    unsigned short* __restrict__ recs) {
    __shared__ int s_hist[32];
    __shared__ int s_base[32];
    int tid = threadIdx.x;
    if (tid < 32) s_hist[tid] = 0;
    __syncthreads();
    int p = blockIdx.x * 256 + tid;
    int bh = p >> 13;               // uniform per block
    int pk = __float_as_int(((const float*)coordbuf)[(size_t)p * 4 + 3]);
    int f0x = pk & 31;
    int rank = atomicAdd(&s_hist[f0x], 1);   // LDS
    __syncthreads();
    if (tid < 32 && s_hist[tid] > 0)
        s_base[tid] = atomicAdd(&cursor[(bh << 5) + tid], s_hist[tid]);
    __syncthreads();
    recs[s_base[f0x] + rank] = (unsigned short)(p & (N_ - 1));
}

// ---------------- splat3: in-block sub-sort by (y,z), register gather -------
__global__ __launch_bounds__(1024) void splat3(
    const float4* __restrict__ coordbuf, const float* __restrict__ vbuf,
    const int* __restrict__ base, const unsigned short* __restrict__ recs,
    unsigned short* __restrict__ zb16p) {
    __shared__ int s_cnt[1024];
    __shared__ int s_start[1024];
    __shared__ int s_cur[1024];
    __shared__ unsigned int s_pts[CHUNK_];
    __shared__ unsigned int s_sorted[CHUNK_];
    __shared__ int s_wavesum[16];
    int logical = (blockIdx.x & 7) * 128 + (blockIdx.x >> 3);  // XCD swizzle
    int bh = logical >> 5;
    int x0 = logical & 31;
    int tid = threadIdx.x;
    int y = tid >> 5, zc = tid & 31;
    int bin0 = (bh << 5) + x0;
    int s0 = base[bin0], len0 = base[bin0 + 1] - s0;
    int s1 = 0, len1 = 0;
    if (x0 > 0) { s1 = base[bin0 - 1]; len1 = s0 - s1; }
    int total = len0 + len1;
    const float4* cb = coordbuf + (size_t)bh * N_;
    const float* vb = vbuf + ((size_t)bh * N_) * 16;
    float acc[16];
    #pragma unroll
    for (int i = 0; i < 16; ++i) acc[i] = 0.f;

    for (int c0 = 0; c0 < total; c0 += CHUNK_) {
        int cl = min(CHUNK_, total - c0);
        s_cnt[tid] = 0;
        __syncthreads();
        for (int t = tid; t < cl; t += 1024) {
            int tp = c0 + t, n, cx;
            if (tp < len0) { n = recs[s0 + tp]; cx = 0; }
            else           { n = recs[s1 + (tp - len0)]; cx = 1; }
            int pk = __float_as_int(cb[n].w);
            int sb = (((pk >> 5) & 31) << 5) | ((pk >> 10) & 31);
            s_pts[t] = ((unsigned)sb << 16) | ((unsigned)cx << 14) | (unsigned)n;
            atomicAdd(&s_cnt[sb], 1);
        }
        __syncthreads();
        int v = s_cnt[tid];
        int incl = v;
        #pragma unroll
        for (int off = 1; off < 64; off <<= 1) {
            int u = __shfl_up(incl, off);
            if ((tid & 63) >= off) incl += u;
        }
        int wid = tid >> 6;
        if ((tid & 63) == 63) s_wavesum[wid] = incl;
        __syncthreads();
        if (tid < 16) {
            int wv = s_wavesum[tid];
            int wincl = wv;
            #pragma unroll
            for (int off = 1; off < 16; off <<= 1) {
                int u = __shfl_up(wincl, off);
                if (tid >= off) wincl += u;
            }
            s_wavesum[tid] = wincl - wv;
        }
        __syncthreads();
        int excl = incl - v + s_wavesum[wid];
        s_start[tid] = excl;
        s_cur[tid] = excl;
        __syncthreads();
        for (int t = tid; t < cl; t += 1024) {
            unsigned rec = s_pts[t];
            int slot = atomicAdd(&s_cur[rec >> 16], 1);
            s_sorted[slot] = rec;
        }
        __syncthreads();
        #pragma unroll
        for (int sy = 0; sy < 2; ++sy) {
            int yy = y - sy;
            if (yy < 0) continue;
            #pragma unroll
            for (int sz = 0; sz < 2; ++sz) {
                int zz = zc - sz;
                if (zz < 0) continue;
                int sb = (yy << 5) | zz;
                int s = s_start[sb], e = s + s_cnt[sb];
                for (int i = s; i < e; ++i) {
                    unsigned rec = s_sorted[i];
                    int n = rec & 0x3FFF;
                    int cx = (rec >> 14) & 1;
                    float4 c = cb[n];
                    float wx = cx ? c.x : 1.f - c.x;
                    float wy = sy ? c.y : 1.f - c.y;
                    float wz = sz ? c.z : 1.f - c.z;
                    float w = wx * wy * wz;
                    const float4* vp = (const float4*)(vb + (size_t)n * 16);
                    float4 a0 = vp[0], a1 = vp[1], a2 = vp[2], a3 = vp[3];
                    acc[0]  = fmaf(w, a0.x, acc[0]);  acc[1]  = fmaf(w, a0.y, acc[1]);
                    acc[2]  = fmaf(w, a0.z, acc[2]);  acc[3]  = fmaf(w, a0.w, acc[3]);
                    acc[4]  = fmaf(w, a1.x, acc[4]);  acc[5]  = fmaf(w, a1.y, acc[5]);
                    acc[6]  = fmaf(w, a1.z, acc[6]);  acc[7]  = fmaf(w, a1.w, acc[7]);
                    acc[8]  = fmaf(w, a2.x, acc[8]);  acc[9]  = fmaf(w, a2.y, acc[9]);
                    acc[10] = fmaf(w, a2.z, acc[10]); acc[11] = fmaf(w, a2.w, acc[11]);
                    acc[12] = fmaf(w, a3.x, acc[12]); acc[13] = fmaf(w, a3.y, acc[13]);
                    acc[14] = fmaf(w, a3.z, acc[14]); acc[15] = fmaf(w, a3.w, acc[15]);
                }
            }
        }
        __syncthreads();
    }
    unsigned int pk[8];
    #pragma unroll
    for (int q = 0; q < 8; ++q)
        pk[q] = (unsigned)f2bf(acc[2 * q]) | ((unsigned)f2bf(acc[2 * q + 1]) << 16);
    int pv = ((x0 + 1) * PS_ + y + 1) * PS_ + zc + 1;
    unsigned short* zb = zb16p + ((size_t)bh * PV_ + pv) * 16;
    ((uint4*)zb)[0] = make_uint4(pk[0], pk[1], pk[2], pk[3]);
    ((uint4*)zb)[1] = make_uint4(pk[4], pk[5], pk[6], pk[7]);
}

// ---------------- grouped 3x3x3 conv via bf16 MFMA, bf16 output -------------
__global__ __launch_bounds__(256) void conv3d_mfma(
    const unsigned short* __restrict__ zp, const unsigned short* __restrict__ wb,
    const float* __restrict__ cbias, unsigned short* __restrict__ zcb16) {
    int logical = (blockIdx.x & 7) * 256 + (blockIdx.x >> 3);  // 2048 = 8*256
    int bh = logical >> 6;
    int rest = logical & 63;
    int x = rest >> 1;
    int half = rest & 1;
    int h = bh & 7;
    int lane = threadIdx.x & 63;
    int wv = threadIdx.x >> 6;
    int rc = lane & 15;
    int kb = lane >> 4;
    int ic0 = (kb & 1) << 3;
    int tsel = kb >> 1;

    bf16x8 bfr[14];
    const unsigned short* wh = wb + h * 28 * 256;
    int doff[14];
    #pragma unroll
    for (int p = 0; p < 14; ++p) {
        int t = 2 * p + tsel;
        bfr[p] = *(const bf16x8*)(wh + (t * 16 + rc) * 16 + ic0);
        int dx = t / 9, r9 = t - dx * 9;
        int dy = r9 / 3, dz = r9 - dy * 3;
        doff[p] = (t < 27) ? ((dx - 1) * PS2_ + (dy - 1) * PS_ + (dz - 1)) * 32 : 0;
    }
    float bias = cbias[h * 16 + rc];
    const char* zb = (const char*)(zp + (size_t)bh * PV_ * 16);
    unsigned short* zcb = zcb16 + ((size_t)bh << 19);
    int basex = (x + 1) * PS2_;

    #pragma unroll 1
    for (int ti = 0; ti < 8; ++ti) {
        int tile = wv * 8 + ti;                   // 0..31
        int y = half * 16 + (tile >> 1);
        int z0 = (tile & 1) << 4;
        int vbase = (basex + (y + 1) * PS_ + z0 + rc + 1) * 32 + ic0 * 2;
        f32x4 acc0 = {0.f, 0.f, 0.f, 0.f};
        f32x4 acc1 = {0.f, 0.f, 0.f, 0.f};
        #pragma unroll
        for (int p = 0; p < 14; p += 2) {
            bf16x8 a0 = *(const bf16x8*)(zb + vbase + doff[p]);
            bf16x8 a1 = *(const bf16x8*)(zb + vbase + doff[p + 1]);
            acc0 = __builtin_amdgcn_mfma_f32_16x16x32_bf16(a0, bfr[p], acc0, 0, 0, 0);
            acc1 = __builtin_amdgcn_mfma_f32_16x16x32_bf16(a1, bfr[p + 1], acc1, 0, 0, 0);
        }
        int vout = (((x << 5) + y) << 5) + z0 + (kb << 2);
        #pragma unroll
        for (int r = 0; r < 4; ++r)
            zcb[(size_t)(vout + r) * 16 + rc] = f2bf(acc0[r] + acc1[r] + bias);
    }
}

// ---------------- slice: weighted gather (bf16 zc, XCD-swizzled) ------------
__global__ __launch_bounds__(256) void slice_vm(
    const unsigned short* __restrict__ zcb16, const float4* __restrict__ coordbuf,
    float* __restrict__ out) {
    int logical = (blockIdx.x & 7) * 128 + (blockIdx.x >> 3);  // 1024 = 8*128
    int p = logical * 256 + threadIdx.x;
    int n = p & (N_ - 1);
    int bh = p >> 13;
    int h = bh & 7, b = bh >> 3;
    float4 c = coordbuf[p];
    int pk = __float_as_int(c.w);
    int f0x = pk & 31, f0y = (pk >> 5) & 31, f0z = (pk >> 10) & 31;
    const unsigned short* gb = zcb16 + ((size_t)bh << 19);
    float acc[16];
    #pragma unroll
    for (int f = 0; f < 16; ++f) acc[f] = 0.f;
    #pragma unroll 1
    for (int k = 0; k < 8; ++k) {
        int cx = (k >> 2) & 1, cy = (k >> 1) & 1, cz = k & 1;
        float w = (cx ? c.x : 1.f - c.x) * (cy ? c.y : 1.f - c.y) * (cz ? c.z : 1.f - c.z);
        int vox = (((f0x + cx) << 5) + f0y + cy) * 32 + f0z + cz;
        const uint4* ip = (const uint4*)(gb + ((size_t)vox << 4));
        uint4 u0 = ip[0], u1 = ip[1];
        unsigned uu[8] = {u0.x, u0.y, u0.z, u0.w, u1.x, u1.y, u1.z, u1.w};
        #pragma unroll
        for (int q = 0; q < 8; ++q) {
            float lo = __uint_as_float(uu[q] << 16);
            float hi = __uint_as_float(uu[q] & 0xFFFF0000u);
            acc[2 * q]     = fmaf(w, lo, acc[2 * q]);
            acc[2 * q + 1] = fmaf(w, hi, acc[2 * q + 1]);
        }
    }
    #pragma unroll
    for (int f = 0; f < 16; ++f)
        out[(((size_t)(b * HF_ + h * F_ + f)) << 13) + n] = acc[f];
}

// ---------------- final AdaIN + ReLU (in place on d_out) --------------------
__global__ __launch_bounds__(256) void final_adain(
    float* __restrict__ out, const float* __restrict__ mean_o,
    const float* __restrict__ rsig_o, const float* __restrict__ ha) {
    size_t i = (size_t)blockIdx.x * 256 + threadIdx.x;
    int bc = (int)(i >> 13);
    int c = bc & 127, b = bc >> 7;
    float x = out[i];
    float xn = (x - mean_o[bc]) * rsig_o[bc];
    float y = fmaf(1.f + ha[b * 256 + c], xn, ha[b * 256 + 128 + c]);
    out[i] = fmaxf(y, 0.f);
}

extern "C" void kernel_launch(void* const* d_in, const int* in_sizes, int n_in,
                              void* d_out, int out_size, void* d_ws, size_t ws_size,
                              hipStream_t stream) {
    (void)in_sizes; (void)n_in; (void)out_size; (void)ws_size;
    const float* input   = (const float*)d_in[0];
    const float* style   = (const float*)d_in[1];
    const float* orig    = (const float*)d_in[2];
    const float* Wkv     = (const float*)d_in[3];
    const float* kw_w    = (const float*)d_in[4];
    const float* kw_b    = (const float*)d_in[5];
    const float* vw_w    = (const float*)d_in[6];
    const float* vw_b    = (const float*)d_in[7];
    const float* aw_w    = (const float*)d_in[8];
    const float* aw_b    = (const float*)d_in[9];
    const float* scale_p = (const float*)d_in[10];
    const float* Tw      = (const float*)d_in[11];
    const float* Tb      = (const float*)d_in[12];
    const float* conv_w  = (const float*)d_in[13];
    const float* conv_b  = (const float*)d_in[14];
    float* out = (float*)d_out;

    // -------- workspace layout (floats), ~146.0 MB total --------------------
    float* ws = (float*)d_ws;
    unsigned short* zb16p = (unsigned short*)ws;     // padded lattice bf16 (40.2MB)
    float* zc       = ws + 10061824;                 // 64MB region; conv uses first 32MB as bf16
    float* xbf_f    = ws + 26839040;                 //  8,388,608 (32MB) bf16 input frags
    float* coordbuf = ws + 35227648;                 //  1,048,576
    float* wt       = ws + 36276224;                 //     55,296 (conv bf16 weights, 112KB used)
    float* wkb_f    = ws + 36331520;                 //     40,960 (W_kv bf16 frags, 160KB)
    float* recs_f   = ws + 36372480;                 //    131,072 (262,144 u16)
    float* ha       = ws + 36503552;                 //      1,024
    float* mean_o   = ha + 1024;                     //        512
    float* rsig_o   = mean_o + 512;                  //        512
    float* mean_kv  = rsig_o + 512;                  //        608
    float* rsig_kv  = mean_kv + 608;                 //        608
    float* hk       = rsig_kv + 608;                 //        192
    float* hv       = hk + 192;                      //      1,024
    int*   counts   = (int*)(hv + 1024);             //      1,024 ints
    int*   base     = counts + 1024;                 //      1,025 ints
    int*   cursor   = base + 1025;                   //      1,024 ints
    // aliased into zc region (dead before conv3d writes zcb16):
    float* vbuf = zc;                                //  4,194,304 (16MB)
    float* kv   = zc + 4194304;                      //  4,980,736 (19MB)
    unsigned short* zcb16 = (unsigned short*)zc;     // conv output bf16 (32MB)
    unsigned short* xbf  = (unsigned short*)xbf_f;
    unsigned short* wb16 = (unsigned short*)wt;
    unsigned short* wkb  = (unsigned short*)wkb_f;
    unsigned short* recs = (unsigned short*)recs_f;

    setup_misc<<<269, 256, 0, stream>>>(style, kw_w, kw_b, vw_w, vw_b, aw_w, aw_b,
                                        conv_w, Wkv, hk, hv, ha, wb16, wkb, counts);
    zero_halo<<<(32 * HALO_ + 255) / 256, 256, 0, stream>>>(zb16p);
    xconvert<<<8192, 256, 0, stream>>>(input, xbf);
    kv_gemm_mfma<<<dim3(16, 10, B_), 256, 0, stream>>>(xbf, wkb, kv);
    stats_kernel<<<B_ * CO_, 256, 0, stream>>>(kv, mean_kv, rsig_kv);
    point_prep<<<B_ * H_ * N_ / 256, 256, 0, stream>>>(
        kv, mean_kv, rsig_kv, hk, hv, orig, scale_p, Tw, Tb,
        (float4*)coordbuf, vbuf, counts);
    prefix_bins<<<1, 64, 0, stream>>>(counts, base, cursor);
    scatter_pts<<<B_ * H_ * N_ / 256, 256, 0, stream>>>((const float4*)coordbuf, cursor, recs);
    splat3<<<1024, 1024, 0, stream>>>((const float4*)coordbuf, vbuf, base, recs, zb16p);
    conv3d_mfma<<<2048, 256, 0, stream>>>(zb16p, wb16, conv_b, zcb16);
    slice_vm<<<B_ * H_ * N_ / 256, 256, 0, stream>>>(zcb16, (const float4*)coordbuf, out);
    stats_kernel<<<B_ * HF_, 256, 0, stream>>>(out, mean_o, rsig_o);
    final_adain<<<B_ * HF_ * N_ / 256, 256, 0, stream>>>(out, mean_o, rsig_o, ha);
}

// Round 13
// 206.865 us; speedup vs baseline: 3.3618x; 1.1137x over previous
//
#include <hip/hip_runtime.h>
#include <hip/hip_bf16.h>
#include <math.h>

#define B_ 4
#define N_ 8192
#define MD_ 512
#define H_ 8
#define F_ 16
#define S_ 32
#define S3_ 32768
#define L_ 256
#define CO_ 152   // H*(F+3)
#define HF_ 128   // H*F
#define EPS_ 1e-5f
#define CHUNK_ 2048
#define PS_ 34            // padded lattice dim
#define PS2_ 1156         // 34*34
#define PV_ 39304         // 34^3 voxels per (b,h)
#define HALO_ 6536        // 34^3 - 32^3

typedef __attribute__((ext_vector_type(8))) short bf16x8;
typedef __attribute__((ext_vector_type(4))) float f32x4;

__device__ inline unsigned short f2bf(float f) {   // RNE fp32 -> bf16
    unsigned u = __float_as_uint(f);
    return (unsigned short)((u + 0x7FFFu + ((u >> 16) & 1u)) >> 16);
}

// ---------------- fused setup: zero_bins + style_proj + conv-w + wconvert ---
// conv weights -> bf16 [h][30 slots][oc][ic]; slot s = p*2+tsel, p = dy*5+pair,
// pair<4: c=(dx*3+dz)=pair*2+tsel; pair4: c=8 both, tsel1 weights ZERO.
__global__ __launch_bounds__(256) void setup_misc(
    const float* __restrict__ style,
    const float* __restrict__ kw_w, const float* __restrict__ kw_b,
    const float* __restrict__ vw_w, const float* __restrict__ vw_b,
    const float* __restrict__ aw_w, const float* __restrict__ aw_b,
    const float* __restrict__ cw, const float* __restrict__ Wkv,
    float* __restrict__ hk, float* __restrict__ hv, float* __restrict__ ha,
    unsigned short* __restrict__ wb, unsigned short* __restrict__ wkb,
    int* __restrict__ counts) {
    int blk = blockIdx.x;
    int tid = threadIdx.x;
    if (blk == 0) {                       // zero the 1024 bin counters
        #pragma unroll
        for (int q = 0; q < 4; ++q) counts[q * 256 + tid] = 0;
    } else if (blk < 5) {                 // style projections (4 blocks)
        int b = blk - 1;
        const float* st = style + b * L_;
        for (int r = tid; r < 48 + 256 + 256; r += 256) {
            const float* wrow; float bias; float* dst; int j;
            if (r < 48)       { j = r;       wrow = kw_w + j * L_; bias = kw_b[j]; dst = hk + b * 48; }
            else if (r < 304) { j = r - 48;  wrow = vw_w + j * L_; bias = vw_b[j]; dst = hv + b * 256; }
            else              { j = r - 304; wrow = aw_w + j * L_; bias = aw_b[j]; dst = ha + b * 256; }
            float acc = bias;
            for (int l = 0; l < L_; ++l) acc = fmaf(st[l], wrow[l], acc);
            dst[j] = acc;
        }
    } else if (blk < 245) {               // conv weights, 61440 total
        int i = (blk - 5) * 256 + tid;
        if (i < 61440) {
            int ic = i & 15;
            int oc = (i >> 4) & 15;
            int s  = (i >> 8) % 30;
            int h  = (i >> 8) / 30;
            int p = s >> 1, tsel = s & 1;
            int pair = p % 5, dy = p / 5;
            int c = (pair < 4) ? (pair * 2 + tsel) : 8;
            bool zero = (pair == 4) && (tsel == 1);
            int tap = (c / 3) * 9 + dy * 3 + (c % 3);
            float v = zero ? 0.f : cw[(((h * 16 + oc) * 16 + ic) * 27) + tap];
            wb[i] = f2bf(v);
        }
    } else {                              // W_kv -> bf16 frags [mt][kc][r16][k8]
        int i = (blk - 245) * 256 + tid;  // 10240 total
        if (i < 10240) {
            int r  = i & 15;
            int kc = (i >> 4) & 63;
            int mt = i >> 10;
            int row = mt * 16 + r;
            unsigned int pk[4];
            #pragma unroll
            for (int j = 0; j < 4; ++j) {
                float v0 = (row < CO_) ? Wkv[(size_t)row * MD_ + kc * 8 + 2 * j] : 0.f;
                float v1 = (row < CO_) ? Wkv[(size_t)row * MD_ + kc * 8 + 2 * j + 1] : 0.f;
                pk[j] = (unsigned)f2bf(v0) | ((unsigned)f2bf(v1) << 16);
            }
            *(uint4*)(wkb + (((size_t)(mt * 64 + kc)) * 16 + r) * 8) =
                make_uint4(pk[0], pk[1], pk[2], pk[3]);
        }
    }
}

// zero only the halo shell of each padded lattice (interior fully written by splat3)
__global__ __launch_bounds__(256) void zero_halo(unsigned short* __restrict__ zb16p) {
    int i = blockIdx.x * 256 + threadIdx.x;     // 32 * 6536 total
    if (i >= 32 * HALO_) return;
    int bh = i / HALO_;
    int j  = i - bh * HALO_;
    int x, y, z;
    if (j < 2312) {                 // x = 0 or 33 full planes
        x = (j / 1156) * 33;
        int rem = j % 1156;
        y = rem / 34; z = rem % 34;
    } else {
        int k = j - 2312;
        x = 1 + k / 132;
        int m = k % 132;
        if (m < 34)       { y = 0;  z = m; }
        else if (m < 68)  { y = 33; z = m - 34; }
        else if (m < 100) { y = m - 68 + 1;  z = 0; }
        else              { y = m - 100 + 1; z = 33; }
    }
    int pv = (x * PS_ + y) * PS_ + z;
    unsigned short* p = zb16p + ((size_t)bh * PV_ + pv) * 16;
    ((uint4*)p)[0] = make_uint4(0, 0, 0, 0);
    ((uint4*)p)[1] = make_uint4(0, 0, 0, 0);
}

// ---------------- input -> bf16 fragment layout [b][nt(512)][kc(64)][n16][k8]
__global__ __launch_bounds__(256) void xconvert(
    const float* __restrict__ X, unsigned short* __restrict__ xb) {
    int i = blockIdx.x * 256 + threadIdx.x;   // 4*64*8192 = 2,097,152
    int n  = i & (N_ - 1);
    int kc = (i >> 13) & 63;
    int b  = i >> 19;
    const float* xp = X + ((size_t)b * MD_ + kc * 8) * N_ + n;
    unsigned int pk[4];
    #pragma unroll
    for (int j = 0; j < 4; ++j) {
        float v0 = xp[(size_t)(2 * j) * N_];
        float v1 = xp[(size_t)(2 * j + 1) * N_];
        pk[j] = (unsigned)f2bf(v0) | ((unsigned)f2bf(v1) << 16);
    }
    int nt = n >> 4, n16 = n & 15;
    *(uint4*)(xb + ((((size_t)(b * 512 + nt)) * 64 + kc) * 16 + n16) * 8) =
        make_uint4(pk[0], pk[1], pk[2], pk[3]);
}

// ---------------- kv = W_kv @ input via bf16 MFMA (no LDS, no barriers) -----
__global__ __launch_bounds__(256) void kv_gemm_mfma(
    const unsigned short* __restrict__ xb, const unsigned short* __restrict__ wkb,
    float* __restrict__ kv) {
    int b  = blockIdx.z;
    int mt = blockIdx.y;
    int lane = threadIdx.x & 63, wv = threadIdx.x >> 6;
    int rc = lane & 15, kg = lane >> 4;
    int n0 = blockIdx.x * 512 + wv * 128;
    int nt0 = n0 >> 4;
    const unsigned short* ap = wkb + (((size_t)(mt * 64 + kg)) * 16 + rc) * 8;
    const unsigned short* bp = xb + ((((size_t)(b * 512 + nt0)) * 64 + kg) * 16 + rc) * 8;
    f32x4 acc[8];
    #pragma unroll
    for (int j = 0; j < 8; ++j) acc[j] = (f32x4){0.f, 0.f, 0.f, 0.f};
    #pragma unroll 1
    for (int ks = 0; ks < 16; ++ks) {
        bf16x8 a = *(const bf16x8*)(ap + ks * 512);
        #pragma unroll
        for (int j = 0; j < 8; ++j) {
            bf16x8 bfr = *(const bf16x8*)(bp + (size_t)j * 8192 + ks * 512);
            acc[j] = __builtin_amdgcn_mfma_f32_16x16x32_bf16(a, bfr, acc[j], 0, 0, 0);
        }
    }
    #pragma unroll
    for (int j = 0; j < 8; ++j) {
        int col = n0 + j * 16 + rc;
        #pragma unroll
        for (int r = 0; r < 4; ++r) {
            int m = mt * 16 + kg * 4 + r;
            if (m < CO_) kv[((size_t)b * CO_ + m) * N_ + col] = acc[j][r];
        }
    }
}

// ---------------- per-(b,channel) mean / rsig over N ------------------------
__global__ __launch_bounds__(256) void stats_kernel(
    const float* __restrict__ x, float* __restrict__ mean, float* __restrict__ rsig) {
    int bc = blockIdx.x;
    const float* p = x + (size_t)bc * N_;
    float s = 0.f, s2 = 0.f;
    for (int i = threadIdx.x; i < N_; i += 256) {
        float v = p[i]; s += v; s2 = fmaf(v, v, s2);
    }
    #pragma unroll
    for (int off = 32; off; off >>= 1) { s += __shfl_down(s, off); s2 += __shfl_down(s2, off); }
    __shared__ float ls[4], ls2[4];
    int wid = threadIdx.x >> 6;
    if ((threadIdx.x & 63) == 0) { ls[wid] = s; ls2[wid] = s2; }
    __syncthreads();
    if (threadIdx.x == 0) {
        float S = ls[0] + ls[1] + ls[2] + ls[3];
        float S2 = ls2[0] + ls2[1] + ls2[2] + ls2[3];
        float mu = S * (1.f / N_);
        float var = S2 * (1.f / N_) - mu * mu;
        mean[bc] = mu;
        rsig[bc] = rsqrtf(var + EPS_);
    }
}

// ---------------- point prep: AdaIN + transform + tanh + interp + count -----
__global__ __launch_bounds__(256) void point_prep(
    const float* __restrict__ kv, const float* __restrict__ mean_kv,
    const float* __restrict__ rsig_kv, const float* __restrict__ hk,
    const float* __restrict__ hv, const float* __restrict__ orig,
    const float* __restrict__ scale_p, const float* __restrict__ Tw,
    const float* __restrict__ Tb,
    float4* __restrict__ coordbuf, float* __restrict__ vbuf,
    int* __restrict__ counts) {
    __shared__ int s_hist[32];
    int tid = threadIdx.x;
    if (tid < 32) s_hist[tid] = 0;
    __syncthreads();
    int p = blockIdx.x * 256 + tid;
    int n = p & (N_ - 1);
    int bh = p >> 13;               // uniform per block
    int h = bh & 7, b = bh >> 3;
    float scl = scale_p[0];

    float pt[3];
    #pragma unroll
    for (int j = 0; j < 3; ++j) {
        int c = h * 3 + j;
        float x  = kv[((size_t)(b * CO_ + c)) * N_ + n];
        float xn = (x - mean_kv[b * CO_ + c]) * rsig_kv[b * CO_ + c];
        float kr = fmaf(1.f + hk[b * 48 + c], xn, hk[b * 48 + 24 + c]);
        pt[j] = fmaf(scl, kr, orig[((size_t)(b * 3 + j)) * N_ + n]);
    }
    int f0[3]; float tt[3];
    #pragma unroll
    for (int i = 0; i < 3; ++i) {
        float key = Tb[h * 3 + i];
        #pragma unroll
        for (int j = 0; j < 3; ++j) key = fmaf(Tw[(h * 3 + i) * 3 + j], pt[j], key);
        float lat = tanhf(key);
        float g = (lat + 1.f) * 0.5f * (float)(S_ - 1);
        float ff = floorf(g);
        ff = fminf(fmaxf(ff, 0.f), 30.f);
        f0[i] = (int)ff;
        tt[i] = fminf(fmaxf(g - ff, 0.f), 1.f);
    }
    coordbuf[p] = make_float4(tt[0], tt[1], tt[2],
                              __int_as_float(f0[0] | (f0[1] << 5) | (f0[2] << 10)));
    atomicAdd(&s_hist[f0[0]], 1);   // LDS
    float vf[16];
    #pragma unroll
    for (int f = 0; f < F_; ++f) {
        int c = 24 + h * F_ + f;
        float x  = kv[((size_t)(b * CO_ + c)) * N_ + n];
        float xn = (x - mean_kv[b * CO_ + c]) * rsig_kv[b * CO_ + c];
        int cv = h * F_ + f;
        vf[f] = fmaf(1.f + hv[b * 256 + cv], xn, hv[b * 256 + 128 + cv]);
    }
    float4* vb = (float4*)(vbuf + (size_t)p * 16);
    #pragma unroll
    for (int q = 0; q < 4; ++q)
        vb[q] = make_float4(vf[q * 4], vf[q * 4 + 1], vf[q * 4 + 2], vf[q * 4 + 3]);
    __syncthreads();
    if (tid < 32 && s_hist[tid] > 0)
        atomicAdd(&counts[(bh << 5) + tid], s_hist[tid]);
}

// ---------------- exclusive prefix over the 1024 bins (one wave) ------------
__global__ __launch_bounds__(64) void prefix_bins(
    const int* __restrict__ counts, int* __restrict__ base, int* __restrict__ cursor) {
    int lane = threadIdx.x;
    int local[16], sum = 0;
    #pragma unroll
    for (int i = 0; i < 16; ++i) { local[i] = sum; sum += counts[lane * 16 + i]; }
    int incl = sum;
    #pragma unroll
    for (int off = 1; off < 64; off <<= 1) {
        int v = __shfl_up(incl, off);
        if (lane >= off) incl += v;
    }
    int excl = incl - sum;
    #pragma unroll
    for (int i = 0; i < 16; ++i) {
        int bse = excl + local[i];
        base[lane * 16 + i] = bse;
        cursor[lane * 16 + i] = bse;
    }
    if (lane == 63) base[1024] = excl + sum;
}

// ---------------- scatter point indices into bins (LDS-aggregated) ----------
__global__ __launch_bounds__(256) void scatter_pts(
    const float4* __restrict__ coordbuf, int* __restrict__ cursor,
    unsigned short* __restrict__ recs) {
    __shared__ int s_hist[32];
    __shared__ int s_base[32];
    int tid = threadIdx.x;
    if (tid < 32) s_hist[tid] = 0;
    __syncthreads();
    int p = blockIdx.x * 256 + tid;
    int bh = p >> 13;               // uniform per block
    int pk = __float_as_int(((const float*)coordbuf)[(size_t)p * 4 + 3]);
    int f0x = pk & 31;
    int rank = atomicAdd(&s_hist[f0x], 1);   // LDS
    __syncthreads();
    if (tid < 32 && s_hist[tid] > 0)
        s_base[tid] = atomicAdd(&cursor[(bh << 5) + tid], s_hist[tid]);
    __syncthreads();
    recs[s_base[f0x] + rank] = (unsigned short)(p & (N_ - 1));
}

// ---------------- splat3: in-block sub-sort by (y,z), register gather -------
__global__ __launch_bounds__(1024) void splat3(
    const float4* __restrict__ coordbuf, const float* __restrict__ vbuf,
    const int* __restrict__ base, const unsigned short* __restrict__ recs,
    unsigned short* __restrict__ zb16p) {
    __shared__ int s_cnt[1024];
    __shared__ int s_start[1024];
    __shared__ int s_cur[1024];
    __shared__ unsigned int s_pts[CHUNK_];
    __shared__ unsigned int s_sorted[CHUNK_];
    __shared__ int s_wavesum[16];
    int logical = (blockIdx.x & 7) * 128 + (blockIdx.x >> 3);  // XCD swizzle
    int bh = logical >> 5;
    int x0 = logical & 31;
    int tid = threadIdx.x;
    int y = tid >> 5, zc = tid & 31;
    int bin0 = (bh << 5) + x0;
    int s0 = base[bin0], len0 = base[bin0 + 1] - s0;
    int s1 = 0, len1 = 0;
    if (x0 > 0) { s1 = base[bin0 - 1]; len1 = s0 - s1; }
    int total = len0 + len1;
    const float4* cb = coordbuf + (size_t)bh * N_;
    const float* vb = vbuf + ((size_t)bh * N_) * 16;
    float acc[16];
    #pragma unroll
    for (int i = 0; i < 16; ++i) acc[i] = 0.f;

    for (int c0 = 0; c0 < total; c0 += CHUNK_) {
        int cl = min(CHUNK_, total - c0);
        s_cnt[tid] = 0;
        __syncthreads();
        for (int t = tid; t < cl; t += 1024) {
            int tp = c0 + t, n, cx;
            if (tp < len0) { n = recs[s0 + tp]; cx = 0; }
            else           { n = recs[s1 + (tp - len0)]; cx = 1; }
            int pk = __float_as_int(cb[n].w);
            int sb = (((pk >> 5) & 31) << 5) | ((pk >> 10) & 31);
            s_pts[t] = ((unsigned)sb << 16) | ((unsigned)cx << 14) | (unsigned)n;
            atomicAdd(&s_cnt[sb], 1);
        }
        __syncthreads();
        int v = s_cnt[tid];
        int incl = v;
        #pragma unroll
        for (int off = 1; off < 64; off <<= 1) {
            int u = __shfl_up(incl, off);
            if ((tid & 63) >= off) incl += u;
        }
        int wid = tid >> 6;
        if ((tid & 63) == 63) s_wavesum[wid] = incl;
        __syncthreads();
        if (tid < 16) {
            int wv = s_wavesum[tid];
            int wincl = wv;
            #pragma unroll
            for (int off = 1; off < 16; off <<= 1) {
                int u = __shfl_up(wincl, off);
                if (tid >= off) wincl += u;
            }
            s_wavesum[tid] = wincl - wv;
        }
        __syncthreads();
        int excl = incl - v + s_wavesum[wid];
        s_start[tid] = excl;
        s_cur[tid] = excl;
        __syncthreads();
        for (int t = tid; t < cl; t += 1024) {
            unsigned rec = s_pts[t];
            int slot = atomicAdd(&s_cur[rec >> 16], 1);
            s_sorted[slot] = rec;
        }
        __syncthreads();
        #pragma unroll
        for (int sy = 0; sy < 2; ++sy) {
            int yy = y - sy;
            if (yy < 0) continue;
            #pragma unroll
            for (int sz = 0; sz < 2; ++sz) {
                int zz = zc - sz;
                if (zz < 0) continue;
                int sb = (yy << 5) | zz;
                int s = s_start[sb], e = s + s_cnt[sb];
                for (int i = s; i < e; ++i) {
                    unsigned rec = s_sorted[i];
                    int n = rec & 0x3FFF;
                    int cx = (rec >> 14) & 1;
                    float4 c = cb[n];
                    float wx = cx ? c.x : 1.f - c.x;
                    float wy = sy ? c.y : 1.f - c.y;
                    float wz = sz ? c.z : 1.f - c.z;
                    float w = wx * wy * wz;
                    const float4* vp = (const float4*)(vb + (size_t)n * 16);
                    float4 a0 = vp[0], a1 = vp[1], a2 = vp[2], a3 = vp[3];
                    acc[0]  = fmaf(w, a0.x, acc[0]);  acc[1]  = fmaf(w, a0.y, acc[1]);
                    acc[2]  = fmaf(w, a0.z, acc[2]);  acc[3]  = fmaf(w, a0.w, acc[3]);
                    acc[4]  = fmaf(w, a1.x, acc[4]);  acc[5]  = fmaf(w, a1.y, acc[5]);
                    acc[6]  = fmaf(w, a1.z, acc[6]);  acc[7]  = fmaf(w, a1.w, acc[7]);
                    acc[8]  = fmaf(w, a2.x, acc[8]);  acc[9]  = fmaf(w, a2.y, acc[9]);
                    acc[10] = fmaf(w, a2.z, acc[10]); acc[11] = fmaf(w, a2.w, acc[11]);
                    acc[12] = fmaf(w, a3.x, acc[12]); acc[13] = fmaf(w, a3.y, acc[13]);
                    acc[14] = fmaf(w, a3.z, acc[14]); acc[15] = fmaf(w, a3.w, acc[15]);
                }
            }
        }
        __syncthreads();
    }
    unsigned int pk[8];
    #pragma unroll
    for (int q = 0; q < 8; ++q)
        pk[q] = (unsigned)f2bf(acc[2 * q]) | ((unsigned)f2bf(acc[2 * q + 1]) << 16);
    int pv = ((x0 + 1) * PS_ + y + 1) * PS_ + zc + 1;
    unsigned short* zb = zb16p + ((size_t)bh * PV_ + pv) * 16;
    ((uint4*)zb)[0] = make_uint4(pk[0], pk[1], pk[2], pk[3]);
    ((uint4*)zb)[1] = make_uint4(pk[4], pk[5], pk[6], pk[7]);
}

// ---------------- grouped 3x3x3 conv via bf16 MFMA, sliding y-window --------
// block = (bh, x); wave = (z-half, y-half); 15 MFMAs/row (5 pairs x 3 dy);
// 3-row x 5-frag register window: 5 new A-loads per output row (3x reuse).
__global__ __launch_bounds__(256) void conv3d_mfma(
    const unsigned short* __restrict__ zp, const unsigned short* __restrict__ wb,
    const float* __restrict__ cbias, unsigned short* __restrict__ zcb16) {
    int logical = (blockIdx.x & 7) * 128 + (blockIdx.x >> 3);  // 1024 = 8*128
    int bh = logical >> 5;
    int x  = logical & 31;
    int h = bh & 7;
    int lane = threadIdx.x & 63;
    int wv = threadIdx.x >> 6;
    int rc = lane & 15;
    int kb = lane >> 4;
    int ic0 = (kb & 1) << 3;
    int tsel = kb >> 1;
    int z0 = (wv & 1) << 4;
    int y0 = (wv >> 1) << 4;

    // per-lane byte offsets for its 5 (dx,dz) combos
    int aoff[5];
    #pragma unroll
    for (int pr = 0; pr < 5; ++pr) {
        int c = (pr < 4) ? (pr * 2 + tsel) : 8;
        int dx = c / 3, dz = c % 3;
        aoff[pr] = ((dx - 1) * PS2_ + (dz - 1)) * 32 + ic0 * 2;
    }
    // B-frags: 15 slots (pair4/tsel1 weights are zero by construction)
    bf16x8 bfr[15];
    const unsigned short* wh = wb + h * 30 * 256;
    #pragma unroll
    for (int p = 0; p < 15; ++p)
        bfr[p] = *(const bf16x8*)(wh + (((p * 2 + tsel) * 16 + rc) << 4) + ic0);
    float bias = cbias[h * 16 + rc];
    const char* zb = (const char*)(zp + (size_t)bh * PV_ * 16);
    unsigned short* zcb = zcb16 + ((size_t)bh << 19);
    int colbase = (x + 1) * PS2_ + z0 + rc + 1;

    // window: w0/w1/w2 hold rows y-1, y, y+1 (addr row term = (row+1)*PS_)
    bf16x8 w0[5], w1[5], w2[5];
    #pragma unroll
    for (int pr = 0; pr < 5; ++pr) {
        w0[pr] = *(const bf16x8*)(zb + (size_t)(colbase + (y0)     * PS_) * 32 + aoff[pr]);
        w1[pr] = *(const bf16x8*)(zb + (size_t)(colbase + (y0 + 1) * PS_) * 32 + aoff[pr]);
        w2[pr] = *(const bf16x8*)(zb + (size_t)(colbase + (y0 + 2) * PS_) * 32 + aoff[pr]);
    }
    #pragma unroll 1
    for (int y = y0; y < y0 + 16; ++y) {
        f32x4 a0 = {0.f, 0.f, 0.f, 0.f};
        f32x4 a1 = {0.f, 0.f, 0.f, 0.f};
        f32x4 a2 = {0.f, 0.f, 0.f, 0.f};
        #pragma unroll
        for (int pr = 0; pr < 5; ++pr) {
            a0 = __builtin_amdgcn_mfma_f32_16x16x32_bf16(w0[pr], bfr[pr],      a0, 0, 0, 0);
            a1 = __builtin_amdgcn_mfma_f32_16x16x32_bf16(w1[pr], bfr[5 + pr],  a1, 0, 0, 0);
            a2 = __builtin_amdgcn_mfma_f32_16x16x32_bf16(w2[pr], bfr[10 + pr], a2, 0, 0, 0);
        }
        int vout = (((x << 5) + y) << 5) + z0 + (kb << 2);
        #pragma unroll
        for (int r = 0; r < 4; ++r)
            zcb[(size_t)(vout + r) * 16 + rc] = f2bf(a0[r] + a1[r] + a2[r] + bias);
        #pragma unroll
        for (int pr = 0; pr < 5; ++pr) { w0[pr] = w1[pr]; w1[pr] = w2[pr]; }
        if (y < y0 + 15) {
            #pragma unroll
            for (int pr = 0; pr < 5; ++pr)
                w2[pr] = *(const bf16x8*)(zb + (size_t)(colbase + (y + 3) * PS_) * 32 + aoff[pr]);
        }
    }
}

// ---------------- slice: weighted gather (bf16 zc, XCD-swizzled) ------------
__global__ __launch_bounds__(256) void slice_vm(
    const unsigned short* __restrict__ zcb16, const float4* __restrict__ coordbuf,
    float* __restrict__ out) {
    int logical = (blockIdx.x & 7) * 128 + (blockIdx.x >> 3);  // 1024 = 8*128
    int p = logical * 256 + threadIdx.x;
    int n = p & (N_ - 1);
    int bh = p >> 13;
    int h = bh & 7, b = bh >> 3;
    float4 c = coordbuf[p];
    int pk = __float_as_int(c.w);
    int f0x = pk & 31, f0y = (pk >> 5) & 31, f0z = (pk >> 10) & 31;
    const unsigned short* gb = zcb16 + ((size_t)bh << 19);
    float acc[16];
    #pragma unroll
    for (int f = 0; f < 16; ++f) acc[f] = 0.f;
    #pragma unroll 1
    for (int k = 0; k < 8; ++k) {
        int cx = (k >> 2) & 1, cy = (k >> 1) & 1, cz = k & 1;
        float w = (cx ? c.x : 1.f - c.x) * (cy ? c.y : 1.f - c.y) * (cz ? c.z : 1.f - c.z);
        int vox = (((f0x + cx) << 5) + f0y + cy) * 32 + f0z + cz;
        const uint4* ip = (const uint4*)(gb + ((size_t)vox << 4));
        uint4 u0 = ip[0], u1 = ip[1];
        unsigned uu[8] = {u0.x, u0.y, u0.z, u0.w, u1.x, u1.y, u1.z, u1.w};
        #pragma unroll
        for (int q = 0; q < 8; ++q) {
            float lo = __uint_as_float(uu[q] << 16);
            float hi = __uint_as_float(uu[q] & 0xFFFF0000u);
            acc[2 * q]     = fmaf(w, lo, acc[2 * q]);
            acc[2 * q + 1] = fmaf(w, hi, acc[2 * q + 1]);
        }
    }
    #pragma unroll
    for (int f = 0; f < 16; ++f)
        out[(((size_t)(b * HF_ + h * F_ + f)) << 13) + n] = acc[f];
}

// ---------------- final AdaIN + ReLU (in place on d_out) --------------------
__global__ __launch_bounds__(256) void final_adain(
    float* __restrict__ out, const float* __restrict__ mean_o,
    const float* __restrict__ rsig_o, const float* __restrict__ ha) {
    size_t i = (size_t)blockIdx.x * 256 + threadIdx.x;
    int bc = (int)(i >> 13);
    int c = bc & 127, b = bc >> 7;
    float x = out[i];
    float xn = (x - mean_o[bc]) * rsig_o[bc];
    float y = fmaf(1.f + ha[b * 256 + c], xn, ha[b * 256 + 128 + c]);
    out[i] = fmaxf(y, 0.f);
}

extern "C" void kernel_launch(void* const* d_in, const int* in_sizes, int n_in,
                              void* d_out, int out_size, void* d_ws, size_t ws_size,
                              hipStream_t stream) {
    (void)in_sizes; (void)n_in; (void)out_size; (void)ws_size;
    const float* input   = (const float*)d_in[0];
    const float* style   = (const float*)d_in[1];
    const float* orig    = (const float*)d_in[2];
    const float* Wkv     = (const float*)d_in[3];
    const float* kw_w    = (const float*)d_in[4];
    const float* kw_b    = (const float*)d_in[5];
    const float* vw_w    = (const float*)d_in[6];
    const float* vw_b    = (const float*)d_in[7];
    const float* aw_w    = (const float*)d_in[8];
    const float* aw_b    = (const float*)d_in[9];
    const float* scale_p = (const float*)d_in[10];
    const float* Tw      = (const float*)d_in[11];
    const float* Tb      = (const float*)d_in[12];
    const float* conv_w  = (const float*)d_in[13];
    const float* conv_b  = (const float*)d_in[14];
    float* out = (float*)d_out;

    // -------- workspace layout (floats), ~146.0 MB total --------------------
    float* ws = (float*)d_ws;
    unsigned short* zb16p = (unsigned short*)ws;     // padded lattice bf16 (40.2MB)
    float* zc       = ws + 10061824;                 // 64MB region; conv uses first 32MB as bf16
    float* xbf_f    = ws + 26839040;                 //  8,388,608 (32MB) bf16 input frags
    float* coordbuf = ws + 35227648;                 //  1,048,576
    float* wt       = ws + 36276224;                 //     55,296 floats (conv bf16 weights, 120KB used)
    float* wkb_f    = ws + 36331520;                 //     40,960 (W_kv bf16 frags, 160KB)
    float* recs_f   = ws + 36372480;                 //    131,072 (262,144 u16)
    float* ha       = ws + 36503552;                 //      1,024
    float* mean_o   = ha + 1024;                     //        512
    float* rsig_o   = mean_o + 512;                  //        512
    float* mean_kv  = rsig_o + 512;                  //        608
    float* rsig_kv  = mean_kv + 608;                 //        608
    float* hk       = rsig_kv + 608;                 //        192
    float* hv       = hk + 192;                      //      1,024
    int*   counts   = (int*)(hv + 1024);             //      1,024 ints
    int*   base     = counts + 1024;                 //      1,025 ints
    int*   cursor   = base + 1025;                   //      1,024 ints
    // aliased into zc region (dead before conv3d writes zcb16):
    float* vbuf = zc;                                //  4,194,304 (16MB)
    float* kv   = zc + 4194304;                      //  4,980,736 (19MB)
    unsigned short* zcb16 = (unsigned short*)zc;     // conv output bf16 (32MB)
    unsigned short* xbf  = (unsigned short*)xbf_f;
    unsigned short* wb16 = (unsigned short*)wt;
    unsigned short* wkb  = (unsigned short*)wkb_f;
    unsigned short* recs = (unsigned short*)recs_f;

    setup_misc<<<285, 256, 0, stream>>>(style, kw_w, kw_b, vw_w, vw_b, aw_w, aw_b,
                                        conv_w, Wkv, hk, hv, ha, wb16, wkb, counts);
    zero_halo<<<(32 * HALO_ + 255) / 256, 256, 0, stream>>>(zb16p);
    xconvert<<<8192, 256, 0, stream>>>(input, xbf);
    kv_gemm_mfma<<<dim3(16, 10, B_), 256, 0, stream>>>(xbf, wkb, kv);
    stats_kernel<<<B_ * CO_, 256, 0, stream>>>(kv, mean_kv, rsig_kv);
    point_prep<<<B_ * H_ * N_ / 256, 256, 0, stream>>>(
        kv, mean_kv, rsig_kv, hk, hv, orig, scale_p, Tw, Tb,
        (float4*)coordbuf, vbuf, counts);
    prefix_bins<<<1, 64, 0, stream>>>(counts, base, cursor);
    scatter_pts<<<B_ * H_ * N_ / 256, 256, 0, stream>>>((const float4*)coordbuf, cursor, recs);
    splat3<<<1024, 1024, 0, stream>>>((const float4*)coordbuf, vbuf, base, recs, zb16p);
    conv3d_mfma<<<1024, 256, 0, stream>>>(zb16p, wb16, conv_b, zcb16);
    slice_vm<<<B_ * H_ * N_ / 256, 256, 0, stream>>>(zcb16, (const float4*)coordbuf, out);
    stats_kernel<<<B_ * HF_, 256, 0, stream>>>(out, mean_o, rsig_o);
    final_adain<<<B_ * HF_ * N_ / 256, 256, 0, stream>>>(out, mean_o, rsig_o, ha);
}

// Round 14
// 185.711 us; speedup vs baseline: 3.7448x; 1.1139x over previous
//
#include <hip/hip_runtime.h>
#include <hip/hip_bf16.h>
#include <math.h>

#define B_ 4
#define N_ 8192
#define MD_ 512
#define H_ 8
#define F_ 16
#define S_ 32
#define S3_ 32768
#define L_ 256
#define CO_ 152   // H*(F+3)
#define HF_ 128   // H*F
#define EPS_ 1e-5f
#define CHUNK_ 512
#define PS_ 34            // padded lattice dim
#define PS2_ 1156         // 34*34
#define PV_ 39304         // 34^3 voxels per (b,h)
#define HALO_ 6536        // 34^3 - 32^3

typedef __attribute__((ext_vector_type(8))) short bf16x8;
typedef __attribute__((ext_vector_type(4))) float f32x4;

__device__ inline unsigned short f2bf(float f) {   // RNE fp32 -> bf16
    unsigned u = __float_as_uint(f);
    return (unsigned short)((u + 0x7FFFu + ((u >> 16) & 1u)) >> 16);
}

// ---------------- fused setup: zero_bins + style_proj + conv-w + wconvert ---
__global__ __launch_bounds__(256) void setup_misc(
    const float* __restrict__ style,
    const float* __restrict__ kw_w, const float* __restrict__ kw_b,
    const float* __restrict__ vw_w, const float* __restrict__ vw_b,
    const float* __restrict__ aw_w, const float* __restrict__ aw_b,
    const float* __restrict__ cw, const float* __restrict__ Wkv,
    float* __restrict__ hk, float* __restrict__ hv, float* __restrict__ ha,
    unsigned short* __restrict__ wb, unsigned short* __restrict__ wkb,
    int* __restrict__ counts) {
    int blk = blockIdx.x;
    int tid = threadIdx.x;
    if (blk == 0) {                       // zero the 1024 bin counters
        #pragma unroll
        for (int q = 0; q < 4; ++q) counts[q * 256 + tid] = 0;
    } else if (blk < 5) {                 // style projections (4 blocks)
        int b = blk - 1;
        const float* st = style + b * L_;
        for (int r = tid; r < 48 + 256 + 256; r += 256) {
            const float* wrow; float bias; float* dst; int j;
            if (r < 48)       { j = r;       wrow = kw_w + j * L_; bias = kw_b[j]; dst = hk + b * 48; }
            else if (r < 304) { j = r - 48;  wrow = vw_w + j * L_; bias = vw_b[j]; dst = hv + b * 256; }
            else              { j = r - 304; wrow = aw_w + j * L_; bias = aw_b[j]; dst = ha + b * 256; }
            float acc = bias;
            for (int l = 0; l < L_; ++l) acc = fmaf(st[l], wrow[l], acc);
            dst[j] = acc;
        }
    } else if (blk < 245) {               // conv weights, 61440 total
        int i = (blk - 5) * 256 + tid;
        if (i < 61440) {
            int ic = i & 15;
            int oc = (i >> 4) & 15;
            int s  = (i >> 8) % 30;
            int h  = (i >> 8) / 30;
            int p = s >> 1, tsel = s & 1;
            int pair = p % 5, dy = p / 5;
            int c = (pair < 4) ? (pair * 2 + tsel) : 8;
            bool zero = (pair == 4) && (tsel == 1);
            int tap = (c / 3) * 9 + dy * 3 + (c % 3);
            float v = zero ? 0.f : cw[(((h * 16 + oc) * 16 + ic) * 27) + tap];
            wb[i] = f2bf(v);
        }
    } else {                              // W_kv -> bf16 frags [mt][kc][r16][k8]
        int i = (blk - 245) * 256 + tid;  // 10240 total
        if (i < 10240) {
            int r  = i & 15;
            int kc = (i >> 4) & 63;
            int mt = i >> 10;
            int row = mt * 16 + r;
            unsigned int pk[4];
            #pragma unroll
            for (int j = 0; j < 4; ++j) {
                float v0 = (row < CO_) ? Wkv[(size_t)row * MD_ + kc * 8 + 2 * j] : 0.f;
                float v1 = (row < CO_) ? Wkv[(size_t)row * MD_ + kc * 8 + 2 * j + 1] : 0.f;
                pk[j] = (unsigned)f2bf(v0) | ((unsigned)f2bf(v1) << 16);
            }
            *(uint4*)(wkb + (((size_t)(mt * 64 + kc)) * 16 + r) * 8) =
                make_uint4(pk[0], pk[1], pk[2], pk[3]);
        }
    }
}

// zero only the halo shell of each padded lattice (interior fully written by splat3)
__global__ __launch_bounds__(256) void zero_halo(unsigned short* __restrict__ zb16p) {
    int i = blockIdx.x * 256 + threadIdx.x;     // 32 * 6536 total
    if (i >= 32 * HALO_) return;
    int bh = i / HALO_;
    int j  = i - bh * HALO_;
    int x, y, z;
    if (j < 2312) {                 // x = 0 or 33 full planes
        x = (j / 1156) * 33;
        int rem = j % 1156;
        y = rem / 34; z = rem % 34;
    } else {
        int k = j - 2312;
        x = 1 + k / 132;
        int m = k % 132;
        if (m < 34)       { y = 0;  z = m; }
        else if (m < 68)  { y = 33; z = m - 34; }
        else if (m < 100) { y = m - 68 + 1;  z = 0; }
        else              { y = m - 100 + 1; z = 33; }
    }
    int pv = (x * PS_ + y) * PS_ + z;
    unsigned short* p = zb16p + ((size_t)bh * PV_ + pv) * 16;
    ((uint4*)p)[0] = make_uint4(0, 0, 0, 0);
    ((uint4*)p)[1] = make_uint4(0, 0, 0, 0);
}

// ---------------- input -> bf16 fragment layout [b][nt(512)][kc(64)][n16][k8]
__global__ __launch_bounds__(256) void xconvert(
    const float* __restrict__ X, unsigned short* __restrict__ xb) {
    int i = blockIdx.x * 256 + threadIdx.x;   // 4*64*8192 = 2,097,152
    int n  = i & (N_ - 1);
    int kc = (i >> 13) & 63;
    int b  = i >> 19;
    const float* xp = X + ((size_t)b * MD_ + kc * 8) * N_ + n;
    unsigned int pk[4];
    #pragma unroll
    for (int j = 0; j < 4; ++j) {
        float v0 = xp[(size_t)(2 * j) * N_];
        float v1 = xp[(size_t)(2 * j + 1) * N_];
        pk[j] = (unsigned)f2bf(v0) | ((unsigned)f2bf(v1) << 16);
    }
    int nt = n >> 4, n16 = n & 15;
    *(uint4*)(xb + ((((size_t)(b * 512 + nt)) * 64 + kc) * 16 + n16) * 8) =
        make_uint4(pk[0], pk[1], pk[2], pk[3]);
}

// ---------------- kv = W_kv @ input via bf16 MFMA (no LDS, no barriers) -----
__global__ __launch_bounds__(256) void kv_gemm_mfma(
    const unsigned short* __restrict__ xb, const unsigned short* __restrict__ wkb,
    float* __restrict__ kv) {
    int b  = blockIdx.z;
    int mt = blockIdx.y;
    int lane = threadIdx.x & 63, wv = threadIdx.x >> 6;
    int rc = lane & 15, kg = lane >> 4;
    int n0 = blockIdx.x * 512 + wv * 128;
    int nt0 = n0 >> 4;
    const unsigned short* ap = wkb + (((size_t)(mt * 64 + kg)) * 16 + rc) * 8;
    const unsigned short* bp = xb + ((((size_t)(b * 512 + nt0)) * 64 + kg) * 16 + rc) * 8;
    f32x4 acc[8];
    #pragma unroll
    for (int j = 0; j < 8; ++j) acc[j] = (f32x4){0.f, 0.f, 0.f, 0.f};
    #pragma unroll 1
    for (int ks = 0; ks < 16; ++ks) {
        bf16x8 a = *(const bf16x8*)(ap + ks * 512);
        #pragma unroll
        for (int j = 0; j < 8; ++j) {
            bf16x8 bfr = *(const bf16x8*)(bp + (size_t)j * 8192 + ks * 512);
            acc[j] = __builtin_amdgcn_mfma_f32_16x16x32_bf16(a, bfr, acc[j], 0, 0, 0);
        }
    }
    #pragma unroll
    for (int j = 0; j < 8; ++j) {
        int col = n0 + j * 16 + rc;
        #pragma unroll
        for (int r = 0; r < 4; ++r) {
            int m = mt * 16 + kg * 4 + r;
            if (m < CO_) kv[((size_t)b * CO_ + m) * N_ + col] = acc[j][r];
        }
    }
}

// ---------------- per-(b,channel) mean / rsig over N ------------------------
__global__ __launch_bounds__(256) void stats_kernel(
    const float* __restrict__ x, float* __restrict__ mean, float* __restrict__ rsig) {
    int bc = blockIdx.x;
    const float* p = x + (size_t)bc * N_;
    float s = 0.f, s2 = 0.f;
    for (int i = threadIdx.x; i < N_; i += 256) {
        float v = p[i]; s += v; s2 = fmaf(v, v, s2);
    }
    #pragma unroll
    for (int off = 32; off; off >>= 1) { s += __shfl_down(s, off); s2 += __shfl_down(s2, off); }
    __shared__ float ls[4], ls2[4];
    int wid = threadIdx.x >> 6;
    if ((threadIdx.x & 63) == 0) { ls[wid] = s; ls2[wid] = s2; }
    __syncthreads();
    if (threadIdx.x == 0) {
        float S = ls[0] + ls[1] + ls[2] + ls[3];
        float S2 = ls2[0] + ls2[1] + ls2[2] + ls2[3];
        float mu = S * (1.f / N_);
        float var = S2 * (1.f / N_) - mu * mu;
        mean[bc] = mu;
        rsig[bc] = rsqrtf(var + EPS_);
    }
}

// ---------------- point prep: AdaIN + transform + tanh + interp + count -----
// vbuf now bf16-packed: 8 u32 per point (32B)
__global__ __launch_bounds__(256) void point_prep(
    const float* __restrict__ kv, const float* __restrict__ mean_kv,
    const float* __restrict__ rsig_kv, const float* __restrict__ hk,
    const float* __restrict__ hv, const float* __restrict__ orig,
    const float* __restrict__ scale_p, const float* __restrict__ Tw,
    const float* __restrict__ Tb,
    float4* __restrict__ coordbuf, unsigned* __restrict__ vbuf16,
    int* __restrict__ counts) {
    __shared__ int s_hist[32];
    int tid = threadIdx.x;
    if (tid < 32) s_hist[tid] = 0;
    __syncthreads();
    int p = blockIdx.x * 256 + tid;
    int n = p & (N_ - 1);
    int bh = p >> 13;               // uniform per block
    int h = bh & 7, b = bh >> 3;
    float scl = scale_p[0];

    float pt[3];
    #pragma unroll
    for (int j = 0; j < 3; ++j) {
        int c = h * 3 + j;
        float x  = kv[((size_t)(b * CO_ + c)) * N_ + n];
        float xn = (x - mean_kv[b * CO_ + c]) * rsig_kv[b * CO_ + c];
        float kr = fmaf(1.f + hk[b * 48 + c], xn, hk[b * 48 + 24 + c]);
        pt[j] = fmaf(scl, kr, orig[((size_t)(b * 3 + j)) * N_ + n]);
    }
    int f0[3]; float tt[3];
    #pragma unroll
    for (int i = 0; i < 3; ++i) {
        float key = Tb[h * 3 + i];
        #pragma unroll
        for (int j = 0; j < 3; ++j) key = fmaf(Tw[(h * 3 + i) * 3 + j], pt[j], key);
        float lat = tanhf(key);
        float g = (lat + 1.f) * 0.5f * (float)(S_ - 1);
        float ff = floorf(g);
        ff = fminf(fmaxf(ff, 0.f), 30.f);
        f0[i] = (int)ff;
        tt[i] = fminf(fmaxf(g - ff, 0.f), 1.f);
    }
    coordbuf[p] = make_float4(tt[0], tt[1], tt[2],
                              __int_as_float(f0[0] | (f0[1] << 5) | (f0[2] << 10)));
    atomicAdd(&s_hist[f0[0]], 1);   // LDS
    float vf[16];
    #pragma unroll
    for (int f = 0; f < F_; ++f) {
        int c = 24 + h * F_ + f;
        float x  = kv[((size_t)(b * CO_ + c)) * N_ + n];
        float xn = (x - mean_kv[b * CO_ + c]) * rsig_kv[b * CO_ + c];
        int cv = h * F_ + f;
        vf[f] = fmaf(1.f + hv[b * 256 + cv], xn, hv[b * 256 + 128 + cv]);
    }
    unsigned pk2[8];
    #pragma unroll
    for (int q = 0; q < 8; ++q)
        pk2[q] = (unsigned)f2bf(vf[2 * q]) | ((unsigned)f2bf(vf[2 * q + 1]) << 16);
    uint4* vb = (uint4*)(vbuf16 + (size_t)p * 8);
    vb[0] = make_uint4(pk2[0], pk2[1], pk2[2], pk2[3]);
    vb[1] = make_uint4(pk2[4], pk2[5], pk2[6], pk2[7]);
    __syncthreads();
    if (tid < 32 && s_hist[tid] > 0)
        atomicAdd(&counts[(bh << 5) + tid], s_hist[tid]);
}

// ---------------- exclusive prefix over the 1024 bins (one wave) ------------
__global__ __launch_bounds__(64) void prefix_bins(
    const int* __restrict__ counts, int* __restrict__ base, int* __restrict__ cursor) {
    int lane = threadIdx.x;
    int local[16], sum = 0;
    #pragma unroll
    for (int i = 0; i < 16; ++i) { local[i] = sum; sum += counts[lane * 16 + i]; }
    int incl = sum;
    #pragma unroll
    for (int off = 1; off < 64; off <<= 1) {
        int v = __shfl_up(incl, off);
        if (lane >= off) incl += v;
    }
    int excl = incl - sum;
    #pragma unroll
    for (int i = 0; i < 16; ++i) {
        int bse = excl + local[i];
        base[lane * 16 + i] = bse;
        cursor[lane * 16 + i] = bse;
    }
    if (lane == 63) base[1024] = excl + sum;
}

// ---------------- scatter point indices into bins (LDS-aggregated) ----------
__global__ __launch_bounds__(256) void scatter_pts(
    const float4* __restrict__ coordbuf, int* __restrict__ cursor,
    unsigned short* __restrict__ recs) {
    __shared__ int s_hist[32];
    __shared__ int s_base[32];
    int tid = threadIdx.x;
    if (tid < 32) s_hist[tid] = 0;
    __syncthreads();
    int p = blockIdx.x * 256 + tid;
    int bh = p >> 13;               // uniform per block
    int pk = __float_as_int(((const float*)coordbuf)[(size_t)p * 4 + 3]);
    int f0x = pk & 31;
    int rank = atomicAdd(&s_hist[f0x], 1);   // LDS
    __syncthreads();
    if (tid < 32 && s_hist[tid] > 0)
        s_base[tid] = atomicAdd(&cursor[(bh << 5) + tid], s_hist[tid]);
    __syncthreads();
    recs[s_base[f0x] + rank] = (unsigned short)(p & (N_ - 1));
}

// ---------------- splat3 v2: sort + LDS-staged records + LDS-only gather ----
// block -> one x-plane of one (b,h); 1024 threads; thread = voxel (y,z).
// Per chunk (<=512 candidates): count -> prefix -> stage 48B sorted records
// {16 bf16 vals, wx, cy, cz} in LDS -> gather reads LDS only.
__global__ __launch_bounds__(1024) void splat3(
    const float4* __restrict__ coordbuf, const unsigned* __restrict__ vbuf16,
    const int* __restrict__ base, const unsigned short* __restrict__ recs,
    unsigned short* __restrict__ zb16p) {
    __shared__ int s_cnt[1024];
    __shared__ int s_start[1024];
    __shared__ int s_cur[1024];
    __shared__ unsigned s_rec[CHUNK_ * 12];   // 24KB sorted records
    __shared__ int s_wavesum[16];
    int logical = (blockIdx.x & 7) * 128 + (blockIdx.x >> 3);  // XCD swizzle
    int bh = logical >> 5;
    int x0 = logical & 31;
    int tid = threadIdx.x;
    int y = tid >> 5, zc = tid & 31;
    int bin0 = (bh << 5) + x0;
    int s0 = base[bin0], len0 = base[bin0 + 1] - s0;
    int s1 = 0, len1 = 0;
    if (x0 > 0) { s1 = base[bin0 - 1]; len1 = s0 - s1; }
    int total = len0 + len1;
    const float4* cb = coordbuf + (size_t)bh * N_;
    const unsigned* vb = vbuf16 + ((size_t)bh * N_) * 8;
    float acc[16];
    #pragma unroll
    for (int i = 0; i < 16; ++i) acc[i] = 0.f;

    for (int c0 = 0; c0 < total; c0 += CHUNK_) {
        int cl = min(CHUNK_, total - c0);
        s_cnt[tid] = 0;
        __syncthreads();
        // ---- pass 1: read rec + coord, count into (y,z) bins
        int n = 0, cx = 0, sb = 0;
        float4 c;
        bool active = (tid < cl);
        if (active) {
            int tp = c0 + tid;
            if (tp < len0) { n = recs[s0 + tp]; cx = 0; }
            else           { n = recs[s1 + (tp - len0)]; cx = 1; }
            c = cb[n];
            int pk = __float_as_int(c.w);
            sb = (((pk >> 5) & 31) << 5) | ((pk >> 10) & 31);
            atomicAdd(&s_cnt[sb], 1);
        }
        __syncthreads();
        // ---- block-wide exclusive prefix over 1024 bins
        int v = s_cnt[tid];
        int incl = v;
        #pragma unroll
        for (int off = 1; off < 64; off <<= 1) {
            int u = __shfl_up(incl, off);
            if ((tid & 63) >= off) incl += u;
        }
        int wid = tid >> 6;
        if ((tid & 63) == 63) s_wavesum[wid] = incl;
        __syncthreads();
        if (tid < 16) {
            int wv = s_wavesum[tid];
            int wincl = wv;
            #pragma unroll
            for (int off = 1; off < 16; off <<= 1) {
                int u = __shfl_up(wincl, off);
                if (tid >= off) wincl += u;
            }
            s_wavesum[tid] = wincl - wv;
        }
        __syncthreads();
        int excl = incl - v + s_wavesum[wid];
        s_start[tid] = excl;
        s_cur[tid] = excl;
        __syncthreads();
        // ---- pass 2: claim slot, stage 48B record in sorted order
        if (active) {
            int slot = atomicAdd(&s_cur[sb], 1);
            const uint4* vp = (const uint4*)(vb + (size_t)n * 8);
            uint4 v0 = vp[0], v1 = vp[1];
            unsigned* r = s_rec + slot * 12;
            *(uint4*)(r)     = v0;
            *(uint4*)(r + 4) = v1;
            float wx = cx ? c.x : 1.f - c.x;
            *(uint4*)(r + 8) = make_uint4(__float_as_uint(wx), __float_as_uint(c.y),
                                          __float_as_uint(c.z), 0u);
        }
        __syncthreads();
        // ---- gather from 4 neighbor sub-bins, LDS only
        #pragma unroll
        for (int sy = 0; sy < 2; ++sy) {
            int yy = y - sy;
            if (yy < 0) continue;
            #pragma unroll
            for (int sz = 0; sz < 2; ++sz) {
                int zz = zc - sz;
                if (zz < 0) continue;
                int sbq = (yy << 5) | zz;
                int s = s_start[sbq], e = s + s_cnt[sbq];
                for (int i = s; i < e; ++i) {
                    const unsigned* r = s_rec + i * 12;
                    uint4 cw_ = *(const uint4*)(r + 8);
                    float wx = __uint_as_float(cw_.x);
                    float cy = __uint_as_float(cw_.y);
                    float cz = __uint_as_float(cw_.z);
                    float w = wx * (sy ? cy : 1.f - cy) * (sz ? cz : 1.f - cz);
                    uint4 u0 = *(const uint4*)(r);
                    uint4 u1 = *(const uint4*)(r + 4);
                    unsigned uu[8] = {u0.x, u0.y, u0.z, u0.w, u1.x, u1.y, u1.z, u1.w};
                    #pragma unroll
                    for (int q = 0; q < 8; ++q) {
                        float lo = __uint_as_float(uu[q] << 16);
                        float hi = __uint_as_float(uu[q] & 0xFFFF0000u);
                        acc[2 * q]     = fmaf(w, lo, acc[2 * q]);
                        acc[2 * q + 1] = fmaf(w, hi, acc[2 * q + 1]);
                    }
                }
            }
        }
        __syncthreads();
    }
    unsigned int pk[8];
    #pragma unroll
    for (int q = 0; q < 8; ++q)
        pk[q] = (unsigned)f2bf(acc[2 * q]) | ((unsigned)f2bf(acc[2 * q + 1]) << 16);
    int pv = ((x0 + 1) * PS_ + y + 1) * PS_ + zc + 1;
    unsigned short* zb = zb16p + ((size_t)bh * PV_ + pv) * 16;
    ((uint4*)zb)[0] = make_uint4(pk[0], pk[1], pk[2], pk[3]);
    ((uint4*)zb)[1] = make_uint4(pk[4], pk[5], pk[6], pk[7]);
}

// ---------------- grouped 3x3x3 conv via bf16 MFMA, sliding y-window --------
__global__ __launch_bounds__(256) void conv3d_mfma(
    const unsigned short* __restrict__ zp, const unsigned short* __restrict__ wb,
    const float* __restrict__ cbias, unsigned short* __restrict__ zcb16) {
    int logical = (blockIdx.x & 7) * 128 + (blockIdx.x >> 3);  // 1024 = 8*128
    int bh = logical >> 5;
    int x  = logical & 31;
    int h = bh & 7;
    int lane = threadIdx.x & 63;
    int wv = threadIdx.x >> 6;
    int rc = lane & 15;
    int kb = lane >> 4;
    int ic0 = (kb & 1) << 3;
    int tsel = kb >> 1;
    int z0 = (wv & 1) << 4;
    int y0 = (wv >> 1) << 4;

    int aoff[5];
    #pragma unroll
    for (int pr = 0; pr < 5; ++pr) {
        int c = (pr < 4) ? (pr * 2 + tsel) : 8;
        int dx = c / 3, dz = c % 3;
        aoff[pr] = ((dx - 1) * PS2_ + (dz - 1)) * 32 + ic0 * 2;
    }
    bf16x8 bfr[15];
    const unsigned short* wh = wb + h * 30 * 256;
    #pragma unroll
    for (int p = 0; p < 15; ++p)
        bfr[p] = *(const bf16x8*)(wh + (((p * 2 + tsel) * 16 + rc) << 4) + ic0);
    float bias = cbias[h * 16 + rc];
    const char* zb = (const char*)(zp + (size_t)bh * PV_ * 16);
    unsigned short* zcb = zcb16 + ((size_t)bh << 19);
    int colbase = (x + 1) * PS2_ + z0 + rc + 1;

    bf16x8 w0[5], w1[5], w2[5];
    #pragma unroll
    for (int pr = 0; pr < 5; ++pr) {
        w0[pr] = *(const bf16x8*)(zb + (size_t)(colbase + (y0)     * PS_) * 32 + aoff[pr]);
        w1[pr] = *(const bf16x8*)(zb + (size_t)(colbase + (y0 + 1) * PS_) * 32 + aoff[pr]);
        w2[pr] = *(const bf16x8*)(zb + (size_t)(colbase + (y0 + 2) * PS_) * 32 + aoff[pr]);
    }
    #pragma unroll 1
    for (int y = y0; y < y0 + 16; ++y) {
        f32x4 a0 = {0.f, 0.f, 0.f, 0.f};
        f32x4 a1 = {0.f, 0.f, 0.f, 0.f};
        f32x4 a2 = {0.f, 0.f, 0.f, 0.f};
        #pragma unroll
        for (int pr = 0; pr < 5; ++pr) {
            a0 = __builtin_amdgcn_mfma_f32_16x16x32_bf16(w0[pr], bfr[pr],      a0, 0, 0, 0);
            a1 = __builtin_amdgcn_mfma_f32_16x16x32_bf16(w1[pr], bfr[5 + pr],  a1, 0, 0, 0);
            a2 = __builtin_amdgcn_mfma_f32_16x16x32_bf16(w2[pr], bfr[10 + pr], a2, 0, 0, 0);
        }
        int vout = (((x << 5) + y) << 5) + z0 + (kb << 2);
        #pragma unroll
        for (int r = 0; r < 4; ++r)
            zcb[(size_t)(vout + r) * 16 + rc] = f2bf(a0[r] + a1[r] + a2[r] + bias);
        #pragma unroll
        for (int pr = 0; pr < 5; ++pr) { w0[pr] = w1[pr]; w1[pr] = w2[pr]; }
        if (y < y0 + 15) {
            #pragma unroll
            for (int pr = 0; pr < 5; ++pr)
                w2[pr] = *(const bf16x8*)(zb + (size_t)(colbase + (y + 3) * PS_) * 32 + aoff[pr]);
        }
    }
}

// ---------------- slice: weighted gather (bf16 zc, XCD-swizzled) ------------
__global__ __launch_bounds__(256) void slice_vm(
    const unsigned short* __restrict__ zcb16, const float4* __restrict__ coordbuf,
    float* __restrict__ out) {
    int logical = (blockIdx.x & 7) * 128 + (blockIdx.x >> 3);  // 1024 = 8*128
    int p = logical * 256 + threadIdx.x;
    int n = p & (N_ - 1);
    int bh = p >> 13;
    int h = bh & 7, b = bh >> 3;
    float4 c = coordbuf[p];
    int pk = __float_as_int(c.w);
    int f0x = pk & 31, f0y = (pk >> 5) & 31, f0z = (pk >> 10) & 31;
    const unsigned short* gb = zcb16 + ((size_t)bh << 19);
    float acc[16];
    #pragma unroll
    for (int f = 0; f < 16; ++f) acc[f] = 0.f;
    #pragma unroll 1
    for (int k = 0; k < 8; ++k) {
        int cx = (k >> 2) & 1, cy = (k >> 1) & 1, cz = k & 1;
        float w = (cx ? c.x : 1.f - c.x) * (cy ? c.y : 1.f - c.y) * (cz ? c.z : 1.f - c.z);
        int vox = (((f0x + cx) << 5) + f0y + cy) * 32 + f0z + cz;
        const uint4* ip = (const uint4*)(gb + ((size_t)vox << 4));
        uint4 u0 = ip[0], u1 = ip[1];
        unsigned uu[8] = {u0.x, u0.y, u0.z, u0.w, u1.x, u1.y, u1.z, u1.w};
        #pragma unroll
        for (int q = 0; q < 8; ++q) {
            float lo = __uint_as_float(uu[q] << 16);
            float hi = __uint_as_float(uu[q] & 0xFFFF0000u);
            acc[2 * q]     = fmaf(w, lo, acc[2 * q]);
            acc[2 * q + 1] = fmaf(w, hi, acc[2 * q + 1]);
        }
    }
    #pragma unroll
    for (int f = 0; f < 16; ++f)
        out[(((size_t)(b * HF_ + h * F_ + f)) << 13) + n] = acc[f];
}

// ---------------- final AdaIN + ReLU (in place on d_out) --------------------
__global__ __launch_bounds__(256) void final_adain(
    float* __restrict__ out, const float* __restrict__ mean_o,
    const float* __restrict__ rsig_o, const float* __restrict__ ha) {
    size_t i = (size_t)blockIdx.x * 256 + threadIdx.x;
    int bc = (int)(i >> 13);
    int c = bc & 127, b = bc >> 7;
    float x = out[i];
    float xn = (x - mean_o[bc]) * rsig_o[bc];
    float y = fmaf(1.f + ha[b * 256 + c], xn, ha[b * 256 + 128 + c]);
    out[i] = fmaxf(y, 0.f);
}

extern "C" void kernel_launch(void* const* d_in, const int* in_sizes, int n_in,
                              void* d_out, int out_size, void* d_ws, size_t ws_size,
                              hipStream_t stream) {
    (void)in_sizes; (void)n_in; (void)out_size; (void)ws_size;
    const float* input   = (const float*)d_in[0];
    const float* style   = (const float*)d_in[1];
    const float* orig    = (const float*)d_in[2];
    const float* Wkv     = (const float*)d_in[3];
    const float* kw_w    = (const float*)d_in[4];
    const float* kw_b    = (const float*)d_in[5];
    const float* vw_w    = (const float*)d_in[6];
    const float* vw_b    = (const float*)d_in[7];
    const float* aw_w    = (const float*)d_in[8];
    const float* aw_b    = (const float*)d_in[9];
    const float* scale_p = (const float*)d_in[10];
    const float* Tw      = (const float*)d_in[11];
    const float* Tb      = (const float*)d_in[12];
    const float* conv_w  = (const float*)d_in[13];
    const float* conv_b  = (const float*)d_in[14];
    float* out = (float*)d_out;

    // -------- workspace layout (floats), ~146.0 MB total --------------------
    float* ws = (float*)d_ws;
    unsigned short* zb16p = (unsigned short*)ws;     // padded lattice bf16 (40.2MB)
    float* zc       = ws + 10061824;                 // 64MB region; conv uses first 32MB as bf16
    float* xbf_f    = ws + 26839040;                 //  8,388,608 (32MB) bf16 input frags
    float* coordbuf = ws + 35227648;                 //  1,048,576
    float* wt       = ws + 36276224;                 //     55,296 floats (conv bf16 weights, 120KB used)
    float* wkb_f    = ws + 36331520;                 //     40,960 (W_kv bf16 frags, 160KB)
    float* recs_f   = ws + 36372480;                 //    131,072 (262,144 u16)
    float* ha       = ws + 36503552;                 //      1,024
    float* mean_o   = ha + 1024;                     //        512
    float* rsig_o   = mean_o + 512;                  //        512
    float* mean_kv  = rsig_o + 512;                  //        608
    float* rsig_kv  = mean_kv + 608;                 //        608
    float* hk       = rsig_kv + 608;                 //        192
    float* hv       = hk + 192;                      //      1,024
    int*   counts   = (int*)(hv + 1024);             //      1,024 ints
    int*   base     = counts + 1024;                 //      1,025 ints
    int*   cursor   = base + 1025;                   //      1,024 ints
    // aliased into zc region (dead before conv3d writes zcb16):
    unsigned* vbuf16 = (unsigned*)zc;                //  2,097,152 u32 (8MB) bf16 values
    float* kv   = zc + 2097152;                      //  4,980,736 (19MB)
    unsigned short* zcb16 = (unsigned short*)zc;     // conv output bf16 (32MB)
    unsigned short* xbf  = (unsigned short*)xbf_f;
    unsigned short* wb16 = (unsigned short*)wt;
    unsigned short* wkb  = (unsigned short*)wkb_f;
    unsigned short* recs = (unsigned short*)recs_f;

    setup_misc<<<285, 256, 0, stream>>>(style, kw_w, kw_b, vw_w, vw_b, aw_w, aw_b,
                                        conv_w, Wkv, hk, hv, ha, wb16, wkb, counts);
    zero_halo<<<(32 * HALO_ + 255) / 256, 256, 0, stream>>>(zb16p);
    xconvert<<<8192, 256, 0, stream>>>(input, xbf);
    kv_gemm_mfma<<<dim3(16, 10, B_), 256, 0, stream>>>(xbf, wkb, kv);
    stats_kernel<<<B_ * CO_, 256, 0, stream>>>(kv, mean_kv, rsig_kv);
    point_prep<<<B_ * H_ * N_ / 256, 256, 0, stream>>>(
        kv, mean_kv, rsig_kv, hk, hv, orig, scale_p, Tw, Tb,
        (float4*)coordbuf, vbuf16, counts);
    prefix_bins<<<1, 64, 0, stream>>>(counts, base, cursor);
    scatter_pts<<<B_ * H_ * N_ / 256, 256, 0, stream>>>((const float4*)coordbuf, cursor, recs);
    splat3<<<1024, 1024, 0, stream>>>((const float4*)coordbuf, vbuf16, base, recs, zb16p);
    conv3d_mfma<<<1024, 256, 0, stream>>>(zb16p, wb16, conv_b, zcb16);
    slice_vm<<<B_ * H_ * N_ / 256, 256, 0, stream>>>(zcb16, (const float4*)coordbuf, out);
    stats_kernel<<<B_ * HF_, 256, 0, stream>>>(out, mean_o, rsig_o);
    final_adain<<<B_ * HF_ * N_ / 256, 256, 0, stream>>>(out, mean_o, rsig_o, ha);
}

// Round 15
// 180.635 us; speedup vs baseline: 3.8500x; 1.0281x over previous
//
#include <hip/hip_runtime.h>
#include <hip/hip_bf16.h>
#include <math.h>

#define B_ 4
#define N_ 8192
#define MD_ 512
#define H_ 8
#define F_ 16
#define S_ 32
#define S3_ 32768
#define L_ 256
#define CO_ 152   // H*(F+3)
#define HF_ 128   // H*F
#define EPS_ 1e-5f
#define CHUNK_ 512
#define PS_ 34            // padded lattice dim
#define PS2_ 1156         // 34*34
#define PV_ 39304         // 34^3 voxels per (b,h)
#define HALO_ 6536        // 34^3 - 32^3
#define INVN_ (1.f / 8192.f)

typedef __attribute__((ext_vector_type(8))) short bf16x8;
typedef __attribute__((ext_vector_type(4))) float f32x4;

__device__ inline unsigned short f2bf(float f) {   // RNE fp32 -> bf16
    unsigned u = __float_as_uint(f);
    return (unsigned short)((u + 0x7FFFu + ((u >> 16) & 1u)) >> 16);
}

// ---------------- fused setup: zeros + style_proj + conv-w + wconvert + halo
__global__ __launch_bounds__(256) void setup_misc(
    const float* __restrict__ style,
    const float* __restrict__ kw_w, const float* __restrict__ kw_b,
    const float* __restrict__ vw_w, const float* __restrict__ vw_b,
    const float* __restrict__ aw_w, const float* __restrict__ aw_b,
    const float* __restrict__ cw, const float* __restrict__ Wkv,
    float* __restrict__ hk, float* __restrict__ hv, float* __restrict__ ha,
    unsigned short* __restrict__ wb, unsigned short* __restrict__ wkb,
    int* __restrict__ counts, float* __restrict__ sums,
    unsigned short* __restrict__ zb16p) {
    int blk = blockIdx.x;
    int tid = threadIdx.x;
    if (blk == 0) {                       // zero bin counters + stat accumulators
        #pragma unroll
        for (int q = 0; q < 4; ++q) counts[q * 256 + tid] = 0;
        for (int i = tid; i < 2240; i += 256) sums[i] = 0.f;
    } else if (blk < 5) {                 // style projections (4 blocks)
        int b = blk - 1;
        const float* st = style + b * L_;
        for (int r = tid; r < 48 + 256 + 256; r += 256) {
            const float* wrow; float bias; float* dst; int j;
            if (r < 48)       { j = r;       wrow = kw_w + j * L_; bias = kw_b[j]; dst = hk + b * 48; }
            else if (r < 304) { j = r - 48;  wrow = vw_w + j * L_; bias = vw_b[j]; dst = hv + b * 256; }
            else              { j = r - 304; wrow = aw_w + j * L_; bias = aw_b[j]; dst = ha + b * 256; }
            float acc = bias;
            for (int l = 0; l < L_; ++l) acc = fmaf(st[l], wrow[l], acc);
            dst[j] = acc;
        }
    } else if (blk < 245) {               // conv weights, 61440 total
        int i = (blk - 5) * 256 + tid;
        if (i < 61440) {
            int ic = i & 15;
            int oc = (i >> 4) & 15;
            int s  = (i >> 8) % 30;
            int h  = (i >> 8) / 30;
            int p = s >> 1, tsel = s & 1;
            int pair = p % 5, dy = p / 5;
            int c = (pair < 4) ? (pair * 2 + tsel) : 8;
            bool zero = (pair == 4) && (tsel == 1);
            int tap = (c / 3) * 9 + dy * 3 + (c % 3);
            float v = zero ? 0.f : cw[(((h * 16 + oc) * 16 + ic) * 27) + tap];
            wb[i] = f2bf(v);
        }
    } else if (blk < 285) {               // W_kv -> bf16 frags [mt][kc][r16][k8]
        int i = (blk - 245) * 256 + tid;  // 10240 total
        if (i < 10240) {
            int r  = i & 15;
            int kc = (i >> 4) & 63;
            int mt = i >> 10;
            int row = mt * 16 + r;
            unsigned int pk[4];
            #pragma unroll
            for (int j = 0; j < 4; ++j) {
                float v0 = (row < CO_) ? Wkv[(size_t)row * MD_ + kc * 8 + 2 * j] : 0.f;
                float v1 = (row < CO_) ? Wkv[(size_t)row * MD_ + kc * 8 + 2 * j + 1] : 0.f;
                pk[j] = (unsigned)f2bf(v0) | ((unsigned)f2bf(v1) << 16);
            }
            *(uint4*)(wkb + (((size_t)(mt * 64 + kc)) * 16 + r) * 8) =
                make_uint4(pk[0], pk[1], pk[2], pk[3]);
        }
    } else {                              // halo zeroing: 817 blocks, 209152 = 32*HALO
        int i = (blk - 285) * 256 + tid;
        int bh = i / HALO_;
        int j  = i - bh * HALO_;
        int x, y, z;
        if (j < 2312) {
            x = (j / 1156) * 33;
            int rem = j % 1156;
            y = rem / 34; z = rem % 34;
        } else {
            int k = j - 2312;
            x = 1 + k / 132;
            int m = k % 132;
            if (m < 34)       { y = 0;  z = m; }
            else if (m < 68)  { y = 33; z = m - 34; }
            else if (m < 100) { y = m - 68 + 1;  z = 0; }
            else              { y = m - 100 + 1; z = 33; }
        }
        int pv = (x * PS_ + y) * PS_ + z;
        unsigned short* p = zb16p + ((size_t)bh * PV_ + pv) * 16;
        ((uint4*)p)[0] = make_uint4(0, 0, 0, 0);
        ((uint4*)p)[1] = make_uint4(0, 0, 0, 0);
    }
}

// ---------------- input -> bf16 fragment layout [b][nt(512)][kc(64)][n16][k8]
__global__ __launch_bounds__(256) void xconvert(
    const float* __restrict__ X, unsigned short* __restrict__ xb) {
    int i = blockIdx.x * 256 + threadIdx.x;   // 4*64*8192 = 2,097,152
    int n  = i & (N_ - 1);
    int kc = (i >> 13) & 63;
    int b  = i >> 19;
    const float* xp = X + ((size_t)b * MD_ + kc * 8) * N_ + n;
    unsigned int pk[4];
    #pragma unroll
    for (int j = 0; j < 4; ++j) {
        float v0 = xp[(size_t)(2 * j) * N_];
        float v1 = xp[(size_t)(2 * j + 1) * N_];
        pk[j] = (unsigned)f2bf(v0) | ((unsigned)f2bf(v1) << 16);
    }
    int nt = n >> 4, n16 = n & 15;
    *(uint4*)(xb + ((((size_t)(b * 512 + nt)) * 64 + kc) * 16 + n16) * 8) =
        make_uint4(pk[0], pk[1], pk[2], pk[3]);
}

// ---------------- kv = W_kv @ input via bf16 MFMA + fused channel stats -----
__global__ __launch_bounds__(256) void kv_gemm_mfma(
    const unsigned short* __restrict__ xb, const unsigned short* __restrict__ wkb,
    float* __restrict__ kv, float* __restrict__ kvsum, float* __restrict__ kvsq) {
    int b  = blockIdx.z;
    int mt = blockIdx.y;
    int lane = threadIdx.x & 63, wv = threadIdx.x >> 6;
    int rc = lane & 15, kg = lane >> 4;
    int n0 = blockIdx.x * 512 + wv * 128;
    int nt0 = n0 >> 4;
    const unsigned short* ap = wkb + (((size_t)(mt * 64 + kg)) * 16 + rc) * 8;
    const unsigned short* bp = xb + ((((size_t)(b * 512 + nt0)) * 64 + kg) * 16 + rc) * 8;
    f32x4 acc[8];
    #pragma unroll
    for (int j = 0; j < 8; ++j) acc[j] = (f32x4){0.f, 0.f, 0.f, 0.f};
    #pragma unroll 1
    for (int ks = 0; ks < 16; ++ks) {
        bf16x8 a = *(const bf16x8*)(ap + ks * 512);
        #pragma unroll
        for (int j = 0; j < 8; ++j) {
            bf16x8 bfr = *(const bf16x8*)(bp + (size_t)j * 8192 + ks * 512);
            acc[j] = __builtin_amdgcn_mfma_f32_16x16x32_bf16(a, bfr, acc[j], 0, 0, 0);
        }
    }
    #pragma unroll
    for (int j = 0; j < 8; ++j) {
        int col = n0 + j * 16 + rc;
        #pragma unroll
        for (int r = 0; r < 4; ++r) {
            int m = mt * 16 + kg * 4 + r;
            if (m < CO_) kv[((size_t)b * CO_ + m) * N_ + col] = acc[j][r];
        }
    }
    // fused per-channel partial sums over this wave's 128 cols
    #pragma unroll
    for (int r = 0; r < 4; ++r) {
        int m = mt * 16 + kg * 4 + r;
        float s = 0.f, q = 0.f;
        #pragma unroll
        for (int j = 0; j < 8; ++j) { float v = acc[j][r]; s += v; q = fmaf(v, v, q); }
        #pragma unroll
        for (int off = 1; off < 16; off <<= 1) {
            s += __shfl_xor(s, off);
            q += __shfl_xor(q, off);
        }
        if (rc == 0 && m < CO_) {
            atomicAdd(&kvsum[b * CO_ + m], s);
            atomicAdd(&kvsq[b * CO_ + m], q);
        }
    }
}

// ---------------- point prep: AdaIN (stats from sums) + transform + interp --
__global__ __launch_bounds__(256) void point_prep(
    const float* __restrict__ kv, const float* __restrict__ kvsum,
    const float* __restrict__ kvsq, const float* __restrict__ hk,
    const float* __restrict__ hv, const float* __restrict__ orig,
    const float* __restrict__ scale_p, const float* __restrict__ Tw,
    const float* __restrict__ Tb,
    float4* __restrict__ coordbuf, unsigned* __restrict__ vbuf16,
    int* __restrict__ counts) {
    __shared__ int s_hist[32];
    int tid = threadIdx.x;
    if (tid < 32) s_hist[tid] = 0;
    __syncthreads();
    int p = blockIdx.x * 256 + tid;
    int n = p & (N_ - 1);
    int bh = p >> 13;               // uniform per block
    int h = bh & 7, b = bh >> 3;
    float scl = scale_p[0];

    float pt[3];
    #pragma unroll
    for (int j = 0; j < 3; ++j) {
        int bc = b * CO_ + h * 3 + j;
        float mu = kvsum[bc] * INVN_;
        float rs = rsqrtf(kvsq[bc] * INVN_ - mu * mu + EPS_);
        float x  = kv[(size_t)bc * N_ + n];
        float xn = (x - mu) * rs;
        float kr = fmaf(1.f + hk[b * 48 + h * 3 + j], xn, hk[b * 48 + 24 + h * 3 + j]);
        pt[j] = fmaf(scl, kr, orig[((size_t)(b * 3 + j)) * N_ + n]);
    }
    int f0[3]; float tt[3];
    #pragma unroll
    for (int i = 0; i < 3; ++i) {
        float key = Tb[h * 3 + i];
        #pragma unroll
        for (int j = 0; j < 3; ++j) key = fmaf(Tw[(h * 3 + i) * 3 + j], pt[j], key);
        float lat = tanhf(key);
        float g = (lat + 1.f) * 0.5f * (float)(S_ - 1);
        float ff = floorf(g);
        ff = fminf(fmaxf(ff, 0.f), 30.f);
        f0[i] = (int)ff;
        tt[i] = fminf(fmaxf(g - ff, 0.f), 1.f);
    }
    coordbuf[p] = make_float4(tt[0], tt[1], tt[2],
                              __int_as_float(f0[0] | (f0[1] << 5) | (f0[2] << 10)));
    atomicAdd(&s_hist[f0[0]], 1);   // LDS
    float vf[16];
    #pragma unroll
    for (int f = 0; f < F_; ++f) {
        int bc = b * CO_ + 24 + h * F_ + f;
        float mu = kvsum[bc] * INVN_;
        float rs = rsqrtf(kvsq[bc] * INVN_ - mu * mu + EPS_);
        float x  = kv[(size_t)bc * N_ + n];
        float xn = (x - mu) * rs;
        int cv = h * F_ + f;
        vf[f] = fmaf(1.f + hv[b * 256 + cv], xn, hv[b * 256 + 128 + cv]);
    }
    unsigned pk2[8];
    #pragma unroll
    for (int q = 0; q < 8; ++q)
        pk2[q] = (unsigned)f2bf(vf[2 * q]) | ((unsigned)f2bf(vf[2 * q + 1]) << 16);
    uint4* vb = (uint4*)(vbuf16 + (size_t)p * 8);
    vb[0] = make_uint4(pk2[0], pk2[1], pk2[2], pk2[3]);
    vb[1] = make_uint4(pk2[4], pk2[5], pk2[6], pk2[7]);
    __syncthreads();
    if (tid < 32 && s_hist[tid] > 0)
        atomicAdd(&counts[(bh << 5) + tid], s_hist[tid]);
}

// ---------------- exclusive prefix over the 1024 bins (one wave) ------------
__global__ __launch_bounds__(64) void prefix_bins(
    const int* __restrict__ counts, int* __restrict__ base, int* __restrict__ cursor) {
    int lane = threadIdx.x;
    int local[16], sum = 0;
    #pragma unroll
    for (int i = 0; i < 16; ++i) { local[i] = sum; sum += counts[lane * 16 + i]; }
    int incl = sum;
    #pragma unroll
    for (int off = 1; off < 64; off <<= 1) {
        int v = __shfl_up(incl, off);
        if (lane >= off) incl += v;
    }
    int excl = incl - sum;
    #pragma unroll
    for (int i = 0; i < 16; ++i) {
        int bse = excl + local[i];
        base[lane * 16 + i] = bse;
        cursor[lane * 16 + i] = bse;
    }
    if (lane == 63) base[1024] = excl + sum;
}

// ---------------- scatter point indices into bins (LDS-aggregated) ----------
__global__ __launch_bounds__(256) void scatter_pts(
    const float4* __restrict__ coordbuf, int* __restrict__ cursor,
    unsigned short* __restrict__ recs) {
    __shared__ int s_hist[32];
    __shared__ int s_base[32];
    int tid = threadIdx.x;
    if (tid < 32) s_hist[tid] = 0;
    __syncthreads();
    int p = blockIdx.x * 256 + tid;
    int bh = p >> 13;               // uniform per block
    int pk = __float_as_int(((const float*)coordbuf)[(size_t)p * 4 + 3]);
    int f0x = pk & 31;
    int rank = atomicAdd(&s_hist[f0x], 1);   // LDS
    __syncthreads();
    if (tid < 32 && s_hist[tid] > 0)
        s_base[tid] = atomicAdd(&cursor[(bh << 5) + tid], s_hist[tid]);
    __syncthreads();
    recs[s_base[f0x] + rank] = (unsigned short)(p & (N_ - 1));
}

// ---------------- splat3 v2: sort + LDS-staged records + LDS-only gather ----
__global__ __launch_bounds__(1024) void splat3(
    const float4* __restrict__ coordbuf, const unsigned* __restrict__ vbuf16,
    const int* __restrict__ base, const unsigned short* __restrict__ recs,
    unsigned short* __restrict__ zb16p) {
    __shared__ int s_cnt[1024];
    __shared__ int s_start[1024];
    __shared__ int s_cur[1024];
    __shared__ unsigned s_rec[CHUNK_ * 12];   // 24KB sorted records
    __shared__ int s_wavesum[16];
    int logical = (blockIdx.x & 7) * 128 + (blockIdx.x >> 3);  // XCD swizzle
    int bh = logical >> 5;
    int x0 = logical & 31;
    int tid = threadIdx.x;
    int y = tid >> 5, zc = tid & 31;
    int bin0 = (bh << 5) + x0;
    int s0 = base[bin0], len0 = base[bin0 + 1] - s0;
    int s1 = 0, len1 = 0;
    if (x0 > 0) { s1 = base[bin0 - 1]; len1 = s0 - s1; }
    int total = len0 + len1;
    const float4* cb = coordbuf + (size_t)bh * N_;
    const unsigned* vb = vbuf16 + ((size_t)bh * N_) * 8;
    float acc[16];
    #pragma unroll
    for (int i = 0; i < 16; ++i) acc[i] = 0.f;

    for (int c0 = 0; c0 < total; c0 += CHUNK_) {
        int cl = min(CHUNK_, total - c0);
        s_cnt[tid] = 0;
        __syncthreads();
        int n = 0, cx = 0, sb = 0;
        float4 c;
        bool active = (tid < cl);
        if (active) {
            int tp = c0 + tid;
            if (tp < len0) { n = recs[s0 + tp]; cx = 0; }
            else           { n = recs[s1 + (tp - len0)]; cx = 1; }
            c = cb[n];
            int pk = __float_as_int(c.w);
            sb = (((pk >> 5) & 31) << 5) | ((pk >> 10) & 31);
            atomicAdd(&s_cnt[sb], 1);
        }
        __syncthreads();
        int v = s_cnt[tid];
        int incl = v;
        #pragma unroll
        for (int off = 1; off < 64; off <<= 1) {
            int u = __shfl_up(incl, off);
            if ((tid & 63) >= off) incl += u;
        }
        int wid = tid >> 6;
        if ((tid & 63) == 63) s_wavesum[wid] = incl;
        __syncthreads();
        if (tid < 16) {
            int wv = s_wavesum[tid];
            int wincl = wv;
            #pragma unroll
            for (int off = 1; off < 16; off <<= 1) {
                int u = __shfl_up(wincl, off);
                if (tid >= off) wincl += u;
            }
            s_wavesum[tid] = wincl - wv;
        }
        __syncthreads();
        int excl = incl - v + s_wavesum[wid];
        s_start[tid] = excl;
        s_cur[tid] = excl;
        __syncthreads();
        if (active) {
            int slot = atomicAdd(&s_cur[sb], 1);
            const uint4* vp = (const uint4*)(vb + (size_t)n * 8);
            uint4 v0 = vp[0], v1 = vp[1];
            unsigned* r = s_rec + slot * 12;
            *(uint4*)(r)     = v0;
            *(uint4*)(r + 4) = v1;
            float wx = cx ? c.x : 1.f - c.x;
            *(uint4*)(r + 8) = make_uint4(__float_as_uint(wx), __float_as_uint(c.y),
                                          __float_as_uint(c.z), 0u);
        }
        __syncthreads();
        #pragma unroll
        for (int sy = 0; sy < 2; ++sy) {
            int yy = y - sy;
            if (yy < 0) continue;
            #pragma unroll
            for (int sz = 0; sz < 2; ++sz) {
                int zz = zc - sz;
                if (zz < 0) continue;
                int sbq = (yy << 5) | zz;
                int s = s_start[sbq], e = s + s_cnt[sbq];
                for (int i = s; i < e; ++i) {
                    const unsigned* r = s_rec + i * 12;
                    uint4 cw_ = *(const uint4*)(r + 8);
                    float wx = __uint_as_float(cw_.x);
                    float cy = __uint_as_float(cw_.y);
                    float cz = __uint_as_float(cw_.z);
                    float w = wx * (sy ? cy : 1.f - cy) * (sz ? cz : 1.f - cz);
                    uint4 u0 = *(const uint4*)(r);
                    uint4 u1 = *(const uint4*)(r + 4);
                    unsigned uu[8] = {u0.x, u0.y, u0.z, u0.w, u1.x, u1.y, u1.z, u1.w};
                    #pragma unroll
                    for (int q = 0; q < 8; ++q) {
                        float lo = __uint_as_float(uu[q] << 16);
                        float hi = __uint_as_float(uu[q] & 0xFFFF0000u);
                        acc[2 * q]     = fmaf(w, lo, acc[2 * q]);
                        acc[2 * q + 1] = fmaf(w, hi, acc[2 * q + 1]);
                    }
                }
            }
        }
        __syncthreads();
    }
    unsigned int pk[8];
    #pragma unroll
    for (int q = 0; q < 8; ++q)
        pk[q] = (unsigned)f2bf(acc[2 * q]) | ((unsigned)f2bf(acc[2 * q + 1]) << 16);
    int pv = ((x0 + 1) * PS_ + y + 1) * PS_ + zc + 1;
    unsigned short* zb = zb16p + ((size_t)bh * PV_ + pv) * 16;
    ((uint4*)zb)[0] = make_uint4(pk[0], pk[1], pk[2], pk[3]);
    ((uint4*)zb)[1] = make_uint4(pk[4], pk[5], pk[6], pk[7]);
}

// ---------------- grouped 3x3x3 conv via bf16 MFMA, sliding y-window --------
__global__ __launch_bounds__(256) void conv3d_mfma(
    const unsigned short* __restrict__ zp, const unsigned short* __restrict__ wb,
    const float* __restrict__ cbias, unsigned short* __restrict__ zcb16) {
    int logical = (blockIdx.x & 7) * 128 + (blockIdx.x >> 3);  // 1024 = 8*128
    int bh = logical >> 5;
    int x  = logical & 31;
    int h = bh & 7;
    int lane = threadIdx.x & 63;
    int wv = threadIdx.x >> 6;
    int rc = lane & 15;
    int kb = lane >> 4;
    int ic0 = (kb & 1) << 3;
    int tsel = kb >> 1;
    int z0 = (wv & 1) << 4;
    int y0 = (wv >> 1) << 4;

    int aoff[5];
    #pragma unroll
    for (int pr = 0; pr < 5; ++pr) {
        int c = (pr < 4) ? (pr * 2 + tsel) : 8;
        int dx = c / 3, dz = c % 3;
        aoff[pr] = ((dx - 1) * PS2_ + (dz - 1)) * 32 + ic0 * 2;
    }
    bf16x8 bfr[15];
    const unsigned short* wh = wb + h * 30 * 256;
    #pragma unroll
    for (int p = 0; p < 15; ++p)
        bfr[p] = *(const bf16x8*)(wh + (((p * 2 + tsel) * 16 + rc) << 4) + ic0);
    float bias = cbias[h * 16 + rc];
    const char* zb = (const char*)(zp + (size_t)bh * PV_ * 16);
    unsigned short* zcb = zcb16 + ((size_t)bh << 19);
    int colbase = (x + 1) * PS2_ + z0 + rc + 1;

    bf16x8 w0[5], w1[5], w2[5];
    #pragma unroll
    for (int pr = 0; pr < 5; ++pr) {
        w0[pr] = *(const bf16x8*)(zb + (size_t)(colbase + (y0)     * PS_) * 32 + aoff[pr]);
        w1[pr] = *(const bf16x8*)(zb + (size_t)(colbase + (y0 + 1) * PS_) * 32 + aoff[pr]);
        w2[pr] = *(const bf16x8*)(zb + (size_t)(colbase + (y0 + 2) * PS_) * 32 + aoff[pr]);
    }
    #pragma unroll 1
    for (int y = y0; y < y0 + 16; ++y) {
        f32x4 a0 = {0.f, 0.f, 0.f, 0.f};
        f32x4 a1 = {0.f, 0.f, 0.f, 0.f};
        f32x4 a2 = {0.f, 0.f, 0.f, 0.f};
        #pragma unroll
        for (int pr = 0; pr < 5; ++pr) {
            a0 = __builtin_amdgcn_mfma_f32_16x16x32_bf16(w0[pr], bfr[pr],      a0, 0, 0, 0);
            a1 = __builtin_amdgcn_mfma_f32_16x16x32_bf16(w1[pr], bfr[5 + pr],  a1, 0, 0, 0);
            a2 = __builtin_amdgcn_mfma_f32_16x16x32_bf16(w2[pr], bfr[10 + pr], a2, 0, 0, 0);
        }
        int vout = (((x << 5) + y) << 5) + z0 + (kb << 2);
        #pragma unroll
        for (int r = 0; r < 4; ++r)
            zcb[(size_t)(vout + r) * 16 + rc] = f2bf(a0[r] + a1[r] + a2[r] + bias);
        #pragma unroll
        for (int pr = 0; pr < 5; ++pr) { w0[pr] = w1[pr]; w1[pr] = w2[pr]; }
        if (y < y0 + 15) {
            #pragma unroll
            for (int pr = 0; pr < 5; ++pr)
                w2[pr] = *(const bf16x8*)(zb + (size_t)(colbase + (y + 3) * PS_) * 32 + aoff[pr]);
        }
    }
}

// ---------------- slice: weighted gather + fused output stats ---------------
__global__ __launch_bounds__(256) void slice_vm(
    const unsigned short* __restrict__ zcb16, const float4* __restrict__ coordbuf,
    float* __restrict__ out, float* __restrict__ osum, float* __restrict__ osq) {
    __shared__ float s_sum[4][16], s_sq[4][16];
    int logical = (blockIdx.x & 7) * 128 + (blockIdx.x >> 3);  // 1024 = 8*128
    int tid = threadIdx.x;
    int p = logical * 256 + tid;
    int n = p & (N_ - 1);
    int bh = p >> 13;               // uniform per block
    int h = bh & 7, b = bh >> 3;
    float4 c = coordbuf[p];
    int pk = __float_as_int(c.w);
    int f0x = pk & 31, f0y = (pk >> 5) & 31, f0z = (pk >> 10) & 31;
    const unsigned short* gb = zcb16 + ((size_t)bh << 19);
    float acc[16];
    #pragma unroll
    for (int f = 0; f < 16; ++f) acc[f] = 0.f;
    #pragma unroll 1
    for (int k = 0; k < 8; ++k) {
        int cx = (k >> 2) & 1, cy = (k >> 1) & 1, cz = k & 1;
        float w = (cx ? c.x : 1.f - c.x) * (cy ? c.y : 1.f - c.y) * (cz ? c.z : 1.f - c.z);
        int vox = (((f0x + cx) << 5) + f0y + cy) * 32 + f0z + cz;
        const uint4* ip = (const uint4*)(gb + ((size_t)vox << 4));
        uint4 u0 = ip[0], u1 = ip[1];
        unsigned uu[8] = {u0.x, u0.y, u0.z, u0.w, u1.x, u1.y, u1.z, u1.w};
        #pragma unroll
        for (int q = 0; q < 8; ++q) {
            float lo = __uint_as_float(uu[q] << 16);
            float hi = __uint_as_float(uu[q] & 0xFFFF0000u);
            acc[2 * q]     = fmaf(w, lo, acc[2 * q]);
            acc[2 * q + 1] = fmaf(w, hi, acc[2 * q + 1]);
        }
    }
    #pragma unroll
    for (int f = 0; f < 16; ++f)
        out[(((size_t)(b * HF_ + h * F_ + f)) << 13) + n] = acc[f];
    // fused stats: wave-reduce sum & sumsq per channel, combine via LDS
    float ps[16], pq[16];
    #pragma unroll
    for (int f = 0; f < 16; ++f) { ps[f] = acc[f]; pq[f] = acc[f] * acc[f]; }
    #pragma unroll
    for (int off = 1; off < 64; off <<= 1) {
        #pragma unroll
        for (int f = 0; f < 16; ++f) {
            ps[f] += __shfl_xor(ps[f], off);
            pq[f] += __shfl_xor(pq[f], off);
        }
    }
    int wv = tid >> 6;
    if ((tid & 63) == 0) {
        #pragma unroll
        for (int f = 0; f < 16; ++f) { s_sum[wv][f] = ps[f]; s_sq[wv][f] = pq[f]; }
    }
    __syncthreads();
    if (tid < 16) {
        float t = s_sum[0][tid] + s_sum[1][tid] + s_sum[2][tid] + s_sum[3][tid];
        float u = s_sq[0][tid] + s_sq[1][tid] + s_sq[2][tid] + s_sq[3][tid];
        atomicAdd(&osum[b * HF_ + h * F_ + tid], t);
        atomicAdd(&osq[b * HF_ + h * F_ + tid], u);
    }
}

// ---------------- final AdaIN + ReLU (stats from sums, in place) ------------
__global__ __launch_bounds__(256) void final_adain(
    float* __restrict__ out, const float* __restrict__ osum,
    const float* __restrict__ osq, const float* __restrict__ ha) {
    size_t i = (size_t)blockIdx.x * 256 + threadIdx.x;
    int bc = (int)(i >> 13);
    int c = bc & 127, b = bc >> 7;
    float mu = osum[bc] * INVN_;
    float rs = rsqrtf(osq[bc] * INVN_ - mu * mu + EPS_);
    float x = out[i];
    float xn = (x - mu) * rs;
    float y = fmaf(1.f + ha[b * 256 + c], xn, ha[b * 256 + 128 + c]);
    out[i] = fmaxf(y, 0.f);
}

extern "C" void kernel_launch(void* const* d_in, const int* in_sizes, int n_in,
                              void* d_out, int out_size, void* d_ws, size_t ws_size,
                              hipStream_t stream) {
    (void)in_sizes; (void)n_in; (void)out_size; (void)ws_size;
    const float* input   = (const float*)d_in[0];
    const float* style   = (const float*)d_in[1];
    const float* orig    = (const float*)d_in[2];
    const float* Wkv     = (const float*)d_in[3];
    const float* kw_w    = (const float*)d_in[4];
    const float* kw_b    = (const float*)d_in[5];
    const float* vw_w    = (const float*)d_in[6];
    const float* vw_b    = (const float*)d_in[7];
    const float* aw_w    = (const float*)d_in[8];
    const float* aw_b    = (const float*)d_in[9];
    const float* scale_p = (const float*)d_in[10];
    const float* Tw      = (const float*)d_in[11];
    const float* Tb      = (const float*)d_in[12];
    const float* conv_w  = (const float*)d_in[13];
    const float* conv_b  = (const float*)d_in[14];
    float* out = (float*)d_out;

    // -------- workspace layout (floats), ~146.0 MB total --------------------
    float* ws = (float*)d_ws;
    unsigned short* zb16p = (unsigned short*)ws;     // padded lattice bf16 (40.2MB)
    float* zc       = ws + 10061824;                 // 64MB region; conv uses first 32MB as bf16
    float* xbf_f    = ws + 26839040;                 //  8,388,608 (32MB) bf16 input frags
    float* coordbuf = ws + 35227648;                 //  1,048,576
    float* wt       = ws + 36276224;                 //     55,296 floats (conv bf16 weights)
    float* wkb_f    = ws + 36331520;                 //     40,960 (W_kv bf16 frags)
    float* recs_f   = ws + 36372480;                 //    131,072 (262,144 u16)
    float* ha       = ws + 36503552;                 //      1,024
    float* hk       = ha + 1024;                     //        192
    float* hv       = hk + 192;                      //      1,024
    int*   counts   = (int*)(hv + 1024);             //      1,024 ints
    int*   base     = counts + 1024;                 //      1,025 ints
    int*   cursor   = base + 1025;                   //      1,024 ints
    float* sums     = (float*)(cursor + 1024);       //      2,240 floats (all stat accumulators)
    float* kvsum    = sums;                          //        608
    float* kvsq     = kvsum + 608;                   //        608
    float* osum     = kvsq + 608;                    //        512
    float* osq      = osum + 512;                    //        512
    // aliased into zc region (dead before conv3d writes zcb16):
    unsigned* vbuf16 = (unsigned*)zc;                //  2,097,152 u32 (8MB) bf16 values
    float* kv   = zc + 2097152;                      //  4,980,736 (19MB)
    unsigned short* zcb16 = (unsigned short*)zc;     // conv output bf16 (32MB)
    unsigned short* xbf  = (unsigned short*)xbf_f;
    unsigned short* wb16 = (unsigned short*)wt;
    unsigned short* wkb  = (unsigned short*)wkb_f;
    unsigned short* recs = (unsigned short*)recs_f;

    setup_misc<<<1102, 256, 0, stream>>>(style, kw_w, kw_b, vw_w, vw_b, aw_w, aw_b,
                                         conv_w, Wkv, hk, hv, ha, wb16, wkb,
                                         counts, sums, zb16p);
    xconvert<<<8192, 256, 0, stream>>>(input, xbf);
    kv_gemm_mfma<<<dim3(16, 10, B_), 256, 0, stream>>>(xbf, wkb, kv, kvsum, kvsq);
    point_prep<<<B_ * H_ * N_ / 256, 256, 0, stream>>>(
        kv, kvsum, kvsq, hk, hv, orig, scale_p, Tw, Tb,
        (float4*)coordbuf, vbuf16, counts);
    prefix_bins<<<1, 64, 0, stream>>>(counts, base, cursor);
    scatter_pts<<<B_ * H_ * N_ / 256, 256, 0, stream>>>((const float4*)coordbuf, cursor, recs);
    splat3<<<1024, 1024, 0, stream>>>((const float4*)coordbuf, vbuf16, base, recs, zb16p);
    conv3d_mfma<<<1024, 256, 0, stream>>>(zb16p, wb16, conv_b, zcb16);
    slice_vm<<<B_ * H_ * N_ / 256, 256, 0, stream>>>(zcb16, (const float4*)coordbuf, out, osum, osq);
    final_adain<<<B_ * HF_ * N_ / 256, 256, 0, stream>>>(out, osum, osq, ha);
}